// Round 1
// baseline (16020.058 us; speedup 1.0000x reference)
//
#include <hip/hip_runtime.h>

#define NPTS 32768
#define HL   32768
#define NNB  15
#define KC   32

__device__ __forceinline__ float lrelu(float x){ return x > 0.0f ? x : 0.1f*x; }

// ---------------------------------------------------------------- zero
__global__ void zero_kernel(float4* __restrict__ buf){
    buf[(size_t)blockIdx.x*256 + threadIdx.x] = make_float4(0.f,0.f,0.f,0.f);
}

// ---------------------------------------------------------------- repack weights
// sw1 (64,68,15) -> sw1t[nn][i][o] (15,68,64); pw1 (128,128,15) -> pw1t[nn][i][o] (15,128,128)
__global__ void repack_kernel(const float* __restrict__ sw1, const float* __restrict__ pw1,
                              float* __restrict__ sw1t, float* __restrict__ pw1t){
    int tid = blockIdx.x*256 + threadIdx.x;
    if (tid < 65280){
        int nn = tid / 4352, r = tid % 4352, i = r >> 6, o = r & 63;
        sw1t[tid] = sw1[(o*68 + i)*15 + nn];
    }
    if (tid < 245760){
        int nn = tid / 16384, r = tid & 16383, i = r >> 7, o = r & 127;
        pw1t[tid] = pw1[(o*128 + i)*15 + nn];
    }
}

// ---------------------------------------------------------------- point MLP (3->32->32->64) + el pack
// pfeat row layout per point: [el0..el3, feat0..feat63]  (68 floats)
__global__ __launch_bounds__(256) void mlp3_kernel(
        const float* __restrict__ pc, const float* __restrict__ el,
        const float* __restrict__ w1, const float* __restrict__ b1,
        const float* __restrict__ w2, const float* __restrict__ b2,
        const float* __restrict__ w3, const float* __restrict__ b3,
        float* __restrict__ pfeat){
    __shared__ float W1[96], W2s[1024], W3s[2048], B1[32], B2[32], B3[64];
    const int t = threadIdx.x;
    for (int e=t;e<96;e+=256)   W1[e]=w1[e];
    for (int e=t;e<1024;e+=256) W2s[e]=w2[e];
    for (int e=t;e<2048;e+=256) W3s[e]=w3[e];
    if (t<32){ B1[t]=b1[t]; B2[t]=b2[t]; }
    if (t<64){ B3[t]=b3[t]; }
    __syncthreads();
    const int n = blockIdx.x*256 + t;
    const float x0 = pc[n], x1 = pc[NPTS+n], x2 = pc[2*NPTS+n];
    float h1[32];
    #pragma unroll
    for (int o=0;o<32;++o)
        h1[o] = lrelu(B1[o] + W1[o*3]*x0 + W1[o*3+1]*x1 + W1[o*3+2]*x2);
    float h2[32];
    #pragma unroll
    for (int o=0;o<32;++o){
        float a = B2[o];
        #pragma unroll
        for (int c=0;c<32;++c) a += W2s[o*32+c]*h1[c];
        h2[o] = lrelu(a);
    }
    float* row = pfeat + (size_t)n*68;
    *(float4*)row = make_float4(el[n], el[NPTS+n], el[2*NPTS+n], el[3*NPTS+n]);
    #pragma unroll
    for (int o4=0;o4<16;++o4){
        float tmp[4];
        #pragma unroll
        for (int q=0;q<4;++q){
            const int o = o4*4+q;
            float a = B3[o];
            #pragma unroll
            for (int c=0;c<32;++c) a += W3s[o*32+c]*h2[c];
            tmp[q] = lrelu(a);
        }
        *(float4*)(row + 4 + o4*4) = make_float4(tmp[0],tmp[1],tmp[2],tmp[3]);
    }
}

// ---------------------------------------------------------------- splat (scatter-add)
// lat layout (H,68): lat[h*68 + c]
__global__ void splat_kernel(const float* __restrict__ pfeat, const float* __restrict__ bary,
                             const int* __restrict__ off, float* __restrict__ lat){
    const int tid = blockIdx.x*256 + threadIdx.x;   // tid = j*NPTS + n,  j<5
    const int n = tid & (NPTS-1);
    const float b = bary[tid];
    const int o = off[tid];
    const float* row = pfeat + (size_t)n*68;
    float* dst = lat + (size_t)o*68;
    #pragma unroll 4
    for (int c=0;c<68;++c) unsafeAtomicAdd(&dst[c], b*row[c]);
}

// ---------------------------------------------------------------- blur_s: 64x(68*15) gathered GEMM + fused sw2 (64x64)
// out (H,ostride): side1 -> cat[h*128 + o] (o<64), side2 -> lat2p[h*64 + o]
__global__ __launch_bounds__(256) void blur_s_kernel(
        const float* __restrict__ lat, const int* __restrict__ nb,
        const float* __restrict__ sw1t, const float* __restrict__ sb1,
        const float* __restrict__ sw2, const float* __restrict__ sb2,
        float* __restrict__ outp, int ostride){
    __shared__ __align__(16) float smem[8704];
    float* Gl = smem;          // [68][64]
    float* Wl = smem + 4352;   // [68][64]
    float* T  = smem;          // [64][64]   (epilogue, overlaps Gl)
    float* W2 = smem + 4096;   // [64][65]   (epilogue, padded)
    const int t = threadIdx.x;
    const int tx = t & 15, ty = t >> 4;
    const int hb = blockIdx.x * 64;
    const int col = t >> 2, part = t & 3;
    float acc[4][4] = {};
    for (int nn=0; nn<NNB; ++nn){
        const int idx = nb[nn*HL + hb + col];
        const float* src = lat + (size_t)idx*68;
        __syncthreads();
        #pragma unroll
        for (int q=0;q<17;++q){
            const int k = part*17 + q;
            Gl[k*64 + col] = src[k];
        }
        for (int e=t;e<4352;e+=256) Wl[e] = sw1t[nn*4352 + e];
        __syncthreads();
        for (int k=0;k<68;++k){
            const float4 g4 = *(const float4*)(Gl + k*64 + tx*4);
            const float4 w4 = *(const float4*)(Wl + k*64 + ty*4);
            const float g[4] = {g4.x,g4.y,g4.z,g4.w};
            const float w[4] = {w4.x,w4.y,w4.z,w4.w};
            #pragma unroll
            for (int i=0;i<4;++i)
                #pragma unroll
                for (int j=0;j<4;++j)
                    acc[i][j] = fmaf(w[i], g[j], acc[i][j]);
        }
    }
    __syncthreads();
    #pragma unroll
    for (int i=0;i<4;++i){
        const int o = ty*4 + i;
        const float b = sb1[o];
        #pragma unroll
        for (int j=0;j<4;++j)
            T[o*64 + tx*4 + j] = lrelu(acc[i][j] + b);
    }
    for (int e=t;e<4096;e+=256){
        const int c = e & 63, o = e >> 6;
        W2[o*65 + c] = sw2[e];
    }
    __syncthreads();
    float acc2[4][4] = {};
    for (int c=0;c<64;++c){
        const float4 t4 = *(const float4*)(T + c*64 + tx*4);
        const float tv[4] = {t4.x,t4.y,t4.z,t4.w};
        #pragma unroll
        for (int i=0;i<4;++i){
            const float w = W2[(ty*4+i)*65 + c];
            #pragma unroll
            for (int j=0;j<4;++j)
                acc2[i][j] = fmaf(w, tv[j], acc2[i][j]);
        }
    }
    #pragma unroll
    for (int j=0;j<4;++j){
        const int h = hb + tx*4 + j;
        #pragma unroll
        for (int i=0;i<4;++i){
            const int o = ty*4 + i;
            outp[(size_t)h*ostride + o] = lrelu(acc2[i][j] + sb2[o]);
        }
    }
}

// ---------------------------------------------------------------- correlation + d-MLP
// reads cat[h*128 + 0..63] (lat1), lat2p; writes cat[h*128 + 64..127]
__global__ __launch_bounds__(256,1) void corr_kernel(
        float* __restrict__ cat, const float* __restrict__ lat2, const int* __restrict__ ci,
        const float* __restrict__ cw1, const float* __restrict__ cb1,
        const float* __restrict__ cw2, const float* __restrict__ cb2,
        const float* __restrict__ dw1, const float* __restrict__ db1,
        const float* __restrict__ dw2, const float* __restrict__ db2){
    __shared__ float CW1[2048], CW2[1024], DW1[2048], DW2[4096];
    __shared__ float CB1[32], CB2[32], DB1[64], DB2[64];
    const int t = threadIdx.x;
    for (int e=t;e<2048;e+=256) CW1[e]=cw1[e];
    for (int e=t;e<1024;e+=256) CW2[e]=cw2[e];
    for (int e=t;e<2048;e+=256) DW1[e]=dw1[e];
    for (int e=t;e<4096;e+=256) DW2[e]=dw2[e];
    if (t<32){ CB1[t]=cb1[t]; CB2[t]=cb2[t]; }
    if (t<64){ DB1[t]=db1[t]; DB2[t]=db2[t]; }
    __syncthreads();
    const int h = blockIdx.x*256 + t;
    float l1[64];
    {
        const float4* cr = (const float4*)(cat + (size_t)h*128);
        #pragma unroll
        for (int c4=0;c4<16;++c4){
            const float4 v = cr[c4];
            l1[c4*4]=v.x; l1[c4*4+1]=v.y; l1[c4*4+2]=v.z; l1[c4*4+3]=v.w;
        }
    }
    float agg[32];
    #pragma unroll
    for (int o=0;o<32;++o) agg[o]=0.f;
    for (int k=0;k<KC;++k){
        const int idx = ci[k*HL + h];
        const float4* g2 = (const float4*)(lat2 + (size_t)idx*64);
        float m1[32];
        #pragma unroll
        for (int o=0;o<32;++o) m1[o]=CB1[o];
        #pragma unroll
        for (int c4=0;c4<16;++c4){
            const float4 gv = g2[c4];
            const float p0 = l1[c4*4  ]*gv.x;
            const float p1 = l1[c4*4+1]*gv.y;
            const float p2 = l1[c4*4+2]*gv.z;
            const float p3 = l1[c4*4+3]*gv.w;
            #pragma unroll
            for (int o=0;o<32;++o){
                const float4 w = *(const float4*)(CW1 + o*64 + c4*4);
                m1[o] += w.x*p0 + w.y*p1 + w.z*p2 + w.w*p3;
            }
        }
        #pragma unroll
        for (int o=0;o<32;++o) m1[o]=lrelu(m1[o]);
        #pragma unroll
        for (int o2=0;o2<32;++o2){
            float a = CB2[o2];
            #pragma unroll
            for (int c=0;c<32;++c) a += CW2[o2*32+c]*m1[c];
            agg[o2] += lrelu(a);
        }
    }
    const float s = 1.0f/32.0f;
    #pragma unroll
    for (int o=0;o<32;++o) agg[o] *= s;
    float d1[64];
    #pragma unroll
    for (int o=0;o<64;++o){
        float a = DB1[o];
        #pragma unroll
        for (int c=0;c<32;++c) a += DW1[o*32+c]*agg[c];
        d1[o] = lrelu(a);
    }
    float* dout = cat + (size_t)h*128 + 64;
    for (int o2=0;o2<64;++o2){
        float a = DB2[o2];
        #pragma unroll
        for (int c=0;c<64;++c) a += DW2[o2*64+c]*d1[c];
        dout[o2] = lrelu(a);
    }
}

// ---------------------------------------------------------------- blur_p: 128x(128*15) gathered GEMM + fused pw2 (128x128)
__global__ __launch_bounds__(256) void blur_p_kernel(
        const float* __restrict__ cat, const int* __restrict__ nb,
        const float* __restrict__ pw1t, const float* __restrict__ pb1,
        const float* __restrict__ pw2, const float* __restrict__ pb2,
        float* __restrict__ p){
    __shared__ __align__(16) float smem[16512];
    float* Gl = smem;           // [64][64]
    float* Wl = smem + 4096;    // [64][128]
    float* T  = smem;           // [128][64]  (epilogue)
    float* W2 = smem + 8192;    // [128][65]  (epilogue, padded)
    const int t = threadIdx.x;
    const int tx = t & 15, ty = t >> 4;
    const int hb = blockIdx.x * 64;
    const int col = t >> 2, part = t & 3;
    float acc[8][4] = {};
    for (int nn=0; nn<NNB; ++nn){
        const int idx = nb[nn*HL + hb + col];
        const float* src = cat + (size_t)idx*128;
        #pragma unroll 1
        for (int ic=0; ic<2; ++ic){
            __syncthreads();
            #pragma unroll
            for (int q=0;q<16;++q){
                const int k = part*16 + q;
                Gl[k*64 + col] = src[ic*64 + k];
            }
            for (int e=t;e<8192;e+=256) Wl[e] = pw1t[nn*16384 + ic*8192 + e];
            __syncthreads();
            for (int k=0;k<64;++k){
                const float4 g4 = *(const float4*)(Gl + k*64 + tx*4);
                const float4 wa = *(const float4*)(Wl + k*128 + ty*8);
                const float4 wb = *(const float4*)(Wl + k*128 + ty*8 + 4);
                const float g[4] = {g4.x,g4.y,g4.z,g4.w};
                const float w[8] = {wa.x,wa.y,wa.z,wa.w, wb.x,wb.y,wb.z,wb.w};
                #pragma unroll
                for (int i=0;i<8;++i)
                    #pragma unroll
                    for (int j=0;j<4;++j)
                        acc[i][j] = fmaf(w[i], g[j], acc[i][j]);
            }
        }
    }
    __syncthreads();
    #pragma unroll
    for (int i=0;i<8;++i){
        const int o = ty*8 + i;
        const float b = pb1[o];
        #pragma unroll
        for (int j=0;j<4;++j)
            T[o*64 + tx*4 + j] = lrelu(acc[i][j] + b);
    }
    float acc2[8][4] = {};
    #pragma unroll 1
    for (int cc=0; cc<2; ++cc){
        __syncthreads();
        for (int e=t;e<8192;e+=256){
            const int c = e & 63, o2 = e >> 6;
            W2[o2*65 + c] = pw2[o2*128 + cc*64 + c];
        }
        __syncthreads();
        for (int c=0;c<64;++c){
            const float4 t4 = *(const float4*)(T + (cc*64+c)*64 + tx*4);
            const float tv[4] = {t4.x,t4.y,t4.z,t4.w};
            #pragma unroll
            for (int i=0;i<8;++i){
                const float w = W2[(ty*8+i)*65 + c];
                #pragma unroll
                for (int j=0;j<4;++j)
                    acc2[i][j] = fmaf(w, tv[j], acc2[i][j]);
            }
        }
    }
    #pragma unroll
    for (int j=0;j<4;++j){
        const int h = hb + tx*4 + j;
        float* prow = p + (size_t)h*128 + ty*8;
        #pragma unroll
        for (int i=0;i<8;++i)
            prow[i] = lrelu(acc2[i][j] + pb2[ty*8+i]);
    }
}

// ---------------------------------------------------------------- slice + final MLP (128->128->64->3)
__global__ __launch_bounds__(256,1) void head_kernel(
        const float* __restrict__ p, const float* __restrict__ bary, const int* __restrict__ off,
        const float* __restrict__ fw2, const float* __restrict__ fb2,
        const float* __restrict__ fw3, const float* __restrict__ fb3,
        const float* __restrict__ fw4, const float* __restrict__ fb4,
        float* __restrict__ out){
    __shared__ float FW2[16384], FW3[8192], FW4[192];
    __shared__ float FB2[128], FB3[64], FB4[3];
    const int t = threadIdx.x;
    for (int e=t;e<16384;e+=256) FW2[e]=fw2[e];
    for (int e=t;e<8192;e+=256)  FW3[e]=fw3[e];
    if (t<192) FW4[t]=fw4[t];
    if (t<128) FB2[t]=fb2[t];
    if (t<64)  FB3[t]=fb3[t];
    if (t<3)   FB4[t]=fb4[t];
    __syncthreads();
    const int n = blockIdx.x*256 + t;
    float bw[5]; int o5[5];
    #pragma unroll
    for (int j=0;j<5;++j){ bw[j]=bary[j*NPTS+n]; o5[j]=off[j*NPTS+n]; }
    float h1[128];
    #pragma unroll
    for (int o=0;o<128;++o) h1[o]=FB2[o];
    for (int c4=0;c4<32;++c4){
        float4 s = make_float4(0.f,0.f,0.f,0.f);
        #pragma unroll
        for (int j=0;j<5;++j){
            const float4 v = *(const float4*)(p + (size_t)o5[j]*128 + c4*4);
            s.x += bw[j]*v.x; s.y += bw[j]*v.y; s.z += bw[j]*v.z; s.w += bw[j]*v.w;
        }
        #pragma unroll
        for (int o=0;o<128;++o){
            const float4 w = *(const float4*)(FW2 + o*128 + c4*4);
            h1[o] += w.x*s.x + w.y*s.y + w.z*s.z + w.w*s.w;
        }
    }
    #pragma unroll
    for (int o=0;o<128;++o) h1[o]=lrelu(h1[o]);
    float f0=FB4[0], f1=FB4[1], f2=FB4[2];
    for (int o2=0;o2<64;++o2){
        float a = FB3[o2];
        #pragma unroll
        for (int c=0;c<128;++c) a += FW3[o2*128+c]*h1[c];
        const float h2 = lrelu(a);
        f0 += FW4[o2]*h2;
        f1 += FW4[64+o2]*h2;
        f2 += FW4[128+o2]*h2;
    }
    out[n] = f0; out[NPTS+n] = f1; out[2*NPTS+n] = f2;
}

// ================================================================ launch
extern "C" void kernel_launch(void* const* d_in, const int* in_sizes, int n_in,
                              void* d_out, int out_size, void* d_ws, size_t ws_size,
                              hipStream_t stream){
    const float* pc1   = (const float*)d_in[0];
    const float* pc2   = (const float*)d_in[1];
    const float* el1   = (const float*)d_in[2];
    const float* el2   = (const float*)d_in[3];
    const float* bary1 = (const float*)d_in[4];
    const float* bary2 = (const float*)d_in[5];
    const int*   off1  = (const int*)d_in[6];
    const int*   off2  = (const int*)d_in[7];
    const int*   nb1   = (const int*)d_in[8];
    const int*   nb2   = (const int*)d_in[9];
    const int*   ci    = (const int*)d_in[10];
    const float* w1    = (const float*)d_in[11];
    const float* b1    = (const float*)d_in[12];
    const float* w2    = (const float*)d_in[13];
    const float* b2    = (const float*)d_in[14];
    const float* w3    = (const float*)d_in[15];
    const float* b3    = (const float*)d_in[16];
    const float* sw1   = (const float*)d_in[17];
    const float* sb1   = (const float*)d_in[18];
    const float* sw2   = (const float*)d_in[19];
    const float* sb2   = (const float*)d_in[20];
    const float* cw1   = (const float*)d_in[21];
    const float* cb1   = (const float*)d_in[22];
    const float* cw2   = (const float*)d_in[23];
    const float* cb2   = (const float*)d_in[24];
    const float* dw1   = (const float*)d_in[25];
    const float* db1   = (const float*)d_in[26];
    const float* dw2   = (const float*)d_in[27];
    const float* db2   = (const float*)d_in[28];
    const float* pw1   = (const float*)d_in[29];
    const float* pb1   = (const float*)d_in[30];
    const float* pw2   = (const float*)d_in[31];
    const float* pb2   = (const float*)d_in[32];
    const float* fw2   = (const float*)d_in[33];
    const float* fb2   = (const float*)d_in[34];
    const float* fw3   = (const float*)d_in[35];
    const float* fb3   = (const float*)d_in[36];
    const float* fw4   = (const float*)d_in[37];
    const float* fb4   = (const float*)d_in[38];
    float* out = (float*)d_out;

    float* ws    = (float*)d_ws;
    float* pf1   = ws;                    // N*68 = 2228224
    float* pf2   = pf1   + 2228224;
    float* latA  = pf2   + 2228224;       // H*68
    float* latB  = latA  + 2228224;
    float* catb  = latB  + 2228224;       // H*128 = 4194304
    float* lat2p = catb  + 4194304;       // H*64  = 2097152
    float* sw1t  = lat2p + 2097152;       // 65280
    float* pw1t  = sw1t  + 65280;         // 245760
    float* pbuf  = pf1;                   // p (H*128) reuses pf1+pf2 (dead after splat)

    // zero the two splat lattices (contiguous: 2*2228224 floats = 1114112 float4)
    zero_kernel<<<4352, 256, 0, stream>>>((float4*)latA);
    repack_kernel<<<960, 256, 0, stream>>>(sw1, pw1, sw1t, pw1t);

    mlp3_kernel<<<128, 256, 0, stream>>>(pc1, el1, w1,b1,w2,b2,w3,b3, pf1);
    mlp3_kernel<<<128, 256, 0, stream>>>(pc2, el2, w1,b1,w2,b2,w3,b3, pf2);

    splat_kernel<<<640, 256, 0, stream>>>(pf1, bary1, off1, latA);
    splat_kernel<<<640, 256, 0, stream>>>(pf2, bary2, off2, latB);

    blur_s_kernel<<<512, 256, 0, stream>>>(latA, nb1, sw1t, sb1, sw2, sb2, catb, 128);
    blur_s_kernel<<<512, 256, 0, stream>>>(latB, nb2, sw1t, sb1, sw2, sb2, lat2p, 64);

    corr_kernel<<<128, 256, 0, stream>>>(catb, lat2p, ci, cw1,cb1,cw2,cb2,dw1,db1,dw2,db2);

    blur_p_kernel<<<512, 256, 0, stream>>>(catb, nb1, pw1t, pb1, pw2, pb2, pbuf);

    head_kernel<<<128, 256, 0, stream>>>(pbuf, bary1, off1, fw2,fb2,fw3,fb3,fw4,fb4, out);
}

// Round 2
// 1900.243 us; speedup vs baseline: 8.4305x; 8.4305x over previous
//
#include <hip/hip_runtime.h>

#define NPTS 32768
#define HL   32768
#define NNB  15
#define KC   32

__device__ __forceinline__ float lrelu(float x){ return x > 0.0f ? x : 0.1f*x; }

// ---------------------------------------------------------------- zero
__global__ void zero_kernel(float4* __restrict__ buf){
    buf[(size_t)blockIdx.x*256 + threadIdx.x] = make_float4(0.f,0.f,0.f,0.f);
}

// ---------------------------------------------------------------- repack weights (+ transposes)
__global__ void repack_kernel(const float* __restrict__ sw1, const float* __restrict__ pw1,
                              const float* __restrict__ sw2, const float* __restrict__ cw1,
                              const float* __restrict__ cw2, const float* __restrict__ dw1,
                              const float* __restrict__ dw2, const float* __restrict__ pw2,
                              const float* __restrict__ fw2, const float* __restrict__ fw3,
                              float* __restrict__ sw1t, float* __restrict__ pw1t,
                              float* __restrict__ sw2T, float* __restrict__ cw1T,
                              float* __restrict__ cw2T, float* __restrict__ dw1T,
                              float* __restrict__ dw2T, float* __restrict__ pw2T,
                              float* __restrict__ fw2T, float* __restrict__ fw3T){
    int tid = blockIdx.x*256 + threadIdx.x;
    if (tid < 65280){ int nn = tid/4352, r = tid%4352, i = r>>6, o = r&63;
        sw1t[tid] = sw1[(o*68+i)*15+nn]; }
    if (tid < 245760){ int nn = tid/16384, r = tid&16383, i = r>>7, o = r&127;
        pw1t[tid] = pw1[(o*128+i)*15+nn]; }
    if (tid < 4096){ int c = tid>>6, o = tid&63; sw2T[tid] = sw2[o*64+c]; }
    if (tid < 2048){ int c = tid>>5, o = tid&31; cw1T[tid] = cw1[o*64+c]; }
    if (tid < 1024){ int c = tid>>5, o = tid&31; cw2T[tid] = cw2[o*32+c]; }
    if (tid < 2048){ int c = tid>>6, o = tid&63; dw1T[tid] = dw1[o*32+c]; }
    if (tid < 4096){ int c = tid>>6, o = tid&63; dw2T[tid] = dw2[o*64+c]; }
    if (tid < 16384){ int c = tid>>7, o = tid&127; pw2T[tid] = pw2[o*128+c]; }
    if (tid < 16384){ int c = tid>>7, o = tid&127; fw2T[tid] = fw2[o*128+c]; }
    if (tid < 8192){ int c = tid>>6, o = tid&63; fw3T[tid] = fw3[o*128+c]; }
}

// ---------------------------------------------------------------- point MLP (3->32->32->64) + el pack
__global__ __launch_bounds__(256) void mlp3_kernel(
        const float* __restrict__ pc, const float* __restrict__ el,
        const float* __restrict__ w1, const float* __restrict__ b1,
        const float* __restrict__ w2, const float* __restrict__ b2,
        const float* __restrict__ w3, const float* __restrict__ b3,
        float* __restrict__ pfeat){
    __shared__ float W1[96], W2s[1024], W3s[2048], B1[32], B2[32], B3[64];
    const int t = threadIdx.x;
    for (int e=t;e<96;e+=256)   W1[e]=w1[e];
    for (int e=t;e<1024;e+=256) W2s[e]=w2[e];
    for (int e=t;e<2048;e+=256) W3s[e]=w3[e];
    if (t<32){ B1[t]=b1[t]; B2[t]=b2[t]; }
    if (t<64){ B3[t]=b3[t]; }
    __syncthreads();
    const int n = blockIdx.x*256 + t;
    const float x0 = pc[n], x1 = pc[NPTS+n], x2 = pc[2*NPTS+n];
    float h1[32];
    #pragma unroll
    for (int o=0;o<32;++o)
        h1[o] = lrelu(B1[o] + W1[o*3]*x0 + W1[o*3+1]*x1 + W1[o*3+2]*x2);
    float h2[32];
    #pragma unroll
    for (int o=0;o<32;++o){
        float a = B2[o];
        #pragma unroll
        for (int c=0;c<32;++c) a += W2s[o*32+c]*h1[c];
        h2[o] = lrelu(a);
    }
    float* row = pfeat + (size_t)n*68;
    *(float4*)row = make_float4(el[n], el[NPTS+n], el[2*NPTS+n], el[3*NPTS+n]);
    #pragma unroll
    for (int o4=0;o4<16;++o4){
        float tmp[4];
        #pragma unroll
        for (int q=0;q<4;++q){
            const int o = o4*4+q;
            float a = B3[o];
            #pragma unroll
            for (int c=0;c<32;++c) a += W3s[o*32+c]*h2[c];
            tmp[q] = lrelu(a);
        }
        *(float4*)(row + 4 + o4*4) = make_float4(tmp[0],tmp[1],tmp[2],tmp[3]);
    }
}

// ---------------------------------------------------------------- splat (scatter-add)
__global__ void splat_kernel(const float* __restrict__ pfeat, const float* __restrict__ bary,
                             const int* __restrict__ off, float* __restrict__ lat){
    const int tid = blockIdx.x*256 + threadIdx.x;   // tid = j*NPTS + n,  j<5
    const int n = tid & (NPTS-1);
    const float b = bary[tid];
    const int o = off[tid];
    const float* row = pfeat + (size_t)n*68;
    float* dst = lat + (size_t)o*68;
    #pragma unroll 4
    for (int c=0;c<68;++c) unsafeAtomicAdd(&dst[c], b*row[c]);
}

// ---------------------------------------------------------------- blur_s: 64x(68*15) gathered GEMM + fused sw2
// G staged [row 64][stride 96] with c-quad XOR swizzle; Wl [68][64]; out: 64 h x 64 o
__global__ __launch_bounds__(256) void blur_s_kernel(
        const float* __restrict__ lat, const int* __restrict__ nb,
        const float* __restrict__ sw1t, const float* __restrict__ sb1,
        const float* __restrict__ sw2T, const float* __restrict__ sb2,
        float* __restrict__ outp, int ostride){
    __shared__ __align__(16) float GT[6144];   // G[64][96]; epilogue T[64][68]=4352
    __shared__ __align__(16) float WW[4352];   // Wl[68][64]; epilogue W2T[64][64]=4096
    __shared__ int sidx[2][64];
    const int t = threadIdx.x;
    const int hb = blockIdx.x*64;
    const int oq = t>>4, hq = t&15;        // gemm: o=oq*4, h=hq*4
    const int lane16 = t&15, rgrp = t>>4;  // staging
    float bs1[4], bs2[4];
    #pragma unroll
    for (int i=0;i<4;++i){ bs1[i]=sb1[oq*4+i]; bs2[i]=sb2[oq*4+i]; }
    if (t<64) sidx[0][t] = nb[hb + t];
    __syncthreads();
    float acc[4][4] = {};
    for (int nn=0; nn<NNB; ++nn){
        const int cur = nn&1;
        #pragma unroll
        for (int i=0;i<4;++i){
            const int row = rgrp + 16*i;
            const float* src = lat + (size_t)sidx[cur][row]*68;
            const float4 v = *(const float4*)(src + lane16*4);
            const int qs = lane16 ^ ((row>>2)&7);
            *(float4*)(GT + row*96 + qs*4) = v;
        }
        if (t<64){
            const int row = t;
            const float4 v = *(const float4*)(lat + (size_t)sidx[cur][row]*68 + 64);
            const int qs = 16 ^ ((row>>2)&7);
            *(float4*)(GT + row*96 + qs*4) = v;
        }
        for (int e=t; e<1088; e+=256)
            *(float4*)(WW + e*4) = *(const float4*)(sw1t + nn*4352 + e*4);
        if (t<64 && nn+1<NNB) sidx[(nn+1)&1][t] = nb[(nn+1)*HL + hb + t];
        __syncthreads();
        for (int q=0;q<17;++q){
            float a[4][4];  // a[cc][j]
            const int qs = q ^ (hq&7);
            #pragma unroll
            for (int j=0;j<4;++j){
                const float4 v = *(const float4*)(GT + (hq*4+j)*96 + qs*4);
                a[0][j]=v.x; a[1][j]=v.y; a[2][j]=v.z; a[3][j]=v.w;
            }
            #pragma unroll
            for (int cc=0;cc<4;++cc){
                const float4 w = *(const float4*)(WW + (q*4+cc)*64 + oq*4);
                const float wv[4] = {w.x,w.y,w.z,w.w};
                #pragma unroll
                for (int i=0;i<4;++i)
                    #pragma unroll
                    for (int j=0;j<4;++j)
                        acc[i][j] = fmaf(wv[i], a[cc][j], acc[i][j]);
            }
        }
        __syncthreads();
    }
    // epilogue: T = lrelu(acc+sb1)  (T[o][68] in GT area), W2T in WW area
    #pragma unroll
    for (int i=0;i<4;++i){
        float4 v = make_float4(lrelu(acc[i][0]+bs1[i]), lrelu(acc[i][1]+bs1[i]),
                               lrelu(acc[i][2]+bs1[i]), lrelu(acc[i][3]+bs1[i]));
        *(float4*)(GT + (oq*4+i)*68 + hq*4) = v;
    }
    for (int e=t;e<1024;e+=256)
        *(float4*)(WW + e*4) = *(const float4*)(sw2T + e*4);
    __syncthreads();
    float acc2[4][4] = {};
    #pragma unroll 4
    for (int c=0;c<64;++c){
        const float4 a4 = *(const float4*)(GT + c*68 + hq*4);
        const float4 w4 = *(const float4*)(WW + c*64 + oq*4);
        const float av[4]={a4.x,a4.y,a4.z,a4.w};
        const float wv[4]={w4.x,w4.y,w4.z,w4.w};
        #pragma unroll
        for (int i=0;i<4;++i)
            #pragma unroll
            for (int j=0;j<4;++j)
                acc2[i][j] = fmaf(wv[i], av[j], acc2[i][j]);
    }
    #pragma unroll
    for (int j=0;j<4;++j){
        const int h = hb + hq*4 + j;
        float4 v = make_float4(lrelu(acc2[0][j]+bs2[0]), lrelu(acc2[1][j]+bs2[1]),
                               lrelu(acc2[2][j]+bs2[2]), lrelu(acc2[3][j]+bs2[3]));
        *(float4*)(outp + (size_t)h*ostride + oq*4) = v;
    }
}

// ---------------------------------------------------------------- corr + d-MLP (GEMM-structured)
// block: 128 h, 256 threads. Per k: stage prod[c][h] -> GEMM1(cw1) -> GEMM2(cw2) -> agg
__global__ __launch_bounds__(256) void corr_kernel(
        float* __restrict__ cat, const float* __restrict__ lat2, const int* __restrict__ ci,
        const float* __restrict__ cw1T, const float* __restrict__ cb1,
        const float* __restrict__ cw2T, const float* __restrict__ cb2,
        const float* __restrict__ dw1T, const float* __restrict__ db1,
        const float* __restrict__ dw2T, const float* __restrict__ db2){
    __shared__ __align__(16) float PROD[8448];  // [64][132]; epilogue D1[64][132]
    __shared__ __align__(16) float M1[4224];    // [32][132]; epilogue DW2T[64][64]
    __shared__ __align__(16) float W1s[2048];   // CW1T[64][32]; epilogue DW1T[32][64]
    __shared__ __align__(16) float W2s[1024];   // CW2T[32][32]
    __shared__ int sidx[2][128];
    const int t = threadIdx.x;
    const int hb = blockIdx.x*128;
    const int oq = t>>5, hq = t&31;        // gemm: o=oq*4 (32), h=hq*4 (128)
    const int lane16 = t&15, rgrp = t>>4;  // staging: rows rgrp+16i
    for (int e=t;e<512;e+=256) *(float4*)(W1s+e*4) = *(const float4*)(cw1T+e*4);
    if (t<256 && t<256){ if (t<256){} }
    for (int e=t;e<256;e+=256) *(float4*)(W2s+e*4) = *(const float4*)(cw2T+e*4);
    float l1r[8][4];
    #pragma unroll
    for (int i=0;i<8;++i){
        const int h = hb + rgrp + 16*i;
        const float4 v = *(const float4*)(cat + (size_t)h*128 + lane16*4);
        l1r[i][0]=v.x; l1r[i][1]=v.y; l1r[i][2]=v.z; l1r[i][3]=v.w;
    }
    float bc1[4], bc2[4];
    #pragma unroll
    for (int i=0;i<4;++i){ bc1[i]=cb1[oq*4+i]; bc2[i]=cb2[oq*4+i]; }
    if (t<128) sidx[0][t] = ci[hb+t];
    __syncthreads();
    float agg[4][4] = {};
    for (int k=0;k<KC;++k){
        const int cur = k&1;
        #pragma unroll
        for (int i=0;i<8;++i){
            const int row = rgrp + 16*i;
            const float4 g = *(const float4*)(lat2 + (size_t)sidx[cur][row]*64 + lane16*4);
            PROD[(lane16*4+0)*132 + row] = g.x * l1r[i][0];
            PROD[(lane16*4+1)*132 + row] = g.y * l1r[i][1];
            PROD[(lane16*4+2)*132 + row] = g.z * l1r[i][2];
            PROD[(lane16*4+3)*132 + row] = g.w * l1r[i][3];
        }
        if (t<128 && k+1<KC) sidx[(k+1)&1][t] = ci[(k+1)*HL + hb + t];
        __syncthreads();
        float a1[4][4] = {};
        #pragma unroll 8
        for (int c=0;c<64;++c){
            const float4 w = *(const float4*)(W1s + c*32 + oq*4);
            const float4 b = *(const float4*)(PROD + c*132 + hq*4);
            const float wv[4]={w.x,w.y,w.z,w.w};
            const float bv[4]={b.x,b.y,b.z,b.w};
            #pragma unroll
            for (int i=0;i<4;++i)
                #pragma unroll
                for (int j=0;j<4;++j)
                    a1[i][j] = fmaf(wv[i], bv[j], a1[i][j]);
        }
        #pragma unroll
        for (int i=0;i<4;++i){
            float4 v = make_float4(lrelu(a1[i][0]+bc1[i]), lrelu(a1[i][1]+bc1[i]),
                                   lrelu(a1[i][2]+bc1[i]), lrelu(a1[i][3]+bc1[i]));
            *(float4*)(M1 + (oq*4+i)*132 + hq*4) = v;
        }
        __syncthreads();
        float a2[4][4] = {};
        #pragma unroll 8
        for (int c=0;c<32;++c){
            const float4 w = *(const float4*)(W2s + c*32 + oq*4);
            const float4 b = *(const float4*)(M1 + c*132 + hq*4);
            const float wv[4]={w.x,w.y,w.z,w.w};
            const float bv[4]={b.x,b.y,b.z,b.w};
            #pragma unroll
            for (int i=0;i<4;++i)
                #pragma unroll
                for (int j=0;j<4;++j)
                    a2[i][j] = fmaf(wv[i], bv[j], a2[i][j]);
        }
        #pragma unroll
        for (int i=0;i<4;++i)
            #pragma unroll
            for (int j=0;j<4;++j)
                agg[i][j] += lrelu(a2[i][j]+bc2[i]);
    }
    // ---- d-MLP epilogue
    __syncthreads();
    const float s = 1.0f/32.0f;
    #pragma unroll
    for (int i=0;i<4;++i){
        float4 v = make_float4(agg[i][0]*s, agg[i][1]*s, agg[i][2]*s, agg[i][3]*s);
        *(float4*)(M1 + (oq*4+i)*132 + hq*4) = v;     // AGG
    }
    for (int e=t;e<512;e+=256) *(float4*)(W1s+e*4) = *(const float4*)(dw1T+e*4);
    __syncthreads();
    const int og = oq;   // 0..7, o = og*8
    float bd1[8];
    #pragma unroll
    for (int i=0;i<8;++i) bd1[i] = db1[og*8+i];
    float d1a[8][4] = {};
    #pragma unroll 4
    for (int c=0;c<32;++c){
        const float4 wa = *(const float4*)(W1s + c*64 + og*8);
        const float4 wb = *(const float4*)(W1s + c*64 + og*8 + 4);
        const float4 a  = *(const float4*)(M1 + c*132 + hq*4);
        const float wv[8]={wa.x,wa.y,wa.z,wa.w,wb.x,wb.y,wb.z,wb.w};
        const float av[4]={a.x,a.y,a.z,a.w};
        #pragma unroll
        for (int i=0;i<8;++i)
            #pragma unroll
            for (int j=0;j<4;++j)
                d1a[i][j] = fmaf(wv[i], av[j], d1a[i][j]);
    }
    __syncthreads();
    #pragma unroll
    for (int i=0;i<8;++i){
        float4 v = make_float4(lrelu(d1a[i][0]+bd1[i]), lrelu(d1a[i][1]+bd1[i]),
                               lrelu(d1a[i][2]+bd1[i]), lrelu(d1a[i][3]+bd1[i]));
        *(float4*)(PROD + (og*8+i)*132 + hq*4) = v;   // D1
    }
    for (int e=t;e<1024;e+=256) *(float4*)(M1+e*4) = *(const float4*)(dw2T+e*4); // DW2T
    __syncthreads();
    float bd2[8];
    #pragma unroll
    for (int i=0;i<8;++i) bd2[i] = db2[og*8+i];
    float d2a[8][4] = {};
    #pragma unroll 4
    for (int c=0;c<64;++c){
        const float4 wa = *(const float4*)(M1 + c*64 + og*8);
        const float4 wb = *(const float4*)(M1 + c*64 + og*8 + 4);
        const float4 a  = *(const float4*)(PROD + c*132 + hq*4);
        const float wv[8]={wa.x,wa.y,wa.z,wa.w,wb.x,wb.y,wb.z,wb.w};
        const float av[4]={a.x,a.y,a.z,a.w};
        #pragma unroll
        for (int i=0;i<8;++i)
            #pragma unroll
            for (int j=0;j<4;++j)
                d2a[i][j] = fmaf(wv[i], av[j], d2a[i][j]);
    }
    #pragma unroll
    for (int j=0;j<4;++j){
        const int h = hb + hq*4 + j;
        float* dst = cat + (size_t)h*128 + 64 + og*8;
        float4 v0 = make_float4(lrelu(d2a[0][j]+bd2[0]), lrelu(d2a[1][j]+bd2[1]),
                                lrelu(d2a[2][j]+bd2[2]), lrelu(d2a[3][j]+bd2[3]));
        float4 v1 = make_float4(lrelu(d2a[4][j]+bd2[4]), lrelu(d2a[5][j]+bd2[5]),
                                lrelu(d2a[6][j]+bd2[6]), lrelu(d2a[7][j]+bd2[7]));
        *(float4*)dst = v0;
        *(float4*)(dst+4) = v1;
    }
}

// ---------------------------------------------------------------- blur_p: 128x(128*15) gathered GEMM + fused pw2
__global__ __launch_bounds__(256) void blur_p_kernel(
        const float* __restrict__ cat, const int* __restrict__ nb,
        const float* __restrict__ pw1t, const float* __restrict__ pb1,
        const float* __restrict__ pw2T, const float* __restrict__ pb2,
        float* __restrict__ p){
    __shared__ __align__(16) float GT[8704];   // G[64][128]=8192; epilogue T[128][68]=8704
    __shared__ __align__(16) float WW[8192];   // Wl half [64][128] / W2T half [64][128]
    __shared__ int sidx[2][64];
    const int t = threadIdx.x;
    const int hb = blockIdx.x*64;
    const int oq8 = t>>4, hq = t&15;       // gemm: o=oq8*8 (128), h=hq*4 (64)
    const int q5 = t&31, rgrp5 = t>>5;     // staging: rows rgrp5+8i
    float bp1[8], bp2[8];
    #pragma unroll
    for (int i=0;i<8;++i){ bp1[i]=pb1[oq8*8+i]; bp2[i]=pb2[oq8*8+i]; }
    if (t<64) sidx[0][t] = nb[hb+t];
    __syncthreads();
    float acc[8][4] = {};
    for (int nn=0;nn<NNB;++nn){
        const int cur = nn&1;
        #pragma unroll
        for (int i=0;i<8;++i){
            const int row = rgrp5 + 8*i;
            const float* src = cat + (size_t)sidx[cur][row]*128;
            const float4 v = *(const float4*)(src + q5*4);
            const int qs = q5 ^ ((row>>2)&7);
            *(float4*)(GT + row*128 + qs*4) = v;
        }
        if (t<64 && nn+1<NNB) sidx[(nn+1)&1][t] = nb[(nn+1)*HL + hb+t];
        for (int e=t;e<2048;e+=256)
            *(float4*)(WW + e*4) = *(const float4*)(pw1t + nn*16384 + e*4);
        __syncthreads();
        #pragma unroll 1
        for (int ic=0; ic<2; ++ic){
            if (ic==1){
                __syncthreads();
                for (int e=t;e<2048;e+=256)
                    *(float4*)(WW + e*4) = *(const float4*)(pw1t + nn*16384 + 8192 + e*4);
                __syncthreads();
            }
            for (int q=0;q<16;++q){
                float a[4][4];  // a[cc][j]
                const int qs = (ic*16 + q) ^ (hq&7);
                #pragma unroll
                for (int j=0;j<4;++j){
                    const float4 v = *(const float4*)(GT + (hq*4+j)*128 + qs*4);
                    a[0][j]=v.x; a[1][j]=v.y; a[2][j]=v.z; a[3][j]=v.w;
                }
                #pragma unroll
                for (int cc=0;cc<4;++cc){
                    const float4 wa = *(const float4*)(WW + (q*4+cc)*128 + oq8*8);
                    const float4 wb = *(const float4*)(WW + (q*4+cc)*128 + oq8*8 + 4);
                    const float wv[8]={wa.x,wa.y,wa.z,wa.w,wb.x,wb.y,wb.z,wb.w};
                    #pragma unroll
                    for (int i=0;i<8;++i)
                        #pragma unroll
                        for (int j=0;j<4;++j)
                            acc[i][j] = fmaf(wv[i], a[cc][j], acc[i][j]);
                }
            }
            __syncthreads();
        }
    }
    // epilogue: T[o 128][68] = lrelu(acc+pb1)
    #pragma unroll
    for (int i=0;i<8;++i){
        const int o = oq8*8+i;
        float4 v = make_float4(lrelu(acc[i][0]+bp1[i]), lrelu(acc[i][1]+bp1[i]),
                               lrelu(acc[i][2]+bp1[i]), lrelu(acc[i][3]+bp1[i]));
        *(float4*)(GT + o*68 + hq*4) = v;
    }
    float acc2[8][4] = {};
    #pragma unroll 1
    for (int cc2=0;cc2<2;++cc2){
        __syncthreads();
        for (int e=t;e<2048;e+=256)
            *(float4*)(WW + e*4) = *(const float4*)(pw2T + cc2*8192 + e*4);
        __syncthreads();
        #pragma unroll 4
        for (int c=0;c<64;++c){
            const float4 a4 = *(const float4*)(GT + (cc2*64+c)*68 + hq*4);
            const float4 wa = *(const float4*)(WW + c*128 + oq8*8);
            const float4 wb = *(const float4*)(WW + c*128 + oq8*8 + 4);
            const float av[4]={a4.x,a4.y,a4.z,a4.w};
            const float wv[8]={wa.x,wa.y,wa.z,wa.w,wb.x,wb.y,wb.z,wb.w};
            #pragma unroll
            for (int i=0;i<8;++i)
                #pragma unroll
                for (int j=0;j<4;++j)
                    acc2[i][j] = fmaf(wv[i], av[j], acc2[i][j]);
        }
    }
    #pragma unroll
    for (int j=0;j<4;++j){
        const int h = hb + hq*4 + j;
        float* dst = p + (size_t)h*128 + oq8*8;
        float4 v0 = make_float4(lrelu(acc2[0][j]+bp2[0]), lrelu(acc2[1][j]+bp2[1]),
                                lrelu(acc2[2][j]+bp2[2]), lrelu(acc2[3][j]+bp2[3]));
        float4 v1 = make_float4(lrelu(acc2[4][j]+bp2[4]), lrelu(acc2[5][j]+bp2[5]),
                                lrelu(acc2[6][j]+bp2[6]), lrelu(acc2[7][j]+bp2[7]));
        *(float4*)dst = v0;
        *(float4*)(dst+4) = v1;
    }
}

// ---------------------------------------------------------------- head: slice + 128->128->64->3
// block: 64 points, 256 threads
__global__ __launch_bounds__(256) void head_kernel(
        const float* __restrict__ p, const float* __restrict__ bary, const int* __restrict__ off,
        const float* __restrict__ fw2T, const float* __restrict__ fb2,
        const float* __restrict__ fw3T, const float* __restrict__ fb3,
        const float* __restrict__ fw4, const float* __restrict__ fb4,
        float* __restrict__ out){
    __shared__ __align__(16) float S[8704];    // S[c 128][68]; then H1[128][68]; then H2[64][68]
    __shared__ __align__(16) float WW[8192];   // FW2T half [64][128] / FW3T [128][64]
    __shared__ float SB[5][64];
    __shared__ int   SO[5][64];
    const int t = threadIdx.x;
    const int pb = blockIdx.x*64;
    const int oq8 = t>>4, pq = t&15;      // gemm1: o=oq8*8 (128), p4=pq*4
    const int q5 = t&31, rgrp5 = t>>5;    // staging rows rgrp5+8i
    if (t<64){
        #pragma unroll
        for (int j=0;j<5;++j){ SB[j][t]=bary[j*NPTS+pb+t]; SO[j][t]=off[j*NPTS+pb+t]; }
    }
    __syncthreads();
    // stage S[c][pt] = sum_j bw*p[off_j]
    #pragma unroll
    for (int i=0;i<8;++i){
        const int row = rgrp5 + 8*i;
        float4 sa = make_float4(0.f,0.f,0.f,0.f);
        #pragma unroll
        for (int j=0;j<5;++j){
            const float4 v = *(const float4*)(p + (size_t)SO[j][row]*128 + q5*4);
            const float b = SB[j][row];
            sa.x += b*v.x; sa.y += b*v.y; sa.z += b*v.z; sa.w += b*v.w;
        }
        S[(q5*4+0)*68 + row] = sa.x;
        S[(q5*4+1)*68 + row] = sa.y;
        S[(q5*4+2)*68 + row] = sa.z;
        S[(q5*4+3)*68 + row] = sa.w;
    }
    float acc1[8][4] = {};
    #pragma unroll 1
    for (int hf=0;hf<2;++hf){
        if (hf==1) __syncthreads();
        for (int e=t;e<2048;e+=256)
            *(float4*)(WW + e*4) = *(const float4*)(fw2T + hf*8192 + e*4);
        __syncthreads();
        #pragma unroll 4
        for (int c=0;c<64;++c){
            const float4 a4 = *(const float4*)(S + (hf*64+c)*68 + pq*4);
            const float4 wa = *(const float4*)(WW + c*128 + oq8*8);
            const float4 wb = *(const float4*)(WW + c*128 + oq8*8 + 4);
            const float av[4]={a4.x,a4.y,a4.z,a4.w};
            const float wv[8]={wa.x,wa.y,wa.z,wa.w,wb.x,wb.y,wb.z,wb.w};
            #pragma unroll
            for (int i=0;i<8;++i)
                #pragma unroll
                for (int j=0;j<4;++j)
                    acc1[i][j] = fmaf(wv[i], av[j], acc1[i][j]);
        }
    }
    __syncthreads();
    // H1 -> S area; FW3T -> WW
    float bf2[8];
    #pragma unroll
    for (int i=0;i<8;++i) bf2[i]=fb2[oq8*8+i];
    #pragma unroll
    for (int i=0;i<8;++i){
        const int o = oq8*8+i;
        float4 v = make_float4(lrelu(acc1[i][0]+bf2[i]), lrelu(acc1[i][1]+bf2[i]),
                               lrelu(acc1[i][2]+bf2[i]), lrelu(acc1[i][3]+bf2[i]));
        *(float4*)(S + o*68 + pq*4) = v;
    }
    for (int e=t;e<2048;e+=256)
        *(float4*)(WW + e*4) = *(const float4*)(fw3T + e*4);
    __syncthreads();
    // gemm2: h2[64][64p], tile 4o x 4p
    const int od = t>>4;  // 0..15, o = od*4
    float bf3[4];
    #pragma unroll
    for (int i=0;i<4;++i) bf3[i]=fb3[od*4+i];
    float a2[4][4] = {};
    #pragma unroll 4
    for (int c=0;c<128;++c){
        const float4 a4 = *(const float4*)(S + c*68 + pq*4);
        const float4 w4 = *(const float4*)(WW + c*64 + od*4);
        const float av[4]={a4.x,a4.y,a4.z,a4.w};
        const float wv[4]={w4.x,w4.y,w4.z,w4.w};
        #pragma unroll
        for (int i=0;i<4;++i)
            #pragma unroll
            for (int j=0;j<4;++j)
                a2[i][j] = fmaf(wv[i], av[j], a2[i][j]);
    }
    __syncthreads();
    // H2 -> S area
    #pragma unroll
    for (int i=0;i<4;++i){
        float4 v = make_float4(lrelu(a2[i][0]+bf3[i]), lrelu(a2[i][1]+bf3[i]),
                               lrelu(a2[i][2]+bf3[i]), lrelu(a2[i][3]+bf3[i]));
        *(float4*)(S + (od*4+i)*68 + pq*4) = v;
    }
    __syncthreads();
    if (t < 192){
        const int r = t>>6, pp = t&63;
        float a = fb4[r];
        #pragma unroll 8
        for (int c=0;c<64;++c) a += fw4[r*64+c]*S[c*68+pp];
        out[r*NPTS + pb + pp] = a;
    }
}

// ================================================================ launch
extern "C" void kernel_launch(void* const* d_in, const int* in_sizes, int n_in,
                              void* d_out, int out_size, void* d_ws, size_t ws_size,
                              hipStream_t stream){
    const float* pc1   = (const float*)d_in[0];
    const float* pc2   = (const float*)d_in[1];
    const float* el1   = (const float*)d_in[2];
    const float* el2   = (const float*)d_in[3];
    const float* bary1 = (const float*)d_in[4];
    const float* bary2 = (const float*)d_in[5];
    const int*   off1  = (const int*)d_in[6];
    const int*   off2  = (const int*)d_in[7];
    const int*   nb1   = (const int*)d_in[8];
    const int*   nb2   = (const int*)d_in[9];
    const int*   ci    = (const int*)d_in[10];
    const float* w1    = (const float*)d_in[11];
    const float* b1    = (const float*)d_in[12];
    const float* w2    = (const float*)d_in[13];
    const float* b2    = (const float*)d_in[14];
    const float* w3    = (const float*)d_in[15];
    const float* b3    = (const float*)d_in[16];
    const float* sw1   = (const float*)d_in[17];
    const float* sb1   = (const float*)d_in[18];
    const float* sw2   = (const float*)d_in[19];
    const float* sb2   = (const float*)d_in[20];
    const float* cw1   = (const float*)d_in[21];
    const float* cb1   = (const float*)d_in[22];
    const float* cw2   = (const float*)d_in[23];
    const float* cb2   = (const float*)d_in[24];
    const float* dw1   = (const float*)d_in[25];
    const float* db1   = (const float*)d_in[26];
    const float* dw2   = (const float*)d_in[27];
    const float* db2   = (const float*)d_in[28];
    const float* pw1   = (const float*)d_in[29];
    const float* pb1   = (const float*)d_in[30];
    const float* pw2   = (const float*)d_in[31];
    const float* pb2   = (const float*)d_in[32];
    const float* fw2   = (const float*)d_in[33];
    const float* fb2   = (const float*)d_in[34];
    const float* fw3   = (const float*)d_in[35];
    const float* fb3   = (const float*)d_in[36];
    const float* fw4   = (const float*)d_in[37];
    const float* fb4   = (const float*)d_in[38];
    float* out = (float*)d_out;

    float* ws    = (float*)d_ws;
    float* pf1   = ws;                    // N*68
    float* pf2   = pf1   + 2228224;
    float* latA  = pf2   + 2228224;       // H*68
    float* latB  = latA  + 2228224;
    float* catb  = latB  + 2228224;       // H*128
    float* lat2p = catb  + 4194304;       // H*64
    float* sw1t  = lat2p + 2097152;       // 65280
    float* pw1t  = sw1t  + 65280;         // 245760
    float* sw2T  = pw1t  + 245760;        // 4096
    float* cw1T  = sw2T  + 4096;          // 2048
    float* cw2T  = cw1T  + 2048;          // 1024
    float* dw1T  = cw2T  + 1024;          // 2048
    float* dw2T  = dw1T  + 2048;          // 4096
    float* pw2T  = dw2T  + 4096;          // 16384
    float* fw2T  = pw2T  + 16384;         // 16384
    float* fw3T  = fw2T  + 16384;         // 8192
    float* pbuf  = pf1;                   // p (H*128) reuses pf1+pf2

    zero_kernel<<<4352, 256, 0, stream>>>((float4*)latA);
    repack_kernel<<<960, 256, 0, stream>>>(sw1, pw1, sw2, cw1, cw2, dw1, dw2, pw2, fw2, fw3,
                                           sw1t, pw1t, sw2T, cw1T, cw2T, dw1T, dw2T, pw2T, fw2T, fw3T);

    mlp3_kernel<<<128, 256, 0, stream>>>(pc1, el1, w1,b1,w2,b2,w3,b3, pf1);
    mlp3_kernel<<<128, 256, 0, stream>>>(pc2, el2, w1,b1,w2,b2,w3,b3, pf2);

    splat_kernel<<<640, 256, 0, stream>>>(pf1, bary1, off1, latA);
    splat_kernel<<<640, 256, 0, stream>>>(pf2, bary2, off2, latB);

    blur_s_kernel<<<512, 256, 0, stream>>>(latA, nb1, sw1t, sb1, sw2T, sb2, catb, 128);
    blur_s_kernel<<<512, 256, 0, stream>>>(latB, nb2, sw1t, sb1, sw2T, sb2, lat2p, 64);

    corr_kernel<<<256, 256, 0, stream>>>(catb, lat2p, ci, cw1T,cb1,cw2T,cb2,dw1T,db1,dw2T,db2);

    blur_p_kernel<<<512, 256, 0, stream>>>(catb, nb1, pw1t, pb1, pw2T, pb2, pbuf);

    head_kernel<<<512, 256, 0, stream>>>(pbuf, bary1, off1, fw2T,fb2,fw3T,fb3,fw4,fb4, out);
}

// Round 3
// 798.986 us; speedup vs baseline: 20.0505x; 2.3783x over previous
//
#include <hip/hip_runtime.h>

#define NPTS 32768
#define HL   32768
#define NNB  15
#define KC   32

__device__ __forceinline__ float lrelu(float x){ return x > 0.0f ? x : 0.1f*x; }

// ---------------------------------------------------------------- zero
__global__ void zero_kernel(float4* __restrict__ buf){
    buf[(size_t)blockIdx.x*256 + threadIdx.x] = make_float4(0.f,0.f,0.f,0.f);
}

// ---------------------------------------------------------------- repack weights (+ transposes)
__global__ void repack_kernel(const float* __restrict__ sw1, const float* __restrict__ pw1,
                              const float* __restrict__ sw2, const float* __restrict__ cw1,
                              const float* __restrict__ cw2, const float* __restrict__ dw1,
                              const float* __restrict__ dw2, const float* __restrict__ pw2,
                              const float* __restrict__ fw2, const float* __restrict__ fw3,
                              float* __restrict__ sw1t, float* __restrict__ pw1t,
                              float* __restrict__ sw2T, float* __restrict__ cw1T,
                              float* __restrict__ cw2T, float* __restrict__ dw1T,
                              float* __restrict__ dw2T, float* __restrict__ pw2T,
                              float* __restrict__ fw2T, float* __restrict__ fw3T){
    int tid = blockIdx.x*256 + threadIdx.x;
    if (tid < 65280){ int nn = tid/4352, r = tid%4352, i = r>>6, o = r&63;
        sw1t[tid] = sw1[(o*68+i)*15+nn]; }
    if (tid < 245760){ int nn = tid/16384, r = tid&16383, i = r>>7, o = r&127;
        pw1t[tid] = pw1[(o*128+i)*15+nn]; }
    if (tid < 4096){ int c = tid>>6, o = tid&63; sw2T[tid] = sw2[o*64+c]; }
    if (tid < 2048){ int c = tid>>5, o = tid&31; cw1T[tid] = cw1[o*64+c]; }
    if (tid < 1024){ int c = tid>>5, o = tid&31; cw2T[tid] = cw2[o*32+c]; }
    if (tid < 2048){ int c = tid>>6, o = tid&63; dw1T[tid] = dw1[o*32+c]; }
    if (tid < 4096){ int c = tid>>6, o = tid&63; dw2T[tid] = dw2[o*64+c]; }
    if (tid < 16384){ int c = tid>>7, o = tid&127; pw2T[tid] = pw2[o*128+c]; }
    if (tid < 16384){ int c = tid>>7, o = tid&127; fw2T[tid] = fw2[o*128+c]; }
    if (tid < 8192){ int c = tid>>6, o = tid&63; fw3T[tid] = fw3[o*128+c]; }
}

// ---------------------------------------------------------------- point MLP (3->32->32->64) + el pack
__global__ __launch_bounds__(256) void mlp3_kernel(
        const float* __restrict__ pc, const float* __restrict__ el,
        const float* __restrict__ w1, const float* __restrict__ b1,
        const float* __restrict__ w2, const float* __restrict__ b2,
        const float* __restrict__ w3, const float* __restrict__ b3,
        float* __restrict__ pfeat){
    __shared__ float W1[96], W2s[1024], W3s[2048], B1[32], B2[32], B3[64];
    const int t = threadIdx.x;
    for (int e=t;e<96;e+=256)   W1[e]=w1[e];
    for (int e=t;e<1024;e+=256) W2s[e]=w2[e];
    for (int e=t;e<2048;e+=256) W3s[e]=w3[e];
    if (t<32){ B1[t]=b1[t]; B2[t]=b2[t]; }
    if (t<64){ B3[t]=b3[t]; }
    __syncthreads();
    const int n = blockIdx.x*256 + t;
    const float x0 = pc[n], x1 = pc[NPTS+n], x2 = pc[2*NPTS+n];
    float h1[32];
    #pragma unroll
    for (int o=0;o<32;++o)
        h1[o] = lrelu(B1[o] + W1[o*3]*x0 + W1[o*3+1]*x1 + W1[o*3+2]*x2);
    float h2[32];
    #pragma unroll
    for (int o=0;o<32;++o){
        float a = B2[o];
        #pragma unroll
        for (int c=0;c<32;++c) a += W2s[o*32+c]*h1[c];
        h2[o] = lrelu(a);
    }
    float* row = pfeat + (size_t)n*68;
    *(float4*)row = make_float4(el[n], el[NPTS+n], el[2*NPTS+n], el[3*NPTS+n]);
    #pragma unroll
    for (int o4=0;o4<16;++o4){
        float tmp[4];
        #pragma unroll
        for (int q=0;q<4;++q){
            const int o = o4*4+q;
            float a = B3[o];
            #pragma unroll
            for (int c=0;c<32;++c) a += W3s[o*32+c]*h2[c];
            tmp[q] = lrelu(a);
        }
        *(float4*)(row + 4 + o4*4) = make_float4(tmp[0],tmp[1],tmp[2],tmp[3]);
    }
}

// ---------------------------------------------------------------- splat (scatter-add, wave-per-pair)
// one wave owns one (point, j) pair; lanes cover channels -> contiguous atomics
__global__ __launch_bounds__(256) void splat_kernel(
        const float* __restrict__ pfeat, const float* __restrict__ bary,
        const int* __restrict__ off, float* __restrict__ lat){
    const int pair = (blockIdx.x*256 + threadIdx.x) >> 6;   // 0 .. 5*NPTS-1
    const int lane = threadIdx.x & 63;
    const int n = pair & (NPTS-1);
    const int j = pair >> 15;
    const float b = bary[j*NPTS + n];
    const int o = off[j*NPTS + n];
    const float* row = pfeat + (size_t)n*68;
    float* dst = lat + (size_t)o*68;
    unsafeAtomicAdd(&dst[lane], b*row[lane]);
    if (lane < 4) unsafeAtomicAdd(&dst[64+lane], b*row[64+lane]);
}

// ---------------------------------------------------------------- blur_s: 64x(68*15) gathered GEMM + fused sw2
// G staged [row 64][stride 96] with c-quad XOR swizzle; Wl [68][64]; out: 64 h x 64 o
__global__ __launch_bounds__(256) void blur_s_kernel(
        const float* __restrict__ lat, const int* __restrict__ nb,
        const float* __restrict__ sw1t, const float* __restrict__ sb1,
        const float* __restrict__ sw2T, const float* __restrict__ sb2,
        float* __restrict__ outp, int ostride){
    __shared__ __align__(16) float GT[6144];   // G[64][96]; epilogue T[64][68]=4352
    __shared__ __align__(16) float WW[4352];   // Wl[68][64]; epilogue W2T[64][64]=4096
    __shared__ int sidx[2][64];
    const int t = threadIdx.x;
    const int hb = blockIdx.x*64;
    const int oq = t>>4, hq = t&15;        // gemm: o=oq*4, h=hq*4
    const int lane16 = t&15, rgrp = t>>4;  // staging
    float bs1[4], bs2[4];
    #pragma unroll
    for (int i=0;i<4;++i){ bs1[i]=sb1[oq*4+i]; bs2[i]=sb2[oq*4+i]; }
    if (t<64) sidx[0][t] = nb[hb + t];
    __syncthreads();
    float acc[4][4] = {};
    for (int nn=0; nn<NNB; ++nn){
        const int cur = nn&1;
        #pragma unroll
        for (int i=0;i<4;++i){
            const int row = rgrp + 16*i;
            const float* src = lat + (size_t)sidx[cur][row]*68;
            const float4 v = *(const float4*)(src + lane16*4);
            const int qs = lane16 ^ ((row>>2)&7);
            *(float4*)(GT + row*96 + qs*4) = v;
        }
        if (t<64){
            const int row = t;
            const float4 v = *(const float4*)(lat + (size_t)sidx[cur][row]*68 + 64);
            const int qs = 16 ^ ((row>>2)&7);
            *(float4*)(GT + row*96 + qs*4) = v;
        }
        for (int e=t; e<1088; e+=256)
            *(float4*)(WW + e*4) = *(const float4*)(sw1t + nn*4352 + e*4);
        if (t<64 && nn+1<NNB) sidx[(nn+1)&1][t] = nb[(nn+1)*HL + hb + t];
        __syncthreads();
        for (int q=0;q<17;++q){
            float a[4][4];  // a[cc][j]
            const int qs = q ^ (hq&7);
            #pragma unroll
            for (int j=0;j<4;++j){
                const float4 v = *(const float4*)(GT + (hq*4+j)*96 + qs*4);
                a[0][j]=v.x; a[1][j]=v.y; a[2][j]=v.z; a[3][j]=v.w;
            }
            #pragma unroll
            for (int cc=0;cc<4;++cc){
                const float4 w = *(const float4*)(WW + (q*4+cc)*64 + oq*4);
                const float wv[4] = {w.x,w.y,w.z,w.w};
                #pragma unroll
                for (int i=0;i<4;++i)
                    #pragma unroll
                    for (int j=0;j<4;++j)
                        acc[i][j] = fmaf(wv[i], a[cc][j], acc[i][j]);
            }
        }
        __syncthreads();
    }
    // epilogue: T = lrelu(acc+sb1)  (T[o][68] in GT area), W2T in WW area
    #pragma unroll
    for (int i=0;i<4;++i){
        float4 v = make_float4(lrelu(acc[i][0]+bs1[i]), lrelu(acc[i][1]+bs1[i]),
                               lrelu(acc[i][2]+bs1[i]), lrelu(acc[i][3]+bs1[i]));
        *(float4*)(GT + (oq*4+i)*68 + hq*4) = v;
    }
    for (int e=t;e<1024;e+=256)
        *(float4*)(WW + e*4) = *(const float4*)(sw2T + e*4);
    __syncthreads();
    float acc2[4][4] = {};
    #pragma unroll 4
    for (int c=0;c<64;++c){
        const float4 a4 = *(const float4*)(GT + c*68 + hq*4);
        const float4 w4 = *(const float4*)(WW + c*64 + oq*4);
        const float av[4]={a4.x,a4.y,a4.z,a4.w};
        const float wv[4]={w4.x,w4.y,w4.z,w4.w};
        #pragma unroll
        for (int i=0;i<4;++i)
            #pragma unroll
            for (int j=0;j<4;++j)
                acc2[i][j] = fmaf(wv[i], av[j], acc2[i][j]);
    }
    #pragma unroll
    for (int j=0;j<4;++j){
        const int h = hb + hq*4 + j;
        float4 v = make_float4(lrelu(acc2[0][j]+bs2[0]), lrelu(acc2[1][j]+bs2[1]),
                               lrelu(acc2[2][j]+bs2[2]), lrelu(acc2[3][j]+bs2[3]));
        *(float4*)(outp + (size_t)h*ostride + oq*4) = v;
    }
}

// ---------------------------------------------------------------- corr + d-MLP (GEMM-structured)
// block: 128 h, 256 threads. Per k: stage prod[c][h] -> GEMM1(cw1) -> GEMM2(cw2) -> agg
__global__ __launch_bounds__(256) void corr_kernel(
        float* __restrict__ cat, const float* __restrict__ lat2, const int* __restrict__ ci,
        const float* __restrict__ cw1T, const float* __restrict__ cb1,
        const float* __restrict__ cw2T, const float* __restrict__ cb2,
        const float* __restrict__ dw1T, const float* __restrict__ db1,
        const float* __restrict__ dw2T, const float* __restrict__ db2){
    __shared__ __align__(16) float PROD[8448];  // [64][132]; epilogue D1[64][132]
    __shared__ __align__(16) float M1[4224];    // [32][132]; epilogue DW2T[64][64]
    __shared__ __align__(16) float W1s[2048];   // CW1T[64][32]; epilogue DW1T[32][64]
    __shared__ __align__(16) float W2s[1024];   // CW2T[32][32]
    __shared__ int sidx[2][128];
    const int t = threadIdx.x;
    const int hb = blockIdx.x*128;
    const int oq = t>>5, hq = t&31;        // gemm: o=oq*4 (32), h=hq*4 (128)
    const int lane16 = t&15, rgrp = t>>4;  // staging: rows rgrp+16i
    for (int e=t;e<512;e+=256) *(float4*)(W1s+e*4) = *(const float4*)(cw1T+e*4);
    for (int e=t;e<256;e+=256) *(float4*)(W2s+e*4) = *(const float4*)(cw2T+e*4);
    float l1r[8][4];
    #pragma unroll
    for (int i=0;i<8;++i){
        const int h = hb + rgrp + 16*i;
        const float4 v = *(const float4*)(cat + (size_t)h*128 + lane16*4);
        l1r[i][0]=v.x; l1r[i][1]=v.y; l1r[i][2]=v.z; l1r[i][3]=v.w;
    }
    float bc1[4], bc2[4];
    #pragma unroll
    for (int i=0;i<4;++i){ bc1[i]=cb1[oq*4+i]; bc2[i]=cb2[oq*4+i]; }
    if (t<128) sidx[0][t] = ci[hb+t];
    __syncthreads();
    float agg[4][4] = {};
    for (int k=0;k<KC;++k){
        const int cur = k&1;
        #pragma unroll
        for (int i=0;i<8;++i){
            const int row = rgrp + 16*i;
            const float4 g = *(const float4*)(lat2 + (size_t)sidx[cur][row]*64 + lane16*4);
            PROD[(lane16*4+0)*132 + row] = g.x * l1r[i][0];
            PROD[(lane16*4+1)*132 + row] = g.y * l1r[i][1];
            PROD[(lane16*4+2)*132 + row] = g.z * l1r[i][2];
            PROD[(lane16*4+3)*132 + row] = g.w * l1r[i][3];
        }
        if (t<128 && k+1<KC) sidx[(k+1)&1][t] = ci[(k+1)*HL + hb + t];
        __syncthreads();
        float a1[4][4] = {};
        #pragma unroll 8
        for (int c=0;c<64;++c){
            const float4 w = *(const float4*)(W1s + c*32 + oq*4);
            const float4 b = *(const float4*)(PROD + c*132 + hq*4);
            const float wv[4]={w.x,w.y,w.z,w.w};
            const float bv[4]={b.x,b.y,b.z,b.w};
            #pragma unroll
            for (int i=0;i<4;++i)
                #pragma unroll
                for (int j=0;j<4;++j)
                    a1[i][j] = fmaf(wv[i], bv[j], a1[i][j]);
        }
        #pragma unroll
        for (int i=0;i<4;++i){
            float4 v = make_float4(lrelu(a1[i][0]+bc1[i]), lrelu(a1[i][1]+bc1[i]),
                                   lrelu(a1[i][2]+bc1[i]), lrelu(a1[i][3]+bc1[i]));
            *(float4*)(M1 + (oq*4+i)*132 + hq*4) = v;
        }
        __syncthreads();
        float a2[4][4] = {};
        #pragma unroll 8
        for (int c=0;c<32;++c){
            const float4 w = *(const float4*)(W2s + c*32 + oq*4);
            const float4 b = *(const float4*)(M1 + c*132 + hq*4);
            const float wv[4]={w.x,w.y,w.z,w.w};
            const float bv[4]={b.x,b.y,b.z,b.w};
            #pragma unroll
            for (int i=0;i<4;++i)
                #pragma unroll
                for (int j=0;j<4;++j)
                    a2[i][j] = fmaf(wv[i], bv[j], a2[i][j]);
        }
        #pragma unroll
        for (int i=0;i<4;++i)
            #pragma unroll
            for (int j=0;j<4;++j)
                agg[i][j] += lrelu(a2[i][j]+bc2[i]);
    }
    // ---- d-MLP epilogue
    __syncthreads();
    const float s = 1.0f/32.0f;
    #pragma unroll
    for (int i=0;i<4;++i){
        float4 v = make_float4(agg[i][0]*s, agg[i][1]*s, agg[i][2]*s, agg[i][3]*s);
        *(float4*)(M1 + (oq*4+i)*132 + hq*4) = v;     // AGG
    }
    for (int e=t;e<512;e+=256) *(float4*)(W1s+e*4) = *(const float4*)(dw1T+e*4);
    __syncthreads();
    const int og = oq;   // 0..7, o = og*8
    float bd1[8];
    #pragma unroll
    for (int i=0;i<8;++i) bd1[i] = db1[og*8+i];
    float d1a[8][4] = {};
    #pragma unroll 4
    for (int c=0;c<32;++c){
        const float4 wa = *(const float4*)(W1s + c*64 + og*8);
        const float4 wb = *(const float4*)(W1s + c*64 + og*8 + 4);
        const float4 a  = *(const float4*)(M1 + c*132 + hq*4);
        const float wv[8]={wa.x,wa.y,wa.z,wa.w,wb.x,wb.y,wb.z,wb.w};
        const float av[4]={a.x,a.y,a.z,a.w};
        #pragma unroll
        for (int i=0;i<8;++i)
            #pragma unroll
            for (int j=0;j<4;++j)
                d1a[i][j] = fmaf(wv[i], av[j], d1a[i][j]);
    }
    __syncthreads();
    #pragma unroll
    for (int i=0;i<8;++i){
        float4 v = make_float4(lrelu(d1a[i][0]+bd1[i]), lrelu(d1a[i][1]+bd1[i]),
                               lrelu(d1a[i][2]+bd1[i]), lrelu(d1a[i][3]+bd1[i]));
        *(float4*)(PROD + (og*8+i)*132 + hq*4) = v;   // D1
    }
    for (int e=t;e<1024;e+=256) *(float4*)(M1+e*4) = *(const float4*)(dw2T+e*4); // DW2T
    __syncthreads();
    float bd2[8];
    #pragma unroll
    for (int i=0;i<8;++i) bd2[i] = db2[og*8+i];
    float d2a[8][4] = {};
    #pragma unroll 4
    for (int c=0;c<64;++c){
        const float4 wa = *(const float4*)(M1 + c*64 + og*8);
        const float4 wb = *(const float4*)(M1 + c*64 + og*8 + 4);
        const float4 a  = *(const float4*)(PROD + c*132 + hq*4);
        const float wv[8]={wa.x,wa.y,wa.z,wa.w,wb.x,wb.y,wb.z,wb.w};
        const float av[4]={a.x,a.y,a.z,a.w};
        #pragma unroll
        for (int i=0;i<8;++i)
            #pragma unroll
            for (int j=0;j<4;++j)
                d2a[i][j] = fmaf(wv[i], av[j], d2a[i][j]);
    }
    #pragma unroll
    for (int j=0;j<4;++j){
        const int h = hb + hq*4 + j;
        float* dst = cat + (size_t)h*128 + 64 + og*8;
        float4 v0 = make_float4(lrelu(d2a[0][j]+bd2[0]), lrelu(d2a[1][j]+bd2[1]),
                                lrelu(d2a[2][j]+bd2[2]), lrelu(d2a[3][j]+bd2[3]));
        float4 v1 = make_float4(lrelu(d2a[4][j]+bd2[4]), lrelu(d2a[5][j]+bd2[5]),
                                lrelu(d2a[6][j]+bd2[6]), lrelu(d2a[7][j]+bd2[7]));
        *(float4*)dst = v0;
        *(float4*)(dst+4) = v1;
    }
}

// ---------------------------------------------------------------- blur_p: 128x(128*15) gathered GEMM + fused pw2
__global__ __launch_bounds__(256) void blur_p_kernel(
        const float* __restrict__ cat, const int* __restrict__ nb,
        const float* __restrict__ pw1t, const float* __restrict__ pb1,
        const float* __restrict__ pw2T, const float* __restrict__ pb2,
        float* __restrict__ p){
    __shared__ __align__(16) float GT[8704];   // G[64][128]=8192; epilogue T[128][68]=8704
    __shared__ __align__(16) float WW[8192];   // Wl half [64][128] / W2T half [64][128]
    __shared__ int sidx[2][64];
    const int t = threadIdx.x;
    const int hb = blockIdx.x*64;
    const int oq8 = t>>4, hq = t&15;       // gemm: o=oq8*8 (128), h=hq*4 (64)
    const int q5 = t&31, rgrp5 = t>>5;     // staging: rows rgrp5+8i
    float bp1[8], bp2[8];
    #pragma unroll
    for (int i=0;i<8;++i){ bp1[i]=pb1[oq8*8+i]; bp2[i]=pb2[oq8*8+i]; }
    if (t<64) sidx[0][t] = nb[hb+t];
    __syncthreads();
    float acc[8][4] = {};
    for (int nn=0;nn<NNB;++nn){
        const int cur = nn&1;
        #pragma unroll
        for (int i=0;i<8;++i){
            const int row = rgrp5 + 8*i;
            const float* src = cat + (size_t)sidx[cur][row]*128;
            const float4 v = *(const float4*)(src + q5*4);
            const int qs = q5 ^ ((row>>2)&7);
            *(float4*)(GT + row*128 + qs*4) = v;
        }
        if (t<64 && nn+1<NNB) sidx[(nn+1)&1][t] = nb[(nn+1)*HL + hb+t];
        for (int e=t;e<2048;e+=256)
            *(float4*)(WW + e*4) = *(const float4*)(pw1t + nn*16384 + e*4);
        __syncthreads();
        #pragma unroll 1
        for (int ic=0; ic<2; ++ic){
            if (ic==1){
                __syncthreads();
                for (int e=t;e<2048;e+=256)
                    *(float4*)(WW + e*4) = *(const float4*)(pw1t + nn*16384 + 8192 + e*4);
                __syncthreads();
            }
            for (int q=0;q<16;++q){
                float a[4][4];  // a[cc][j]
                const int qs = (ic*16 + q) ^ (hq&7);
                #pragma unroll
                for (int j=0;j<4;++j){
                    const float4 v = *(const float4*)(GT + (hq*4+j)*128 + qs*4);
                    a[0][j]=v.x; a[1][j]=v.y; a[2][j]=v.z; a[3][j]=v.w;
                }
                #pragma unroll
                for (int cc=0;cc<4;++cc){
                    const float4 wa = *(const float4*)(WW + (q*4+cc)*128 + oq8*8);
                    const float4 wb = *(const float4*)(WW + (q*4+cc)*128 + oq8*8 + 4);
                    const float wv[8]={wa.x,wa.y,wa.z,wa.w,wb.x,wb.y,wb.z,wb.w};
                    #pragma unroll
                    for (int i=0;i<8;++i)
                        #pragma unroll
                        for (int j=0;j<4;++j)
                            acc[i][j] = fmaf(wv[i], a[cc][j], acc[i][j]);
                }
            }
            __syncthreads();
        }
    }
    // epilogue: T[o 128][68] = lrelu(acc+pb1)
    #pragma unroll
    for (int i=0;i<8;++i){
        const int o = oq8*8+i;
        float4 v = make_float4(lrelu(acc[i][0]+bp1[i]), lrelu(acc[i][1]+bp1[i]),
                               lrelu(acc[i][2]+bp1[i]), lrelu(acc[i][3]+bp1[i]));
        *(float4*)(GT + o*68 + hq*4) = v;
    }
    float acc2[8][4] = {};
    #pragma unroll 1
    for (int cc2=0;cc2<2;++cc2){
        __syncthreads();
        for (int e=t;e<2048;e+=256)
            *(float4*)(WW + e*4) = *(const float4*)(pw2T + cc2*8192 + e*4);
        __syncthreads();
        #pragma unroll 4
        for (int c=0;c<64;++c){
            const float4 a4 = *(const float4*)(GT + (cc2*64+c)*68 + hq*4);
            const float4 wa = *(const float4*)(WW + c*128 + oq8*8);
            const float4 wb = *(const float4*)(WW + c*128 + oq8*8 + 4);
            const float av[4]={a4.x,a4.y,a4.z,a4.w};
            const float wv[8]={wa.x,wa.y,wa.z,wa.w,wb.x,wb.y,wb.z,wb.w};
            #pragma unroll
            for (int i=0;i<8;++i)
                #pragma unroll
                for (int j=0;j<4;++j)
                    acc2[i][j] = fmaf(wv[i], av[j], acc2[i][j]);
        }
    }
    #pragma unroll
    for (int j=0;j<4;++j){
        const int h = hb + hq*4 + j;
        float* dst = p + (size_t)h*128 + oq8*8;
        float4 v0 = make_float4(lrelu(acc2[0][j]+bp2[0]), lrelu(acc2[1][j]+bp2[1]),
                                lrelu(acc2[2][j]+bp2[2]), lrelu(acc2[3][j]+bp2[3]));
        float4 v1 = make_float4(lrelu(acc2[4][j]+bp2[4]), lrelu(acc2[5][j]+bp2[5]),
                                lrelu(acc2[6][j]+bp2[6]), lrelu(acc2[7][j]+bp2[7]));
        *(float4*)dst = v0;
        *(float4*)(dst+4) = v1;
    }
}

// ---------------------------------------------------------------- head: slice + 128->128->64->3
// block: 64 points, 256 threads
__global__ __launch_bounds__(256) void head_kernel(
        const float* __restrict__ p, const float* __restrict__ bary, const int* __restrict__ off,
        const float* __restrict__ fw2T, const float* __restrict__ fb2,
        const float* __restrict__ fw3T, const float* __restrict__ fb3,
        const float* __restrict__ fw4, const float* __restrict__ fb4,
        float* __restrict__ out){
    __shared__ __align__(16) float S[8704];    // S[c 128][68]; then H1[128][68]; then H2[64][68]
    __shared__ __align__(16) float WW[8192];   // FW2T half [64][128] / FW3T [128][64]
    __shared__ float SB[5][64];
    __shared__ int   SO[5][64];
    const int t = threadIdx.x;
    const int pb = blockIdx.x*64;
    const int oq8 = t>>4, pq = t&15;      // gemm1: o=oq8*8 (128), p4=pq*4
    const int q5 = t&31, rgrp5 = t>>5;    // staging rows rgrp5+8i
    if (t<64){
        #pragma unroll
        for (int j=0;j<5;++j){ SB[j][t]=bary[j*NPTS+pb+t]; SO[j][t]=off[j*NPTS+pb+t]; }
    }
    __syncthreads();
    // stage S[c][pt] = sum_j bw*p[off_j]
    #pragma unroll
    for (int i=0;i<8;++i){
        const int row = rgrp5 + 8*i;
        float4 sa = make_float4(0.f,0.f,0.f,0.f);
        #pragma unroll
        for (int j=0;j<5;++j){
            const float4 v = *(const float4*)(p + (size_t)SO[j][row]*128 + q5*4);
            const float b = SB[j][row];
            sa.x += b*v.x; sa.y += b*v.y; sa.z += b*v.z; sa.w += b*v.w;
        }
        S[(q5*4+0)*68 + row] = sa.x;
        S[(q5*4+1)*68 + row] = sa.y;
        S[(q5*4+2)*68 + row] = sa.z;
        S[(q5*4+3)*68 + row] = sa.w;
    }
    float acc1[8][4] = {};
    #pragma unroll 1
    for (int hf=0;hf<2;++hf){
        if (hf==1) __syncthreads();
        for (int e=t;e<2048;e+=256)
            *(float4*)(WW + e*4) = *(const float4*)(fw2T + hf*8192 + e*4);
        __syncthreads();
        #pragma unroll 4
        for (int c=0;c<64;++c){
            const float4 a4 = *(const float4*)(S + (hf*64+c)*68 + pq*4);
            const float4 wa = *(const float4*)(WW + c*128 + oq8*8);
            const float4 wb = *(const float4*)(WW + c*128 + oq8*8 + 4);
            const float av[4]={a4.x,a4.y,a4.z,a4.w};
            const float wv[8]={wa.x,wa.y,wa.z,wa.w,wb.x,wb.y,wb.z,wb.w};
            #pragma unroll
            for (int i=0;i<8;++i)
                #pragma unroll
                for (int j=0;j<4;++j)
                    acc1[i][j] = fmaf(wv[i], av[j], acc1[i][j]);
        }
    }
    __syncthreads();
    // H1 -> S area; FW3T -> WW
    float bf2[8];
    #pragma unroll
    for (int i=0;i<8;++i) bf2[i]=fb2[oq8*8+i];
    #pragma unroll
    for (int i=0;i<8;++i){
        const int o = oq8*8+i;
        float4 v = make_float4(lrelu(acc1[i][0]+bf2[i]), lrelu(acc1[i][1]+bf2[i]),
                               lrelu(acc1[i][2]+bf2[i]), lrelu(acc1[i][3]+bf2[i]));
        *(float4*)(S + o*68 + pq*4) = v;
    }
    for (int e=t;e<2048;e+=256)
        *(float4*)(WW + e*4) = *(const float4*)(fw3T + e*4);
    __syncthreads();
    // gemm2: h2[64][64p], tile 4o x 4p
    const int od = t>>4;  // 0..15, o = od*4
    float bf3[4];
    #pragma unroll
    for (int i=0;i<4;++i) bf3[i]=fb3[od*4+i];
    float a2[4][4] = {};
    #pragma unroll 4
    for (int c=0;c<128;++c){
        const float4 a4 = *(const float4*)(S + c*68 + pq*4);
        const float4 w4 = *(const float4*)(WW + c*64 + od*4);
        const float av[4]={a4.x,a4.y,a4.z,a4.w};
        const float wv[4]={w4.x,w4.y,w4.z,w4.w};
        #pragma unroll
        for (int i=0;i<4;++i)
            #pragma unroll
            for (int j=0;j<4;++j)
                a2[i][j] = fmaf(wv[i], av[j], a2[i][j]);
    }
    __syncthreads();
    // H2 -> S area
    #pragma unroll
    for (int i=0;i<4;++i){
        float4 v = make_float4(lrelu(a2[i][0]+bf3[i]), lrelu(a2[i][1]+bf3[i]),
                               lrelu(a2[i][2]+bf3[i]), lrelu(a2[i][3]+bf3[i]));
        *(float4*)(S + (od*4+i)*68 + pq*4) = v;
    }
    __syncthreads();
    if (t < 192){
        const int r = t>>6, pp = t&63;
        float a = fb4[r];
        #pragma unroll 8
        for (int c=0;c<64;++c) a += fw4[r*64+c]*S[c*68+pp];
        out[r*NPTS + pb + pp] = a;
    }
}

// ================================================================ launch
extern "C" void kernel_launch(void* const* d_in, const int* in_sizes, int n_in,
                              void* d_out, int out_size, void* d_ws, size_t ws_size,
                              hipStream_t stream){
    const float* pc1   = (const float*)d_in[0];
    const float* pc2   = (const float*)d_in[1];
    const float* el1   = (const float*)d_in[2];
    const float* el2   = (const float*)d_in[3];
    const float* bary1 = (const float*)d_in[4];
    const float* bary2 = (const float*)d_in[5];
    const int*   off1  = (const int*)d_in[6];
    const int*   off2  = (const int*)d_in[7];
    const int*   nb1   = (const int*)d_in[8];
    const int*   nb2   = (const int*)d_in[9];
    const int*   ci    = (const int*)d_in[10];
    const float* w1    = (const float*)d_in[11];
    const float* b1    = (const float*)d_in[12];
    const float* w2    = (const float*)d_in[13];
    const float* b2    = (const float*)d_in[14];
    const float* w3    = (const float*)d_in[15];
    const float* b3    = (const float*)d_in[16];
    const float* sw1   = (const float*)d_in[17];
    const float* sb1   = (const float*)d_in[18];
    const float* sw2   = (const float*)d_in[19];
    const float* sb2   = (const float*)d_in[20];
    const float* cw1   = (const float*)d_in[21];
    const float* cb1   = (const float*)d_in[22];
    const float* cw2   = (const float*)d_in[23];
    const float* cb2   = (const float*)d_in[24];
    const float* dw1   = (const float*)d_in[25];
    const float* db1   = (const float*)d_in[26];
    const float* dw2   = (const float*)d_in[27];
    const float* db2   = (const float*)d_in[28];
    const float* pw1   = (const float*)d_in[29];
    const float* pb1   = (const float*)d_in[30];
    const float* pw2   = (const float*)d_in[31];
    const float* pb2   = (const float*)d_in[32];
    const float* fw2   = (const float*)d_in[33];
    const float* fb2   = (const float*)d_in[34];
    const float* fw3   = (const float*)d_in[35];
    const float* fb3   = (const float*)d_in[36];
    const float* fw4   = (const float*)d_in[37];
    const float* fb4   = (const float*)d_in[38];
    float* out = (float*)d_out;

    float* ws    = (float*)d_ws;
    float* pf1   = ws;                    // N*68
    float* pf2   = pf1   + 2228224;
    float* latA  = pf2   + 2228224;       // H*68
    float* latB  = latA  + 2228224;
    float* catb  = latB  + 2228224;       // H*128
    float* lat2p = catb  + 4194304;       // H*64
    float* sw1t  = lat2p + 2097152;       // 65280
    float* pw1t  = sw1t  + 65280;         // 245760
    float* sw2T  = pw1t  + 245760;        // 4096
    float* cw1T  = sw2T  + 4096;          // 2048
    float* cw2T  = cw1T  + 2048;          // 1024
    float* dw1T  = cw2T  + 1024;          // 2048
    float* dw2T  = dw1T  + 2048;          // 4096
    float* pw2T  = dw2T  + 4096;          // 16384
    float* fw2T  = pw2T  + 16384;         // 16384
    float* fw3T  = fw2T  + 16384;         // 8192
    float* pbuf  = pf1;                   // p (H*128) reuses pf1+pf2

    zero_kernel<<<4352, 256, 0, stream>>>((float4*)latA);
    repack_kernel<<<960, 256, 0, stream>>>(sw1, pw1, sw2, cw1, cw2, dw1, dw2, pw2, fw2, fw3,
                                           sw1t, pw1t, sw2T, cw1T, cw2T, dw1T, dw2T, pw2T, fw2T, fw3T);

    mlp3_kernel<<<128, 256, 0, stream>>>(pc1, el1, w1,b1,w2,b2,w3,b3, pf1);
    mlp3_kernel<<<128, 256, 0, stream>>>(pc2, el2, w1,b1,w2,b2,w3,b3, pf2);

    // wave-per-pair splat: 5*NPTS pairs, 4 pairs per 256-thread block
    splat_kernel<<<40960, 256, 0, stream>>>(pf1, bary1, off1, latA);
    splat_kernel<<<40960, 256, 0, stream>>>(pf2, bary2, off2, latB);

    blur_s_kernel<<<512, 256, 0, stream>>>(latA, nb1, sw1t, sb1, sw2T, sb2, catb, 128);
    blur_s_kernel<<<512, 256, 0, stream>>>(latB, nb2, sw1t, sb1, sw2T, sb2, lat2p, 64);

    corr_kernel<<<256, 256, 0, stream>>>(catb, lat2p, ci, cw1T,cb1,cw2T,cb2,dw1T,db1,dw2T,db2);

    blur_p_kernel<<<512, 256, 0, stream>>>(catb, nb1, pw1t, pb1, pw2T, pb2, pbuf);

    head_kernel<<<512, 256, 0, stream>>>(pbuf, bary1, off1, fw2T,fb2,fw3T,fb3,fw4,fb4, out);
}

// Round 4
// 638.161 us; speedup vs baseline: 25.1035x; 1.2520x over previous
//
#include <hip/hip_runtime.h>

#define NPTS 32768
#define HL   32768
#define NNB  15
#define KC   32

typedef __attribute__((ext_vector_type(8))) short s16x8;
typedef __attribute__((ext_vector_type(4))) float f32x4;

__device__ __forceinline__ float lrelu(float x){ return x > 0.0f ? x : 0.1f*x; }

// round-to-nearest-even bf16 split: x ~= hi + lo
__device__ __forceinline__ void bf16_hilo(float x, unsigned short& hi, unsigned short& lo){
    union { float f; unsigned u; } a; a.f = x;
    unsigned r = a.u + 0x7FFF + ((a.u >> 16) & 1);
    hi = (unsigned short)(r >> 16);
    union { float f; unsigned u; } b; b.u = ((unsigned)hi) << 16;
    union { float f; unsigned u; } c; c.f = x - b.f;
    unsigned r2 = c.u + 0x7FFF + ((c.u >> 16) & 1);
    lo = (unsigned short)(r2 >> 16);
}

// ---------------------------------------------------------------- zero
__global__ void zero_kernel(float4* __restrict__ buf){
    buf[(size_t)blockIdx.x*256 + threadIdx.x] = make_float4(0.f,0.f,0.f,0.f);
}

// ---------------------------------------------------------------- repack weights
__global__ void repack_kernel(const float* __restrict__ sw1, const float* __restrict__ pw1,
                              const float* __restrict__ sw2, const float* __restrict__ cw1,
                              const float* __restrict__ cw2, const float* __restrict__ dw1,
                              const float* __restrict__ dw2, const float* __restrict__ pw2,
                              const float* __restrict__ fw2, const float* __restrict__ fw3,
                              float* __restrict__ sw1t,
                              unsigned short* __restrict__ pw1fH, unsigned short* __restrict__ pw1fL,
                              float* __restrict__ sw2T, float* __restrict__ cw1T,
                              float* __restrict__ cw2T, float* __restrict__ dw1T,
                              float* __restrict__ dw2T,
                              unsigned short* __restrict__ pw2fH, unsigned short* __restrict__ pw2fL,
                              float* __restrict__ fw2T, float* __restrict__ fw3T){
    int tid = blockIdx.x*256 + threadIdx.x;
    if (tid < 65280){ int nn = tid/4352, r = tid%4352, i = r>>6, o = r&63;
        sw1t[tid] = sw1[(o*68+i)*15+nn]; }
    // pw1 MFMA A-fragments (hi/lo): frag idx = ((nn*4+kt)*8+ot), lane-major
    if (tid < 245760){
        int b = tid & 7, ln = (tid>>3)&63, ot = (tid>>9)&7, kt = (tid>>12)&3, nn = tid>>14;
        int o = ot*16 + (ln&15), k = kt*32 + (ln>>4)*8 + b;
        float v = pw1[(o*128 + k)*15 + nn];
        unsigned short hi, lo; bf16_hilo(v, hi, lo);
        pw1fH[tid] = hi; pw1fL[tid] = lo;
    }
    if (tid < 16384){
        int b = tid & 7, ln = (tid>>3)&63, ot = (tid>>9)&7, kt = (tid>>12)&3;
        int o = ot*16 + (ln&15), k = kt*32 + (ln>>4)*8 + b;
        float v = pw2[o*128 + k];
        unsigned short hi, lo; bf16_hilo(v, hi, lo);
        pw2fH[tid] = hi; pw2fL[tid] = lo;
    }
    if (tid < 4096){ int c = tid>>6, o = tid&63; sw2T[tid] = sw2[o*64+c]; }
    if (tid < 2048){ int c = tid>>5, o = tid&31; cw1T[tid] = cw1[o*64+c]; }
    if (tid < 1024){ int c = tid>>5, o = tid&31; cw2T[tid] = cw2[o*32+c]; }
    if (tid < 2048){ int c = tid>>6, o = tid&63; dw1T[tid] = dw1[o*32+c]; }
    if (tid < 4096){ int c = tid>>6, o = tid&63; dw2T[tid] = dw2[o*64+c]; }
    if (tid < 16384){ int c = tid>>7, o = tid&127; fw2T[tid] = fw2[o*128+c]; }
    if (tid < 8192){ int c = tid>>6, o = tid&63; fw3T[tid] = fw3[o*128+c]; }
}

// ---------------------------------------------------------------- point MLP (3->32->32->64) + el pack
__global__ __launch_bounds__(256) void mlp3_kernel(
        const float* __restrict__ pc, const float* __restrict__ el,
        const float* __restrict__ w1, const float* __restrict__ b1,
        const float* __restrict__ w2, const float* __restrict__ b2,
        const float* __restrict__ w3, const float* __restrict__ b3,
        float* __restrict__ pfeat){
    __shared__ float W1[96], W2s[1024], W3s[2048], B1[32], B2[32], B3[64];
    const int t = threadIdx.x;
    for (int e=t;e<96;e+=256)   W1[e]=w1[e];
    for (int e=t;e<1024;e+=256) W2s[e]=w2[e];
    for (int e=t;e<2048;e+=256) W3s[e]=w3[e];
    if (t<32){ B1[t]=b1[t]; B2[t]=b2[t]; }
    if (t<64){ B3[t]=b3[t]; }
    __syncthreads();
    const int n = blockIdx.x*256 + t;
    const float x0 = pc[n], x1 = pc[NPTS+n], x2 = pc[2*NPTS+n];
    float h1[32];
    #pragma unroll
    for (int o=0;o<32;++o)
        h1[o] = lrelu(B1[o] + W1[o*3]*x0 + W1[o*3+1]*x1 + W1[o*3+2]*x2);
    float h2[32];
    #pragma unroll
    for (int o=0;o<32;++o){
        float a = B2[o];
        #pragma unroll
        for (int c=0;c<32;++c) a += W2s[o*32+c]*h1[c];
        h2[o] = lrelu(a);
    }
    float* row = pfeat + (size_t)n*68;
    *(float4*)row = make_float4(el[n], el[NPTS+n], el[2*NPTS+n], el[3*NPTS+n]);
    #pragma unroll
    for (int o4=0;o4<16;++o4){
        float tmp[4];
        #pragma unroll
        for (int q=0;q<4;++q){
            const int o = o4*4+q;
            float a = B3[o];
            #pragma unroll
            for (int c=0;c<32;++c) a += W3s[o*32+c]*h2[c];
            tmp[q] = lrelu(a);
        }
        *(float4*)(row + 4 + o4*4) = make_float4(tmp[0],tmp[1],tmp[2],tmp[3]);
    }
}

// ---------------------------------------------------------------- splat (scatter-add, wave-per-pair)
__global__ __launch_bounds__(256) void splat_kernel(
        const float* __restrict__ pfeat, const float* __restrict__ bary,
        const int* __restrict__ off, float* __restrict__ lat){
    const int pair = (blockIdx.x*256 + threadIdx.x) >> 6;   // 0 .. 5*NPTS-1
    const int lane = threadIdx.x & 63;
    const int n = pair & (NPTS-1);
    const int j = pair >> 15;
    const float b = bary[j*NPTS + n];
    const int o = off[j*NPTS + n];
    const float* row = pfeat + (size_t)n*68;
    float* dst = lat + (size_t)o*68;
    unsafeAtomicAdd(&dst[lane], b*row[lane]);
    if (lane < 4) unsafeAtomicAdd(&dst[64+lane], b*row[64+lane]);
}

// ---------------------------------------------------------------- blur_s (vector f32, unchanged)
__global__ __launch_bounds__(256) void blur_s_kernel(
        const float* __restrict__ lat, const int* __restrict__ nb,
        const float* __restrict__ sw1t, const float* __restrict__ sb1,
        const float* __restrict__ sw2T, const float* __restrict__ sb2,
        float* __restrict__ outp, int ostride){
    __shared__ __align__(16) float GT[6144];
    __shared__ __align__(16) float WW[4352];
    __shared__ int sidx[2][64];
    const int t = threadIdx.x;
    const int hb = blockIdx.x*64;
    const int oq = t>>4, hq = t&15;
    const int lane16 = t&15, rgrp = t>>4;
    float bs1[4], bs2[4];
    #pragma unroll
    for (int i=0;i<4;++i){ bs1[i]=sb1[oq*4+i]; bs2[i]=sb2[oq*4+i]; }
    if (t<64) sidx[0][t] = nb[hb + t];
    __syncthreads();
    float acc[4][4] = {};
    for (int nn=0; nn<NNB; ++nn){
        const int cur = nn&1;
        #pragma unroll
        for (int i=0;i<4;++i){
            const int row = rgrp + 16*i;
            const float* src = lat + (size_t)sidx[cur][row]*68;
            const float4 v = *(const float4*)(src + lane16*4);
            const int qs = lane16 ^ ((row>>2)&7);
            *(float4*)(GT + row*96 + qs*4) = v;
        }
        if (t<64){
            const int row = t;
            const float4 v = *(const float4*)(lat + (size_t)sidx[cur][row]*68 + 64);
            const int qs = 16 ^ ((row>>2)&7);
            *(float4*)(GT + row*96 + qs*4) = v;
        }
        for (int e=t; e<1088; e+=256)
            *(float4*)(WW + e*4) = *(const float4*)(sw1t + nn*4352 + e*4);
        if (t<64 && nn+1<NNB) sidx[(nn+1)&1][t] = nb[(nn+1)*HL + hb + t];
        __syncthreads();
        for (int q=0;q<17;++q){
            float a[4][4];
            const int qs = q ^ (hq&7);
            #pragma unroll
            for (int j=0;j<4;++j){
                const float4 v = *(const float4*)(GT + (hq*4+j)*96 + qs*4);
                a[0][j]=v.x; a[1][j]=v.y; a[2][j]=v.z; a[3][j]=v.w;
            }
            #pragma unroll
            for (int cc=0;cc<4;++cc){
                const float4 w = *(const float4*)(WW + (q*4+cc)*64 + oq*4);
                const float wv[4] = {w.x,w.y,w.z,w.w};
                #pragma unroll
                for (int i=0;i<4;++i)
                    #pragma unroll
                    for (int j=0;j<4;++j)
                        acc[i][j] = fmaf(wv[i], a[cc][j], acc[i][j]);
            }
        }
        __syncthreads();
    }
    #pragma unroll
    for (int i=0;i<4;++i){
        float4 v = make_float4(lrelu(acc[i][0]+bs1[i]), lrelu(acc[i][1]+bs1[i]),
                               lrelu(acc[i][2]+bs1[i]), lrelu(acc[i][3]+bs1[i]));
        *(float4*)(GT + (oq*4+i)*68 + hq*4) = v;
    }
    for (int e=t;e<1024;e+=256)
        *(float4*)(WW + e*4) = *(const float4*)(sw2T + e*4);
    __syncthreads();
    float acc2[4][4] = {};
    #pragma unroll 4
    for (int c=0;c<64;++c){
        const float4 a4 = *(const float4*)(GT + c*68 + hq*4);
        const float4 w4 = *(const float4*)(WW + c*64 + oq*4);
        const float av[4]={a4.x,a4.y,a4.z,a4.w};
        const float wv[4]={w4.x,w4.y,w4.z,w4.w};
        #pragma unroll
        for (int i=0;i<4;++i)
            #pragma unroll
            for (int j=0;j<4;++j)
                acc2[i][j] = fmaf(wv[i], av[j], acc2[i][j]);
    }
    #pragma unroll
    for (int j=0;j<4;++j){
        const int h = hb + hq*4 + j;
        float4 v = make_float4(lrelu(acc2[0][j]+bs2[0]), lrelu(acc2[1][j]+bs2[1]),
                               lrelu(acc2[2][j]+bs2[2]), lrelu(acc2[3][j]+bs2[3]));
        *(float4*)(outp + (size_t)h*ostride + oq*4) = v;
    }
}

// ---------------------------------------------------------------- corr + d-MLP (vector f32, unchanged)
__global__ __launch_bounds__(256) void corr_kernel(
        float* __restrict__ cat, const float* __restrict__ lat2, const int* __restrict__ ci,
        const float* __restrict__ cw1T, const float* __restrict__ cb1,
        const float* __restrict__ cw2T, const float* __restrict__ cb2,
        const float* __restrict__ dw1T, const float* __restrict__ db1,
        const float* __restrict__ dw2T, const float* __restrict__ db2){
    __shared__ __align__(16) float PROD[8448];
    __shared__ __align__(16) float M1[4224];
    __shared__ __align__(16) float W1s[2048];
    __shared__ __align__(16) float W2s[1024];
    __shared__ int sidx[2][128];
    const int t = threadIdx.x;
    const int hb = blockIdx.x*128;
    const int oq = t>>5, hq = t&31;
    const int lane16 = t&15, rgrp = t>>4;
    for (int e=t;e<512;e+=256) *(float4*)(W1s+e*4) = *(const float4*)(cw1T+e*4);
    for (int e=t;e<256;e+=256) *(float4*)(W2s+e*4) = *(const float4*)(cw2T+e*4);
    float l1r[8][4];
    #pragma unroll
    for (int i=0;i<8;++i){
        const int h = hb + rgrp + 16*i;
        const float4 v = *(const float4*)(cat + (size_t)h*128 + lane16*4);
        l1r[i][0]=v.x; l1r[i][1]=v.y; l1r[i][2]=v.z; l1r[i][3]=v.w;
    }
    float bc1[4], bc2[4];
    #pragma unroll
    for (int i=0;i<4;++i){ bc1[i]=cb1[oq*4+i]; bc2[i]=cb2[oq*4+i]; }
    if (t<128) sidx[0][t] = ci[hb+t];
    __syncthreads();
    float agg[4][4] = {};
    for (int k=0;k<KC;++k){
        const int cur = k&1;
        #pragma unroll
        for (int i=0;i<8;++i){
            const int row = rgrp + 16*i;
            const float4 g = *(const float4*)(lat2 + (size_t)sidx[cur][row]*64 + lane16*4);
            PROD[(lane16*4+0)*132 + row] = g.x * l1r[i][0];
            PROD[(lane16*4+1)*132 + row] = g.y * l1r[i][1];
            PROD[(lane16*4+2)*132 + row] = g.z * l1r[i][2];
            PROD[(lane16*4+3)*132 + row] = g.w * l1r[i][3];
        }
        if (t<128 && k+1<KC) sidx[(k+1)&1][t] = ci[(k+1)*HL + hb + t];
        __syncthreads();
        float a1[4][4] = {};
        #pragma unroll 8
        for (int c=0;c<64;++c){
            const float4 w = *(const float4*)(W1s + c*32 + oq*4);
            const float4 b = *(const float4*)(PROD + c*132 + hq*4);
            const float wv[4]={w.x,w.y,w.z,w.w};
            const float bv[4]={b.x,b.y,b.z,b.w};
            #pragma unroll
            for (int i=0;i<4;++i)
                #pragma unroll
                for (int j=0;j<4;++j)
                    a1[i][j] = fmaf(wv[i], bv[j], a1[i][j]);
        }
        #pragma unroll
        for (int i=0;i<4;++i){
            float4 v = make_float4(lrelu(a1[i][0]+bc1[i]), lrelu(a1[i][1]+bc1[i]),
                                   lrelu(a1[i][2]+bc1[i]), lrelu(a1[i][3]+bc1[i]));
            *(float4*)(M1 + (oq*4+i)*132 + hq*4) = v;
        }
        __syncthreads();
        float a2[4][4] = {};
        #pragma unroll 8
        for (int c=0;c<32;++c){
            const float4 w = *(const float4*)(W2s + c*32 + oq*4);
            const float4 b = *(const float4*)(M1 + c*132 + hq*4);
            const float wv[4]={w.x,w.y,w.z,w.w};
            const float bv[4]={b.x,b.y,b.z,b.w};
            #pragma unroll
            for (int i=0;i<4;++i)
                #pragma unroll
                for (int j=0;j<4;++j)
                    a2[i][j] = fmaf(wv[i], bv[j], a2[i][j]);
        }
        #pragma unroll
        for (int i=0;i<4;++i)
            #pragma unroll
            for (int j=0;j<4;++j)
                agg[i][j] += lrelu(a2[i][j]+bc2[i]);
    }
    __syncthreads();
    const float s = 1.0f/32.0f;
    #pragma unroll
    for (int i=0;i<4;++i){
        float4 v = make_float4(agg[i][0]*s, agg[i][1]*s, agg[i][2]*s, agg[i][3]*s);
        *(float4*)(M1 + (oq*4+i)*132 + hq*4) = v;
    }
    for (int e=t;e<512;e+=256) *(float4*)(W1s+e*4) = *(const float4*)(dw1T+e*4);
    __syncthreads();
    const int og = oq;
    float bd1[8];
    #pragma unroll
    for (int i=0;i<8;++i) bd1[i] = db1[og*8+i];
    float d1a[8][4] = {};
    #pragma unroll 4
    for (int c=0;c<32;++c){
        const float4 wa = *(const float4*)(W1s + c*64 + og*8);
        const float4 wb = *(const float4*)(W1s + c*64 + og*8 + 4);
        const float4 a  = *(const float4*)(M1 + c*132 + hq*4);
        const float wv[8]={wa.x,wa.y,wa.z,wa.w,wb.x,wb.y,wb.z,wb.w};
        const float av[4]={a.x,a.y,a.z,a.w};
        #pragma unroll
        for (int i=0;i<8;++i)
            #pragma unroll
            for (int j=0;j<4;++j)
                d1a[i][j] = fmaf(wv[i], av[j], d1a[i][j]);
    }
    __syncthreads();
    #pragma unroll
    for (int i=0;i<8;++i){
        float4 v = make_float4(lrelu(d1a[i][0]+bd1[i]), lrelu(d1a[i][1]+bd1[i]),
                               lrelu(d1a[i][2]+bd1[i]), lrelu(d1a[i][3]+bd1[i]));
        *(float4*)(PROD + (og*8+i)*132 + hq*4) = v;
    }
    for (int e=t;e<1024;e+=256) *(float4*)(M1+e*4) = *(const float4*)(dw2T+e*4);
    __syncthreads();
    float bd2[8];
    #pragma unroll
    for (int i=0;i<8;++i) bd2[i] = db2[og*8+i];
    float d2a[8][4] = {};
    #pragma unroll 4
    for (int c=0;c<64;++c){
        const float4 wa = *(const float4*)(M1 + c*64 + og*8);
        const float4 wb = *(const float4*)(M1 + c*64 + og*8 + 4);
        const float4 a  = *(const float4*)(PROD + c*132 + hq*4);
        const float wv[8]={wa.x,wa.y,wa.z,wa.w,wb.x,wb.y,wb.z,wb.w};
        const float av[4]={a.x,a.y,a.z,a.w};
        #pragma unroll
        for (int i=0;i<8;++i)
            #pragma unroll
            for (int j=0;j<4;++j)
                d2a[i][j] = fmaf(wv[i], av[j], d2a[i][j]);
    }
    #pragma unroll
    for (int j=0;j<4;++j){
        const int h = hb + hq*4 + j;
        float* dst = cat + (size_t)h*128 + 64 + og*8;
        float4 v0 = make_float4(lrelu(d2a[0][j]+bd2[0]), lrelu(d2a[1][j]+bd2[1]),
                                lrelu(d2a[2][j]+bd2[2]), lrelu(d2a[3][j]+bd2[3]));
        float4 v1 = make_float4(lrelu(d2a[4][j]+bd2[4]), lrelu(d2a[5][j]+bd2[5]),
                                lrelu(d2a[6][j]+bd2[6]), lrelu(d2a[7][j]+bd2[7]));
        *(float4*)dst = v0;
        *(float4*)(dst+4) = v1;
    }
}

// ---------------------------------------------------------------- cat -> bf16 hi/lo
__global__ __launch_bounds__(256) void cvt_cat_kernel(const float* __restrict__ cat,
        unsigned short* __restrict__ cH, unsigned short* __restrict__ cL){
    const size_t i = (size_t)blockIdx.x*256 + threadIdx.x;
    const float4 v = *(const float4*)(cat + i*4);
    unsigned short h0,h1,h2,h3,l0,l1,l2,l3;
    bf16_hilo(v.x,h0,l0); bf16_hilo(v.y,h1,l1); bf16_hilo(v.z,h2,l2); bf16_hilo(v.w,h3,l3);
    *(ushort4*)(cH + i*4) = make_ushort4(h0,h1,h2,h3);
    *(ushort4*)(cL + i*4) = make_ushort4(l0,l1,l2,l3);
}

// ---------------------------------------------------------------- blur_p via split-bf16 MFMA
// block: 64 h, 256 threads (4 waves). wave w: o-tiles {2w, 2w+1} (16 o each), all 4 h-tiles.
__global__ __launch_bounds__(256) void blur_p_mfma_kernel(
        const unsigned short* __restrict__ catH, const unsigned short* __restrict__ catL,
        const int* __restrict__ nb,
        const unsigned short* __restrict__ pw1fH, const unsigned short* __restrict__ pw1fL,
        const float* __restrict__ pb1,
        const unsigned short* __restrict__ pw2fH, const unsigned short* __restrict__ pw2fL,
        const float* __restrict__ pb2,
        float* __restrict__ p){
    __shared__ unsigned short GH[8192];   // [64 rows][128 ch] XOR-swizzled 16B chunks
    __shared__ unsigned short GLb[8192];
    __shared__ int sidx[NNB][64];
    const int t = threadIdx.x;
    const int hb = blockIdx.x*64;
    const int w = t>>6, lane = t&63;
    const int l15 = lane&15, lg = lane>>4;
    for (int e=t; e<NNB*64; e+=256) sidx[e>>6][e&63] = nb[(e>>6)*HL + hb + (e&63)];
    f32x4 acc1[2][4];
    #pragma unroll
    for (int ot=0;ot<2;++ot)
        #pragma unroll
        for (int ht=0;ht<4;++ht) acc1[ot][ht] = (f32x4){0.f,0.f,0.f,0.f};
    __syncthreads();
    for (int nn=0; nn<NNB; ++nn){
        if (nn) __syncthreads();
        #pragma unroll
        for (int i=0;i<4;++i){
            const int j2 = t + 256*i;
            const int row = j2>>4, q = j2&15;
            const int g = sidx[nn][row];
            const uint4 vh = *(const uint4*)(catH + (size_t)g*128 + q*8);
            const uint4 vl = *(const uint4*)(catL + (size_t)g*128 + q*8);
            const int d = row*128 + ((q ^ (row&7))*8);
            *(uint4*)(GH + d) = vh;
            *(uint4*)(GLb + d) = vl;
        }
        __syncthreads();
        #pragma unroll
        for (int kt=0; kt<4; ++kt){
            s16x8 BH[4], BL[4];
            #pragma unroll
            for (int ht=0; ht<4; ++ht){
                const int h = ht*16 + l15;
                const int q = kt*4 + lg;
                const int d = h*128 + ((q ^ (h&7))*8);
                BH[ht] = *(const s16x8*)(GH + d);
                BL[ht] = *(const s16x8*)(GLb + d);
            }
            s16x8 AH[2], AL[2];
            #pragma unroll
            for (int ot=0; ot<2; ++ot){
                const size_t fo = ((size_t)((nn*4 + kt)*8 + (w*2+ot)))*512 + lane*8;
                AH[ot] = *(const s16x8*)(pw1fH + fo);
                AL[ot] = *(const s16x8*)(pw1fL + fo);
            }
            #pragma unroll
            for (int ht=0; ht<4; ++ht)
                #pragma unroll
                for (int ot=0; ot<2; ++ot)
                    acc1[ot][ht] = __builtin_amdgcn_mfma_f32_16x16x32_bf16(AH[ot], BH[ht], acc1[ot][ht], 0,0,0);
            #pragma unroll
            for (int ht=0; ht<4; ++ht)
                #pragma unroll
                for (int ot=0; ot<2; ++ot)
                    acc1[ot][ht] = __builtin_amdgcn_mfma_f32_16x16x32_bf16(AH[ot], BL[ht], acc1[ot][ht], 0,0,0);
            #pragma unroll
            for (int ht=0; ht<4; ++ht)
                #pragma unroll
                for (int ot=0; ot<2; ++ot)
                    acc1[ot][ht] = __builtin_amdgcn_mfma_f32_16x16x32_bf16(AL[ot], BH[ht], acc1[ot][ht], 0,0,0);
        }
    }
    __syncthreads();
    // epilogue 1: T[h][o] = lrelu(acc1 + pb1) as bf16 hi/lo into GH/GLb (same swizzle)
    #pragma unroll
    for (int ot=0; ot<2; ++ot){
        const int o0 = (w*2+ot)*16 + lg*4;
        const float b0 = pb1[o0], b1v = pb1[o0+1], b2v = pb1[o0+2], b3v = pb1[o0+3];
        const int q = o0>>3;
        #pragma unroll
        for (int ht=0; ht<4; ++ht){
            const int h = ht*16 + l15;
            unsigned short th[4], tl[4];
            bf16_hilo(lrelu(acc1[ot][ht][0] + b0), th[0], tl[0]);
            bf16_hilo(lrelu(acc1[ot][ht][1] + b1v), th[1], tl[1]);
            bf16_hilo(lrelu(acc1[ot][ht][2] + b2v), th[2], tl[2]);
            bf16_hilo(lrelu(acc1[ot][ht][3] + b3v), th[3], tl[3]);
            const int d = h*128 + ((q ^ (h&7))*8) + (o0&7);
            *(ushort4*)(GH + d)  = make_ushort4(th[0],th[1],th[2],th[3]);
            *(ushort4*)(GLb + d) = make_ushort4(tl[0],tl[1],tl[2],tl[3]);
        }
    }
    __syncthreads();
    // GEMM2: P[o2][h] = pw2 . T
    f32x4 acc2[2][4];
    #pragma unroll
    for (int ot=0;ot<2;++ot)
        #pragma unroll
        for (int ht=0;ht<4;++ht) acc2[ot][ht] = (f32x4){0.f,0.f,0.f,0.f};
    #pragma unroll
    for (int kt=0; kt<4; ++kt){
        s16x8 BH[4], BL[4];
        #pragma unroll
        for (int ht=0; ht<4; ++ht){
            const int h = ht*16 + l15;
            const int q = kt*4 + lg;
            const int d = h*128 + ((q ^ (h&7))*8);
            BH[ht] = *(const s16x8*)(GH + d);
            BL[ht] = *(const s16x8*)(GLb + d);
        }
        s16x8 AH[2], AL[2];
        #pragma unroll
        for (int ot=0; ot<2; ++ot){
            const size_t fo = ((size_t)(kt*8 + (w*2+ot)))*512 + lane*8;
            AH[ot] = *(const s16x8*)(pw2fH + fo);
            AL[ot] = *(const s16x8*)(pw2fL + fo);
        }
        #pragma unroll
        for (int ht=0; ht<4; ++ht)
            #pragma unroll
            for (int ot=0; ot<2; ++ot)
                acc2[ot][ht] = __builtin_amdgcn_mfma_f32_16x16x32_bf16(AH[ot], BH[ht], acc2[ot][ht], 0,0,0);
        #pragma unroll
        for (int ht=0; ht<4; ++ht)
            #pragma unroll
            for (int ot=0; ot<2; ++ot)
                acc2[ot][ht] = __builtin_amdgcn_mfma_f32_16x16x32_bf16(AH[ot], BL[ht], acc2[ot][ht], 0,0,0);
        #pragma unroll
        for (int ht=0; ht<4; ++ht)
            #pragma unroll
            for (int ot=0; ot<2; ++ot)
                acc2[ot][ht] = __builtin_amdgcn_mfma_f32_16x16x32_bf16(AL[ot], BH[ht], acc2[ot][ht], 0,0,0);
    }
    #pragma unroll
    for (int ot=0; ot<2; ++ot){
        const int o0 = (w*2+ot)*16 + lg*4;
        const float b0 = pb2[o0], b1v = pb2[o0+1], b2v = pb2[o0+2], b3v = pb2[o0+3];
        #pragma unroll
        for (int ht=0; ht<4; ++ht){
            const int h = hb + ht*16 + l15;
            float4 v = make_float4(lrelu(acc2[ot][ht][0] + b0), lrelu(acc2[ot][ht][1] + b1v),
                                   lrelu(acc2[ot][ht][2] + b2v), lrelu(acc2[ot][ht][3] + b3v));
            *(float4*)(p + (size_t)h*128 + o0) = v;
        }
    }
}

// ---------------------------------------------------------------- head: slice + 128->128->64->3
__global__ __launch_bounds__(256) void head_kernel(
        const float* __restrict__ p, const float* __restrict__ bary, const int* __restrict__ off,
        const float* __restrict__ fw2T, const float* __restrict__ fb2,
        const float* __restrict__ fw3T, const float* __restrict__ fb3,
        const float* __restrict__ fw4, const float* __restrict__ fb4,
        float* __restrict__ out){
    __shared__ __align__(16) float S[8704];
    __shared__ __align__(16) float WW[8192];
    __shared__ float SB[5][64];
    __shared__ int   SO[5][64];
    const int t = threadIdx.x;
    const int pb = blockIdx.x*64;
    const int oq8 = t>>4, pq = t&15;
    const int q5 = t&31, rgrp5 = t>>5;
    if (t<64){
        #pragma unroll
        for (int j=0;j<5;++j){ SB[j][t]=bary[j*NPTS+pb+t]; SO[j][t]=off[j*NPTS+pb+t]; }
    }
    __syncthreads();
    #pragma unroll
    for (int i=0;i<8;++i){
        const int row = rgrp5 + 8*i;
        float4 sa = make_float4(0.f,0.f,0.f,0.f);
        #pragma unroll
        for (int j=0;j<5;++j){
            const float4 v = *(const float4*)(p + (size_t)SO[j][row]*128 + q5*4);
            const float b = SB[j][row];
            sa.x += b*v.x; sa.y += b*v.y; sa.z += b*v.z; sa.w += b*v.w;
        }
        S[(q5*4+0)*68 + row] = sa.x;
        S[(q5*4+1)*68 + row] = sa.y;
        S[(q5*4+2)*68 + row] = sa.z;
        S[(q5*4+3)*68 + row] = sa.w;
    }
    float acc1[8][4] = {};
    #pragma unroll 1
    for (int hf=0;hf<2;++hf){
        if (hf==1) __syncthreads();
        for (int e=t;e<2048;e+=256)
            *(float4*)(WW + e*4) = *(const float4*)(fw2T + hf*8192 + e*4);
        __syncthreads();
        #pragma unroll 4
        for (int c=0;c<64;++c){
            const float4 a4 = *(const float4*)(S + (hf*64+c)*68 + pq*4);
            const float4 wa = *(const float4*)(WW + c*128 + oq8*8);
            const float4 wb = *(const float4*)(WW + c*128 + oq8*8 + 4);
            const float av[4]={a4.x,a4.y,a4.z,a4.w};
            const float wv[8]={wa.x,wa.y,wa.z,wa.w,wb.x,wb.y,wb.z,wb.w};
            #pragma unroll
            for (int i=0;i<8;++i)
                #pragma unroll
                for (int j=0;j<4;++j)
                    acc1[i][j] = fmaf(wv[i], av[j], acc1[i][j]);
        }
    }
    __syncthreads();
    float bf2[8];
    #pragma unroll
    for (int i=0;i<8;++i) bf2[i]=fb2[oq8*8+i];
    #pragma unroll
    for (int i=0;i<8;++i){
        const int o = oq8*8+i;
        float4 v = make_float4(lrelu(acc1[i][0]+bf2[i]), lrelu(acc1[i][1]+bf2[i]),
                               lrelu(acc1[i][2]+bf2[i]), lrelu(acc1[i][3]+bf2[i]));
        *(float4*)(S + o*68 + pq*4) = v;
    }
    for (int e=t;e<2048;e+=256)
        *(float4*)(WW + e*4) = *(const float4*)(fw3T + e*4);
    __syncthreads();
    const int od = t>>4;
    float bf3[4];
    #pragma unroll
    for (int i=0;i<4;++i) bf3[i]=fb3[od*4+i];
    float a2[4][4] = {};
    #pragma unroll 4
    for (int c=0;c<128;++c){
        const float4 a4 = *(const float4*)(S + c*68 + pq*4);
        const float4 w4 = *(const float4*)(WW + c*64 + od*4);
        const float av[4]={a4.x,a4.y,a4.z,a4.w};
        const float wv[4]={w4.x,w4.y,w4.z,w4.w};
        #pragma unroll
        for (int i=0;i<4;++i)
            #pragma unroll
            for (int j=0;j<4;++j)
                a2[i][j] = fmaf(wv[i], av[j], a2[i][j]);
    }
    __syncthreads();
    #pragma unroll
    for (int i=0;i<4;++i){
        float4 v = make_float4(lrelu(a2[i][0]+bf3[i]), lrelu(a2[i][1]+bf3[i]),
                               lrelu(a2[i][2]+bf3[i]), lrelu(a2[i][3]+bf3[i]));
        *(float4*)(S + (od*4+i)*68 + pq*4) = v;
    }
    __syncthreads();
    if (t < 192){
        const int r = t>>6, pp = t&63;
        float a = fb4[r];
        #pragma unroll 8
        for (int c=0;c<64;++c) a += fw4[r*64+c]*S[c*68+pp];
        out[r*NPTS + pb + pp] = a;
    }
}

// ================================================================ launch
extern "C" void kernel_launch(void* const* d_in, const int* in_sizes, int n_in,
                              void* d_out, int out_size, void* d_ws, size_t ws_size,
                              hipStream_t stream){
    const float* pc1   = (const float*)d_in[0];
    const float* pc2   = (const float*)d_in[1];
    const float* el1   = (const float*)d_in[2];
    const float* el2   = (const float*)d_in[3];
    const float* bary1 = (const float*)d_in[4];
    const float* bary2 = (const float*)d_in[5];
    const int*   off1  = (const int*)d_in[6];
    const int*   off2  = (const int*)d_in[7];
    const int*   nb1   = (const int*)d_in[8];
    const int*   nb2   = (const int*)d_in[9];
    const int*   ci    = (const int*)d_in[10];
    const float* w1    = (const float*)d_in[11];
    const float* b1    = (const float*)d_in[12];
    const float* w2    = (const float*)d_in[13];
    const float* b2    = (const float*)d_in[14];
    const float* w3    = (const float*)d_in[15];
    const float* b3    = (const float*)d_in[16];
    const float* sw1   = (const float*)d_in[17];
    const float* sb1   = (const float*)d_in[18];
    const float* sw2   = (const float*)d_in[19];
    const float* sb2   = (const float*)d_in[20];
    const float* cw1   = (const float*)d_in[21];
    const float* cb1   = (const float*)d_in[22];
    const float* cw2   = (const float*)d_in[23];
    const float* cb2   = (const float*)d_in[24];
    const float* dw1   = (const float*)d_in[25];
    const float* db1   = (const float*)d_in[26];
    const float* dw2   = (const float*)d_in[27];
    const float* db2   = (const float*)d_in[28];
    const float* pw1   = (const float*)d_in[29];
    const float* pb1   = (const float*)d_in[30];
    const float* pw2   = (const float*)d_in[31];
    const float* pb2   = (const float*)d_in[32];
    const float* fw2   = (const float*)d_in[33];
    const float* fb2   = (const float*)d_in[34];
    const float* fw3   = (const float*)d_in[35];
    const float* fb3   = (const float*)d_in[36];
    const float* fw4   = (const float*)d_in[37];
    const float* fb4   = (const float*)d_in[38];
    float* out = (float*)d_out;

    float* ws    = (float*)d_ws;
    float* pf1   = ws;                    // N*68
    float* pf2   = pf1   + 2228224;
    float* latA  = pf2   + 2228224;       // H*68
    float* latB  = latA  + 2228224;
    float* catb  = latB  + 2228224;       // H*128
    float* lat2p = catb  + 4194304;       // H*64
    float* sw1t  = lat2p + 2097152;       // 65280
    float* pw1fS = sw1t  + 65280;         // 245760 floats = 491520 ushorts
    float* sw2T  = pw1fS + 245760;        // 4096
    float* cw1T  = sw2T  + 4096;          // 2048
    float* cw2T  = cw1T  + 2048;          // 1024
    float* dw1T  = cw2T  + 1024;          // 2048
    float* dw2T  = dw1T  + 2048;          // 4096
    float* pw2fS = dw2T  + 4096;          // 16384 floats = 32768 ushorts
    float* fw2T  = pw2fS + 16384;         // 16384
    float* fw3T  = fw2T  + 16384;         // 8192
    float* pbuf  = pf1;                   // p (H*128) reuses pf1+pf2

    unsigned short* pw1fH = (unsigned short*)pw1fS;
    unsigned short* pw1fL = pw1fH + 245760;
    unsigned short* pw2fH = (unsigned short*)pw2fS;
    unsigned short* pw2fL = pw2fH + 16384;
    unsigned short* catH  = (unsigned short*)latA;   // lattices dead by cvt time
    unsigned short* catL  = catH + (size_t)HL*128;

    zero_kernel<<<4352, 256, 0, stream>>>((float4*)latA);
    repack_kernel<<<960, 256, 0, stream>>>(sw1, pw1, sw2, cw1, cw2, dw1, dw2, pw2, fw2, fw3,
                                           sw1t, pw1fH, pw1fL, sw2T, cw1T, cw2T, dw1T, dw2T,
                                           pw2fH, pw2fL, fw2T, fw3T);

    mlp3_kernel<<<128, 256, 0, stream>>>(pc1, el1, w1,b1,w2,b2,w3,b3, pf1);
    mlp3_kernel<<<128, 256, 0, stream>>>(pc2, el2, w1,b1,w2,b2,w3,b3, pf2);

    splat_kernel<<<40960, 256, 0, stream>>>(pf1, bary1, off1, latA);
    splat_kernel<<<40960, 256, 0, stream>>>(pf2, bary2, off2, latB);

    blur_s_kernel<<<512, 256, 0, stream>>>(latA, nb1, sw1t, sb1, sw2T, sb2, catb, 128);
    blur_s_kernel<<<512, 256, 0, stream>>>(latB, nb2, sw1t, sb1, sw2T, sb2, lat2p, 64);

    corr_kernel<<<256, 256, 0, stream>>>(catb, lat2p, ci, cw1T,cb1,cw2T,cb2,dw1T,db1,dw2T,db2);

    cvt_cat_kernel<<<4096, 256, 0, stream>>>(catb, catH, catL);

    blur_p_mfma_kernel<<<512, 256, 0, stream>>>(catH, catL, nb1, pw1fH, pw1fL, pb1,
                                                pw2fH, pw2fL, pb2, pbuf);

    head_kernel<<<512, 256, 0, stream>>>(pbuf, bary1, off1, fw2T,fb2,fw3T,fb3,fw4,fb4, out);
}

// Round 5
// 520.216 us; speedup vs baseline: 30.7950x; 1.2267x over previous
//
#include <hip/hip_runtime.h>

#define NPTS 32768
#define HL   32768
#define NNB  15
#define KC   32

typedef __attribute__((ext_vector_type(8))) short s16x8;
typedef __attribute__((ext_vector_type(4))) float f32x4;

typedef union { s16x8 v; unsigned u[4]; } pk8;

__device__ __forceinline__ float lrelu(float x){ return x > 0.0f ? x : 0.1f*x; }

__device__ __forceinline__ unsigned short bf16r(float x){
    union { float f; unsigned u; } a; a.f = x;
    unsigned r = a.u + 0x7FFF + ((a.u >> 16) & 1);
    return (unsigned short)(r >> 16);
}
// round-to-nearest-even bf16 split: x ~= hi + lo
__device__ __forceinline__ void bf16_hilo(float x, unsigned short& hi, unsigned short& lo){
    hi = bf16r(x);
    union { float f; unsigned u; } b; b.u = ((unsigned)hi) << 16;
    lo = bf16r(x - b.f);
}
__device__ __forceinline__ unsigned pk2(unsigned short a, unsigned short b){
    return (unsigned)a | ((unsigned)b << 16);
}

// rows lg*8+0..7 of a 32-row column (2 ot-tiles packed p0/p1, u32 = row pair) -> B frag
__device__ __forceinline__ pk8 shuf32(const unsigned* p0, const unsigned* p1,
                                      int sel, int srcA, int srcB){
    pk8 o;
    int a0 = __builtin_amdgcn_ds_bpermute(srcA, (int)p0[0]);
    int a1 = __builtin_amdgcn_ds_bpermute(srcA, (int)p1[0]);
    o.u[0] = (unsigned)(sel ? a1 : a0);
    int b0 = __builtin_amdgcn_ds_bpermute(srcA, (int)p0[1]);
    int b1 = __builtin_amdgcn_ds_bpermute(srcA, (int)p1[1]);
    o.u[1] = (unsigned)(sel ? b1 : b0);
    int c0 = __builtin_amdgcn_ds_bpermute(srcB, (int)p0[0]);
    int c1 = __builtin_amdgcn_ds_bpermute(srcB, (int)p1[0]);
    o.u[2] = (unsigned)(sel ? c1 : c0);
    int d0 = __builtin_amdgcn_ds_bpermute(srcB, (int)p0[1]);
    int d1 = __builtin_amdgcn_ds_bpermute(srcB, (int)p1[1]);
    o.u[3] = (unsigned)(sel ? d1 : d0);
    return o;
}

// ---------------------------------------------------------------- zero
__global__ void zero_kernel(float4* __restrict__ buf){
    buf[(size_t)blockIdx.x*256 + threadIdx.x] = make_float4(0.f,0.f,0.f,0.f);
}

// ---------------------------------------------------------------- repack weights
__global__ void repack_kernel(const float* __restrict__ sw1, const float* __restrict__ pw1,
                              const float* __restrict__ sw2, const float* __restrict__ cw1,
                              const float* __restrict__ cw2, const float* __restrict__ dw1,
                              const float* __restrict__ dw2, const float* __restrict__ pw2,
                              const float* __restrict__ fw2, const float* __restrict__ fw3,
                              float* __restrict__ sw1t,
                              unsigned short* __restrict__ pw1fH, unsigned short* __restrict__ pw1fL,
                              float* __restrict__ sw2T,
                              unsigned short* __restrict__ W16,
                              unsigned short* __restrict__ pw2fH, unsigned short* __restrict__ pw2fL,
                              float* __restrict__ fw2T, float* __restrict__ fw3T){
    int tid = blockIdx.x*256 + threadIdx.x;
    if (tid < 65280){ int nn = tid/4352, r = tid%4352, i = r>>6, o = r&63;
        sw1t[tid] = sw1[(o*68+i)*15+nn]; }
    // pw1 MFMA A-fragments (hi/lo): frag idx = ((nn*4+kt)*8+ot), lane-major
    if (tid < 245760){
        int b = tid & 7, ln = (tid>>3)&63, ot = (tid>>9)&7, kt = (tid>>12)&3, nn = tid>>14;
        int o = ot*16 + (ln&15), k = kt*32 + (ln>>4)*8 + b;
        float v = pw1[(o*128 + k)*15 + nn];
        unsigned short hi, lo; bf16_hilo(v, hi, lo);
        pw1fH[tid] = hi; pw1fL[tid] = lo;
    }
    if (tid < 16384){
        int b = tid & 7, ln = (tid>>3)&63, ot = (tid>>9)&7, kt = (tid>>12)&3;
        int o = ot*16 + (ln&15), k = kt*32 + (ln>>4)*8 + b;
        float v = pw2[o*128 + k];
        unsigned short hi, lo; bf16_hilo(v, hi, lo);
        pw2fH[tid] = hi; pw2fL[tid] = lo;
    }
    // corr/d-MLP weight fragments (hi/lo) into W16:
    // cw1fH @0 (2048) cw1fL @2048 | cw2fH @4096 (1024) cw2fL @5120
    // dw1fH @6144 (2048) dw1fL @8192 | dw2fH @10240 (4096) dw2fL @14336
    if (tid < 2048){   // cw1 (32x64): frag f=ot*2+kt
        int b = tid&7, ln = (tid>>3)&63, f = tid>>9;
        int ot = f>>1, kt = f&1;
        int o = ot*16 + (ln&15), c = kt*32 + (ln>>4)*8 + b;
        unsigned short hi, lo; bf16_hilo(cw1[o*64+c], hi, lo);
        W16[tid] = hi; W16[2048+tid] = lo;
    }
    if (tid < 1024){   // cw2 (32x32): frag f=ot
        int b = tid&7, ln = (tid>>3)&63, ot = tid>>9;
        int o = ot*16 + (ln&15), c = (ln>>4)*8 + b;
        unsigned short hi, lo; bf16_hilo(cw2[o*32+c], hi, lo);
        W16[4096+tid] = hi; W16[5120+tid] = lo;
    }
    if (tid < 2048){   // dw1 (64x32): frag f=ot (4)
        int b = tid&7, ln = (tid>>3)&63, ot = tid>>9;
        int o = ot*16 + (ln&15), c = (ln>>4)*8 + b;
        unsigned short hi, lo; bf16_hilo(dw1[o*32+c], hi, lo);
        W16[6144+tid] = hi; W16[8192+tid] = lo;
    }
    if (tid < 4096){   // dw2 (64x64): frag f=ot*2+kt (8)
        int b = tid&7, ln = (tid>>3)&63, f = tid>>9;
        int ot = f>>1, kt = f&1;
        int o = ot*16 + (ln&15), c = kt*32 + (ln>>4)*8 + b;
        unsigned short hi, lo; bf16_hilo(dw2[o*64+c], hi, lo);
        W16[10240+tid] = hi; W16[14336+tid] = lo;
    }
    if (tid < 4096){ int c = tid>>6, o = tid&63; sw2T[tid] = sw2[o*64+c]; }
    if (tid < 16384){ int c = tid>>7, o = tid&127; fw2T[tid] = fw2[o*128+c]; }
    if (tid < 8192){ int c = tid>>6, o = tid&63; fw3T[tid] = fw3[o*128+c]; }
}

// ---------------------------------------------------------------- point MLP (3->32->32->64) + el pack
__global__ __launch_bounds__(256) void mlp3_kernel(
        const float* __restrict__ pc, const float* __restrict__ el,
        const float* __restrict__ w1, const float* __restrict__ b1,
        const float* __restrict__ w2, const float* __restrict__ b2,
        const float* __restrict__ w3, const float* __restrict__ b3,
        float* __restrict__ pfeat){
    __shared__ float W1[96], W2s[1024], W3s[2048], B1[32], B2[32], B3[64];
    const int t = threadIdx.x;
    for (int e=t;e<96;e+=256)   W1[e]=w1[e];
    for (int e=t;e<1024;e+=256) W2s[e]=w2[e];
    for (int e=t;e<2048;e+=256) W3s[e]=w3[e];
    if (t<32){ B1[t]=b1[t]; B2[t]=b2[t]; }
    if (t<64){ B3[t]=b3[t]; }
    __syncthreads();
    const int n = blockIdx.x*256 + t;
    const float x0 = pc[n], x1 = pc[NPTS+n], x2 = pc[2*NPTS+n];
    float h1[32];
    #pragma unroll
    for (int o=0;o<32;++o)
        h1[o] = lrelu(B1[o] + W1[o*3]*x0 + W1[o*3+1]*x1 + W1[o*3+2]*x2);
    float h2[32];
    #pragma unroll
    for (int o=0;o<32;++o){
        float a = B2[o];
        #pragma unroll
        for (int c=0;c<32;++c) a += W2s[o*32+c]*h1[c];
        h2[o] = lrelu(a);
    }
    float* row = pfeat + (size_t)n*68;
    *(float4*)row = make_float4(el[n], el[NPTS+n], el[2*NPTS+n], el[3*NPTS+n]);
    #pragma unroll
    for (int o4=0;o4<16;++o4){
        float tmp[4];
        #pragma unroll
        for (int q=0;q<4;++q){
            const int o = o4*4+q;
            float a = B3[o];
            #pragma unroll
            for (int c=0;c<32;++c) a += W3s[o*32+c]*h2[c];
            tmp[q] = lrelu(a);
        }
        *(float4*)(row + 4 + o4*4) = make_float4(tmp[0],tmp[1],tmp[2],tmp[3]);
    }
}

// ---------------------------------------------------------------- splat (scatter-add, wave-per-pair)
__global__ __launch_bounds__(256) void splat_kernel(
        const float* __restrict__ pfeat, const float* __restrict__ bary,
        const int* __restrict__ off, float* __restrict__ lat){
    const int pair = (blockIdx.x*256 + threadIdx.x) >> 6;   // 0 .. 5*NPTS-1
    const int lane = threadIdx.x & 63;
    const int n = pair & (NPTS-1);
    const int j = pair >> 15;
    const float b = bary[j*NPTS + n];
    const int o = off[j*NPTS + n];
    const float* row = pfeat + (size_t)n*68;
    float* dst = lat + (size_t)o*68;
    unsafeAtomicAdd(&dst[lane], b*row[lane]);
    if (lane < 4) unsafeAtomicAdd(&dst[64+lane], b*row[64+lane]);
}

// ---------------------------------------------------------------- blur_s (vector f32)
__global__ __launch_bounds__(256) void blur_s_kernel(
        const float* __restrict__ lat, const int* __restrict__ nb,
        const float* __restrict__ sw1t, const float* __restrict__ sb1,
        const float* __restrict__ sw2T, const float* __restrict__ sb2,
        float* __restrict__ outp, int ostride){
    __shared__ __align__(16) float GT[6144];
    __shared__ __align__(16) float WW[4352];
    __shared__ int sidx[2][64];
    const int t = threadIdx.x;
    const int hb = blockIdx.x*64;
    const int oq = t>>4, hq = t&15;
    const int lane16 = t&15, rgrp = t>>4;
    float bs1[4], bs2[4];
    #pragma unroll
    for (int i=0;i<4;++i){ bs1[i]=sb1[oq*4+i]; bs2[i]=sb2[oq*4+i]; }
    if (t<64) sidx[0][t] = nb[hb + t];
    __syncthreads();
    float acc[4][4] = {};
    for (int nn=0; nn<NNB; ++nn){
        const int cur = nn&1;
        #pragma unroll
        for (int i=0;i<4;++i){
            const int row = rgrp + 16*i;
            const float* src = lat + (size_t)sidx[cur][row]*68;
            const float4 v = *(const float4*)(src + lane16*4);
            const int qs = lane16 ^ ((row>>2)&7);
            *(float4*)(GT + row*96 + qs*4) = v;
        }
        if (t<64){
            const int row = t;
            const float4 v = *(const float4*)(lat + (size_t)sidx[cur][row]*68 + 64);
            const int qs = 16 ^ ((row>>2)&7);
            *(float4*)(GT + row*96 + qs*4) = v;
        }
        for (int e=t; e<1088; e+=256)
            *(float4*)(WW + e*4) = *(const float4*)(sw1t + nn*4352 + e*4);
        if (t<64 && nn+1<NNB) sidx[(nn+1)&1][t] = nb[(nn+1)*HL + hb + t];
        __syncthreads();
        for (int q=0;q<17;++q){
            float a[4][4];
            const int qs = q ^ (hq&7);
            #pragma unroll
            for (int j=0;j<4;++j){
                const float4 v = *(const float4*)(GT + (hq*4+j)*96 + qs*4);
                a[0][j]=v.x; a[1][j]=v.y; a[2][j]=v.z; a[3][j]=v.w;
            }
            #pragma unroll
            for (int cc=0;cc<4;++cc){
                const float4 w = *(const float4*)(WW + (q*4+cc)*64 + oq*4);
                const float wv[4] = {w.x,w.y,w.z,w.w};
                #pragma unroll
                for (int i=0;i<4;++i)
                    #pragma unroll
                    for (int j=0;j<4;++j)
                        acc[i][j] = fmaf(wv[i], a[cc][j], acc[i][j]);
            }
        }
        __syncthreads();
    }
    #pragma unroll
    for (int i=0;i<4;++i){
        float4 v = make_float4(lrelu(acc[i][0]+bs1[i]), lrelu(acc[i][1]+bs1[i]),
                               lrelu(acc[i][2]+bs1[i]), lrelu(acc[i][3]+bs1[i]));
        *(float4*)(GT + (oq*4+i)*68 + hq*4) = v;
    }
    for (int e=t;e<1024;e+=256)
        *(float4*)(WW + e*4) = *(const float4*)(sw2T + e*4);
    __syncthreads();
    float acc2[4][4] = {};
    #pragma unroll 4
    for (int c=0;c<64;++c){
        const float4 a4 = *(const float4*)(GT + c*68 + hq*4);
        const float4 w4 = *(const float4*)(WW + c*64 + oq*4);
        const float av[4]={a4.x,a4.y,a4.z,a4.w};
        const float wv[4]={w4.x,w4.y,w4.z,w4.w};
        #pragma unroll
        for (int i=0;i<4;++i)
            #pragma unroll
            for (int j=0;j<4;++j)
                acc2[i][j] = fmaf(wv[i], av[j], acc2[i][j]);
    }
    #pragma unroll
    for (int j=0;j<4;++j){
        const int h = hb + hq*4 + j;
        float4 v = make_float4(lrelu(acc2[0][j]+bs2[0]), lrelu(acc2[1][j]+bs2[1]),
                               lrelu(acc2[2][j]+bs2[2]), lrelu(acc2[3][j]+bs2[3]));
        *(float4*)(outp + (size_t)h*ostride + oq*4) = v;
    }
}

// ---------------------------------------------------------------- corr + d-MLP via split-bf16 MFMA
// wave owns 16 h-columns; no LDS, no barriers. GEMMs batched over (k,h) columns.
__global__ __launch_bounds__(256) void corr_mfma_kernel(
        float* __restrict__ cat, const float* __restrict__ lat2, const int* __restrict__ ci,
        const unsigned short* __restrict__ W16,
        const float* __restrict__ cb1, const float* __restrict__ cb2,
        const float* __restrict__ db1, const float* __restrict__ db2){
    const int t = threadIdx.x;
    const int lane = t & 63;
    const int l15 = lane & 15, lg = lane >> 4;
    const int hcol = blockIdx.x*64 + (t>>6)*16 + l15;
    const int srcA = (l15 + ((lg&1)*32)) * 4;     // bpermute byte index
    const int srcB = srcA + 64;
    const int sel = (lg>>1) & 1;

    // A-fragments: cw1 (2ot x 2kt), cw2 (2ot)
    s16x8 C1H[2][2], C1L[2][2], C2H[2], C2L[2];
    #pragma unroll
    for (int ot=0; ot<2; ++ot){
        #pragma unroll
        for (int kt=0; kt<2; ++kt){
            C1H[ot][kt] = *(const s16x8*)(W16 + (ot*2+kt)*512 + lane*8);
            C1L[ot][kt] = *(const s16x8*)(W16 + 2048 + (ot*2+kt)*512 + lane*8);
        }
        C2H[ot] = *(const s16x8*)(W16 + 4096 + ot*512 + lane*8);
        C2L[ot] = *(const s16x8*)(W16 + 5120 + ot*512 + lane*8);
    }
    // l1 column (this lane's h), c = kt*32+lg*8 .. +7
    float l1f[16];
    {
        const float* lr = cat + (size_t)hcol*128;
        *(float4*)&l1f[0]  = *(const float4*)(lr + lg*8);
        *(float4*)&l1f[4]  = *(const float4*)(lr + lg*8 + 4);
        *(float4*)&l1f[8]  = *(const float4*)(lr + 32 + lg*8);
        *(float4*)&l1f[12] = *(const float4*)(lr + 32 + lg*8 + 4);
    }
    float cb1r[8], cb2r[8];
    #pragma unroll
    for (int i=0;i<8;++i){
        cb1r[i] = cb1[(i>>2)*16 + lg*4 + (i&3)];
        cb2r[i] = cb2[(i>>2)*16 + lg*4 + (i&3)];
    }
    float agg[8] = {};
    const f32x4 z = {0.f,0.f,0.f,0.f};

    // prefetch k=0 gather
    int idx = ci[hcol];
    float4 g0 = *(const float4*)(lat2 + (size_t)idx*64 + lg*8);
    float4 g1 = *(const float4*)(lat2 + (size_t)idx*64 + lg*8 + 4);
    float4 g2v = *(const float4*)(lat2 + (size_t)idx*64 + 32 + lg*8);
    float4 g3 = *(const float4*)(lat2 + (size_t)idx*64 + 32 + lg*8 + 4);

    for (int k=0; k<KC; ++k){
        float p[16];
        p[0]=l1f[0]*g0.x; p[1]=l1f[1]*g0.y; p[2]=l1f[2]*g0.z; p[3]=l1f[3]*g0.w;
        p[4]=l1f[4]*g1.x; p[5]=l1f[5]*g1.y; p[6]=l1f[6]*g1.z; p[7]=l1f[7]*g1.w;
        p[8]=l1f[8]*g2v.x; p[9]=l1f[9]*g2v.y; p[10]=l1f[10]*g2v.z; p[11]=l1f[11]*g2v.w;
        p[12]=l1f[12]*g3.x; p[13]=l1f[13]*g3.y; p[14]=l1f[14]*g3.z; p[15]=l1f[15]*g3.w;
        if (k+1 < KC){
            idx = ci[(k+1)*HL + hcol];
            g0 = *(const float4*)(lat2 + (size_t)idx*64 + lg*8);
            g1 = *(const float4*)(lat2 + (size_t)idx*64 + lg*8 + 4);
            g2v = *(const float4*)(lat2 + (size_t)idx*64 + 32 + lg*8);
            g3 = *(const float4*)(lat2 + (size_t)idx*64 + 32 + lg*8 + 4);
        }
        pk8 BH[2], BL[2];
        #pragma unroll
        for (int kt=0; kt<2; ++kt){
            #pragma unroll
            for (int q=0; q<4; ++q){
                unsigned short h0,l0,h1,l1v;
                bf16_hilo(p[kt*8+2*q], h0, l0);
                bf16_hilo(p[kt*8+2*q+1], h1, l1v);
                BH[kt].u[q] = pk2(h0,h1);
                BL[kt].u[q] = pk2(l0,l1v);
            }
        }
        // GEMM1: m1[32 o][16 h]
        f32x4 a1[2] = {z, z};
        #pragma unroll
        for (int kt=0; kt<2; ++kt){
            a1[0] = __builtin_amdgcn_mfma_f32_16x16x32_bf16(C1H[0][kt], BH[kt].v, a1[0], 0,0,0);
            a1[1] = __builtin_amdgcn_mfma_f32_16x16x32_bf16(C1H[1][kt], BH[kt].v, a1[1], 0,0,0);
            a1[0] = __builtin_amdgcn_mfma_f32_16x16x32_bf16(C1H[0][kt], BL[kt].v, a1[0], 0,0,0);
            a1[1] = __builtin_amdgcn_mfma_f32_16x16x32_bf16(C1H[1][kt], BL[kt].v, a1[1], 0,0,0);
            a1[0] = __builtin_amdgcn_mfma_f32_16x16x32_bf16(C1L[0][kt], BH[kt].v, a1[0], 0,0,0);
            a1[1] = __builtin_amdgcn_mfma_f32_16x16x32_bf16(C1L[1][kt], BH[kt].v, a1[1], 0,0,0);
        }
        // m1 -> bf16 hi/lo row-pair packs
        unsigned mh[2][2], ml[2][2];
        #pragma unroll
        for (int ot=0; ot<2; ++ot){
            #pragma unroll
            for (int j=0; j<2; ++j){
                unsigned short h0,l0,h1,l1v;
                bf16_hilo(lrelu(a1[ot][2*j]   + cb1r[ot*4+2*j]),   h0, l0);
                bf16_hilo(lrelu(a1[ot][2*j+1] + cb1r[ot*4+2*j+1]), h1, l1v);
                mh[ot][j] = pk2(h0,h1);
                ml[ot][j] = pk2(l0,l1v);
            }
        }
        pk8 B2H = shuf32(mh[0], mh[1], sel, srcA, srcB);
        pk8 B2L = shuf32(ml[0], ml[1], sel, srcA, srcB);
        // GEMM2
        f32x4 a2[2] = {z, z};
        a2[0] = __builtin_amdgcn_mfma_f32_16x16x32_bf16(C2H[0], B2H.v, a2[0], 0,0,0);
        a2[1] = __builtin_amdgcn_mfma_f32_16x16x32_bf16(C2H[1], B2H.v, a2[1], 0,0,0);
        a2[0] = __builtin_amdgcn_mfma_f32_16x16x32_bf16(C2H[0], B2L.v, a2[0], 0,0,0);
        a2[1] = __builtin_amdgcn_mfma_f32_16x16x32_bf16(C2H[1], B2L.v, a2[1], 0,0,0);
        a2[0] = __builtin_amdgcn_mfma_f32_16x16x32_bf16(C2L[0], B2H.v, a2[0], 0,0,0);
        a2[1] = __builtin_amdgcn_mfma_f32_16x16x32_bf16(C2L[1], B2H.v, a2[1], 0,0,0);
        #pragma unroll
        for (int i=0;i<8;++i)
            agg[i] += lrelu(a2[i>>2][i&3] + cb2r[i]);
    }
    // ---- d-MLP (once per wave)
    #pragma unroll
    for (int i=0;i<8;++i) agg[i] *= (1.0f/32.0f);
    unsigned agH[2][2], agL[2][2];
    #pragma unroll
    for (int ot=0; ot<2; ++ot)
        #pragma unroll
        for (int j=0; j<2; ++j){
            unsigned short h0,l0,h1,l1v;
            bf16_hilo(agg[ot*4+2*j],   h0, l0);
            bf16_hilo(agg[ot*4+2*j+1], h1, l1v);
            agH[ot][j] = pk2(h0,h1); agL[ot][j] = pk2(l0,l1v);
        }
    pk8 B3H = shuf32(agH[0], agH[1], sel, srcA, srcB);
    pk8 B3L = shuf32(agL[0], agL[1], sel, srcA, srcB);
    float db1r[16], db2r[16];
    #pragma unroll
    for (int i=0;i<16;++i){
        db1r[i] = db1[(i>>2)*16 + lg*4 + (i&3)];
        db2r[i] = db2[(i>>2)*16 + lg*4 + (i&3)];
    }
    // d1 = lrelu(dw1 @ agg + db1): 4 o-tiles
    unsigned d1H[4][2], d1L[4][2];
    #pragma unroll
    for (int ot=0; ot<4; ++ot){
        s16x8 AH = *(const s16x8*)(W16 + 6144 + ot*512 + lane*8);
        s16x8 AL = *(const s16x8*)(W16 + 8192 + ot*512 + lane*8);
        f32x4 a3 = z;
        a3 = __builtin_amdgcn_mfma_f32_16x16x32_bf16(AH, B3H.v, a3, 0,0,0);
        a3 = __builtin_amdgcn_mfma_f32_16x16x32_bf16(AH, B3L.v, a3, 0,0,0);
        a3 = __builtin_amdgcn_mfma_f32_16x16x32_bf16(AL, B3H.v, a3, 0,0,0);
        #pragma unroll
        for (int j=0;j<2;++j){
            unsigned short h0,l0,h1,l1v;
            bf16_hilo(lrelu(a3[2*j]   + db1r[ot*4+2*j]),   h0, l0);
            bf16_hilo(lrelu(a3[2*j+1] + db1r[ot*4+2*j+1]), h1, l1v);
            d1H[ot][j] = pk2(h0,h1); d1L[ot][j] = pk2(l0,l1v);
        }
    }
    // d2 = lrelu(dw2 @ d1 + db2): K=64 (2 kt), 4 o-tiles
    f32x4 a4[4] = {z,z,z,z};
    #pragma unroll
    for (int kt=0; kt<2; ++kt){
        pk8 B4H = shuf32(d1H[kt*2], d1H[kt*2+1], sel, srcA, srcB);
        pk8 B4L = shuf32(d1L[kt*2], d1L[kt*2+1], sel, srcA, srcB);
        #pragma unroll
        for (int ot=0; ot<4; ++ot){
            s16x8 AH = *(const s16x8*)(W16 + 10240 + (ot*2+kt)*512 + lane*8);
            s16x8 AL = *(const s16x8*)(W16 + 14336 + (ot*2+kt)*512 + lane*8);
            a4[ot] = __builtin_amdgcn_mfma_f32_16x16x32_bf16(AH, B4H.v, a4[ot], 0,0,0);
            a4[ot] = __builtin_amdgcn_mfma_f32_16x16x32_bf16(AH, B4L.v, a4[ot], 0,0,0);
            a4[ot] = __builtin_amdgcn_mfma_f32_16x16x32_bf16(AL, B4H.v, a4[ot], 0,0,0);
        }
    }
    float* dst = cat + (size_t)hcol*128 + 64;
    #pragma unroll
    for (int ot=0; ot<4; ++ot){
        float4 v = make_float4(lrelu(a4[ot][0]+db2r[ot*4+0]), lrelu(a4[ot][1]+db2r[ot*4+1]),
                               lrelu(a4[ot][2]+db2r[ot*4+2]), lrelu(a4[ot][3]+db2r[ot*4+3]));
        *(float4*)(dst + ot*16 + lg*4) = v;
    }
}

// ---------------------------------------------------------------- cat -> bf16 hi/lo
__global__ __launch_bounds__(256) void cvt_cat_kernel(const float* __restrict__ cat,
        unsigned short* __restrict__ cH, unsigned short* __restrict__ cL){
    const size_t i = (size_t)blockIdx.x*256 + threadIdx.x;
    const float4 v = *(const float4*)(cat + i*4);
    unsigned short h0,h1,h2,h3,l0,l1,l2,l3;
    bf16_hilo(v.x,h0,l0); bf16_hilo(v.y,h1,l1); bf16_hilo(v.z,h2,l2); bf16_hilo(v.w,h3,l3);
    *(ushort4*)(cH + i*4) = make_ushort4(h0,h1,h2,h3);
    *(ushort4*)(cL + i*4) = make_ushort4(l0,l1,l2,l3);
}

// ---------------------------------------------------------------- blur_p via split-bf16 MFMA
__global__ __launch_bounds__(256) void blur_p_mfma_kernel(
        const unsigned short* __restrict__ catH, const unsigned short* __restrict__ catL,
        const int* __restrict__ nb,
        const unsigned short* __restrict__ pw1fH, const unsigned short* __restrict__ pw1fL,
        const float* __restrict__ pb1,
        const unsigned short* __restrict__ pw2fH, const unsigned short* __restrict__ pw2fL,
        const float* __restrict__ pb2,
        float* __restrict__ p){
    __shared__ unsigned short GH[8192];
    __shared__ unsigned short GLb[8192];
    __shared__ int sidx[NNB][64];
    const int t = threadIdx.x;
    const int hb = blockIdx.x*64;
    const int w = t>>6, lane = t&63;
    const int l15 = lane&15, lg = lane>>4;
    for (int e=t; e<NNB*64; e+=256) sidx[e>>6][e&63] = nb[(e>>6)*HL + hb + (e&63)];
    f32x4 acc1[2][4];
    #pragma unroll
    for (int ot=0;ot<2;++ot)
        #pragma unroll
        for (int ht=0;ht<4;++ht) acc1[ot][ht] = (f32x4){0.f,0.f,0.f,0.f};
    __syncthreads();
    for (int nn=0; nn<NNB; ++nn){
        if (nn) __syncthreads();
        #pragma unroll
        for (int i=0;i<4;++i){
            const int j2 = t + 256*i;
            const int row = j2>>4, q = j2&15;
            const int g = sidx[nn][row];
            const uint4 vh = *(const uint4*)(catH + (size_t)g*128 + q*8);
            const uint4 vl = *(const uint4*)(catL + (size_t)g*128 + q*8);
            const int d = row*128 + ((q ^ (row&7))*8);
            *(uint4*)(GH + d) = vh;
            *(uint4*)(GLb + d) = vl;
        }
        __syncthreads();
        #pragma unroll
        for (int kt=0; kt<4; ++kt){
            s16x8 BH[4], BL[4];
            #pragma unroll
            for (int ht=0; ht<4; ++ht){
                const int h = ht*16 + l15;
                const int q = kt*4 + lg;
                const int d = h*128 + ((q ^ (h&7))*8);
                BH[ht] = *(const s16x8*)(GH + d);
                BL[ht] = *(const s16x8*)(GLb + d);
            }
            s16x8 AH[2], AL[2];
            #pragma unroll
            for (int ot=0; ot<2; ++ot){
                const size_t fo = ((size_t)((nn*4 + kt)*8 + (w*2+ot)))*512 + lane*8;
                AH[ot] = *(const s16x8*)(pw1fH + fo);
                AL[ot] = *(const s16x8*)(pw1fL + fo);
            }
            #pragma unroll
            for (int ht=0; ht<4; ++ht)
                #pragma unroll
                for (int ot=0; ot<2; ++ot)
                    acc1[ot][ht] = __builtin_amdgcn_mfma_f32_16x16x32_bf16(AH[ot], BH[ht], acc1[ot][ht], 0,0,0);
            #pragma unroll
            for (int ht=0; ht<4; ++ht)
                #pragma unroll
                for (int ot=0; ot<2; ++ot)
                    acc1[ot][ht] = __builtin_amdgcn_mfma_f32_16x16x32_bf16(AH[ot], BL[ht], acc1[ot][ht], 0,0,0);
            #pragma unroll
            for (int ht=0; ht<4; ++ht)
                #pragma unroll
                for (int ot=0; ot<2; ++ot)
                    acc1[ot][ht] = __builtin_amdgcn_mfma_f32_16x16x32_bf16(AL[ot], BH[ht], acc1[ot][ht], 0,0,0);
        }
    }
    __syncthreads();
    #pragma unroll
    for (int ot=0; ot<2; ++ot){
        const int o0 = (w*2+ot)*16 + lg*4;
        const float b0 = pb1[o0], b1v = pb1[o0+1], b2v = pb1[o0+2], b3v = pb1[o0+3];
        const int q = o0>>3;
        #pragma unroll
        for (int ht=0; ht<4; ++ht){
            const int h = ht*16 + l15;
            unsigned short th[4], tl[4];
            bf16_hilo(lrelu(acc1[ot][ht][0] + b0), th[0], tl[0]);
            bf16_hilo(lrelu(acc1[ot][ht][1] + b1v), th[1], tl[1]);
            bf16_hilo(lrelu(acc1[ot][ht][2] + b2v), th[2], tl[2]);
            bf16_hilo(lrelu(acc1[ot][ht][3] + b3v), th[3], tl[3]);
            const int d = h*128 + ((q ^ (h&7))*8) + (o0&7);
            *(ushort4*)(GH + d)  = make_ushort4(th[0],th[1],th[2],th[3]);
            *(ushort4*)(GLb + d) = make_ushort4(tl[0],tl[1],tl[2],tl[3]);
        }
    }
    __syncthreads();
    f32x4 acc2[2][4];
    #pragma unroll
    for (int ot=0;ot<2;++ot)
        #pragma unroll
        for (int ht=0;ht<4;++ht) acc2[ot][ht] = (f32x4){0.f,0.f,0.f,0.f};
    #pragma unroll
    for (int kt=0; kt<4; ++kt){
        s16x8 BH[4], BL[4];
        #pragma unroll
        for (int ht=0; ht<4; ++ht){
            const int h = ht*16 + l15;
            const int q = kt*4 + lg;
            const int d = h*128 + ((q ^ (h&7))*8);
            BH[ht] = *(const s16x8*)(GH + d);
            BL[ht] = *(const s16x8*)(GLb + d);
        }
        s16x8 AH[2], AL[2];
        #pragma unroll
        for (int ot=0; ot<2; ++ot){
            const size_t fo = ((size_t)(kt*8 + (w*2+ot)))*512 + lane*8;
            AH[ot] = *(const s16x8*)(pw2fH + fo);
            AL[ot] = *(const s16x8*)(pw2fL + fo);
        }
        #pragma unroll
        for (int ht=0; ht<4; ++ht)
            #pragma unroll
            for (int ot=0; ot<2; ++ot)
                acc2[ot][ht] = __builtin_amdgcn_mfma_f32_16x16x32_bf16(AH[ot], BH[ht], acc2[ot][ht], 0,0,0);
        #pragma unroll
        for (int ht=0; ht<4; ++ht)
            #pragma unroll
            for (int ot=0; ot<2; ++ot)
                acc2[ot][ht] = __builtin_amdgcn_mfma_f32_16x16x32_bf16(AH[ot], BL[ht], acc2[ot][ht], 0,0,0);
        #pragma unroll
        for (int ht=0; ht<4; ++ht)
            #pragma unroll
            for (int ot=0; ot<2; ++ot)
                acc2[ot][ht] = __builtin_amdgcn_mfma_f32_16x16x32_bf16(AL[ot], BH[ht], acc2[ot][ht], 0,0,0);
    }
    #pragma unroll
    for (int ot=0; ot<2; ++ot){
        const int o0 = (w*2+ot)*16 + lg*4;
        const float b0 = pb2[o0], b1v = pb2[o0+1], b2v = pb2[o0+2], b3v = pb2[o0+3];
        #pragma unroll
        for (int ht=0; ht<4; ++ht){
            const int h = hb + ht*16 + l15;
            float4 v = make_float4(lrelu(acc2[ot][ht][0] + b0), lrelu(acc2[ot][ht][1] + b1v),
                                   lrelu(acc2[ot][ht][2] + b2v), lrelu(acc2[ot][ht][3] + b3v));
            *(float4*)(p + (size_t)h*128 + o0) = v;
        }
    }
}

// ---------------------------------------------------------------- head: slice + 128->128->64->3
__global__ __launch_bounds__(256) void head_kernel(
        const float* __restrict__ p, const float* __restrict__ bary, const int* __restrict__ off,
        const float* __restrict__ fw2T, const float* __restrict__ fb2,
        const float* __restrict__ fw3T, const float* __restrict__ fb3,
        const float* __restrict__ fw4, const float* __restrict__ fb4,
        float* __restrict__ out){
    __shared__ __align__(16) float S[8704];
    __shared__ __align__(16) float WW[8192];
    __shared__ float SB[5][64];
    __shared__ int   SO[5][64];
    const int t = threadIdx.x;
    const int pb = blockIdx.x*64;
    const int oq8 = t>>4, pq = t&15;
    const int q5 = t&31, rgrp5 = t>>5;
    if (t<64){
        #pragma unroll
        for (int j=0;j<5;++j){ SB[j][t]=bary[j*NPTS+pb+t]; SO[j][t]=off[j*NPTS+pb+t]; }
    }
    __syncthreads();
    #pragma unroll
    for (int i=0;i<8;++i){
        const int row = rgrp5 + 8*i;
        float4 sa = make_float4(0.f,0.f,0.f,0.f);
        #pragma unroll
        for (int j=0;j<5;++j){
            const float4 v = *(const float4*)(p + (size_t)SO[j][row]*128 + q5*4);
            const float b = SB[j][row];
            sa.x += b*v.x; sa.y += b*v.y; sa.z += b*v.z; sa.w += b*v.w;
        }
        S[(q5*4+0)*68 + row] = sa.x;
        S[(q5*4+1)*68 + row] = sa.y;
        S[(q5*4+2)*68 + row] = sa.z;
        S[(q5*4+3)*68 + row] = sa.w;
    }
    float acc1[8][4] = {};
    #pragma unroll 1
    for (int hf=0;hf<2;++hf){
        if (hf==1) __syncthreads();
        for (int e=t;e<2048;e+=256)
            *(float4*)(WW + e*4) = *(const float4*)(fw2T + hf*8192 + e*4);
        __syncthreads();
        #pragma unroll 4
        for (int c=0;c<64;++c){
            const float4 a4 = *(const float4*)(S + (hf*64+c)*68 + pq*4);
            const float4 wa = *(const float4*)(WW + c*128 + oq8*8);
            const float4 wb = *(const float4*)(WW + c*128 + oq8*8 + 4);
            const float av[4]={a4.x,a4.y,a4.z,a4.w};
            const float wv[8]={wa.x,wa.y,wa.z,wa.w,wb.x,wb.y,wb.z,wb.w};
            #pragma unroll
            for (int i=0;i<8;++i)
                #pragma unroll
                for (int j=0;j<4;++j)
                    acc1[i][j] = fmaf(wv[i], av[j], acc1[i][j]);
        }
    }
    __syncthreads();
    float bf2[8];
    #pragma unroll
    for (int i=0;i<8;++i) bf2[i]=fb2[oq8*8+i];
    #pragma unroll
    for (int i=0;i<8;++i){
        const int o = oq8*8+i;
        float4 v = make_float4(lrelu(acc1[i][0]+bf2[i]), lrelu(acc1[i][1]+bf2[i]),
                               lrelu(acc1[i][2]+bf2[i]), lrelu(acc1[i][3]+bf2[i]));
        *(float4*)(S + o*68 + pq*4) = v;
    }
    for (int e=t;e<2048;e+=256)
        *(float4*)(WW + e*4) = *(const float4*)(fw3T + e*4);
    __syncthreads();
    const int od = t>>4;
    float bf3[4];
    #pragma unroll
    for (int i=0;i<4;++i) bf3[i]=fb3[od*4+i];
    float a2[4][4] = {};
    #pragma unroll 4
    for (int c=0;c<128;++c){
        const float4 a4 = *(const float4*)(S + c*68 + pq*4);
        const float4 w4 = *(const float4*)(WW + c*64 + od*4);
        const float av[4]={a4.x,a4.y,a4.z,a4.w};
        const float wv[4]={w4.x,w4.y,w4.z,w4.w};
        #pragma unroll
        for (int i=0;i<4;++i)
            #pragma unroll
            for (int j=0;j<4;++j)
                a2[i][j] = fmaf(wv[i], av[j], a2[i][j]);
    }
    __syncthreads();
    #pragma unroll
    for (int i=0;i<4;++i){
        float4 v = make_float4(lrelu(a2[i][0]+bf3[i]), lrelu(a2[i][1]+bf3[i]),
                               lrelu(a2[i][2]+bf3[i]), lrelu(a2[i][3]+bf3[i]));
        *(float4*)(S + (od*4+i)*68 + pq*4) = v;
    }
    __syncthreads();
    if (t < 192){
        const int r = t>>6, pp = t&63;
        float a = fb4[r];
        #pragma unroll 8
        for (int c=0;c<64;++c) a += fw4[r*64+c]*S[c*68+pp];
        out[r*NPTS + pb + pp] = a;
    }
}

// ================================================================ launch
extern "C" void kernel_launch(void* const* d_in, const int* in_sizes, int n_in,
                              void* d_out, int out_size, void* d_ws, size_t ws_size,
                              hipStream_t stream){
    const float* pc1   = (const float*)d_in[0];
    const float* pc2   = (const float*)d_in[1];
    const float* el1   = (const float*)d_in[2];
    const float* el2   = (const float*)d_in[3];
    const float* bary1 = (const float*)d_in[4];
    const float* bary2 = (const float*)d_in[5];
    const int*   off1  = (const int*)d_in[6];
    const int*   off2  = (const int*)d_in[7];
    const int*   nb1   = (const int*)d_in[8];
    const int*   nb2   = (const int*)d_in[9];
    const int*   ci    = (const int*)d_in[10];
    const float* w1    = (const float*)d_in[11];
    const float* b1    = (const float*)d_in[12];
    const float* w2    = (const float*)d_in[13];
    const float* b2    = (const float*)d_in[14];
    const float* w3    = (const float*)d_in[15];
    const float* b3    = (const float*)d_in[16];
    const float* sw1   = (const float*)d_in[17];
    const float* sb1   = (const float*)d_in[18];
    const float* sw2   = (const float*)d_in[19];
    const float* sb2   = (const float*)d_in[20];
    const float* cw1   = (const float*)d_in[21];
    const float* cb1   = (const float*)d_in[22];
    const float* cw2   = (const float*)d_in[23];
    const float* cb2   = (const float*)d_in[24];
    const float* dw1   = (const float*)d_in[25];
    const float* db1   = (const float*)d_in[26];
    const float* dw2   = (const float*)d_in[27];
    const float* db2   = (const float*)d_in[28];
    const float* pw1   = (const float*)d_in[29];
    const float* pb1   = (const float*)d_in[30];
    const float* pw2   = (const float*)d_in[31];
    const float* pb2   = (const float*)d_in[32];
    const float* fw2   = (const float*)d_in[33];
    const float* fb2   = (const float*)d_in[34];
    const float* fw3   = (const float*)d_in[35];
    const float* fb3   = (const float*)d_in[36];
    const float* fw4   = (const float*)d_in[37];
    const float* fb4   = (const float*)d_in[38];
    float* out = (float*)d_out;

    float* ws    = (float*)d_ws;
    float* pf1   = ws;                    // N*68
    float* pf2   = pf1   + 2228224;
    float* latA  = pf2   + 2228224;       // H*68
    float* latB  = latA  + 2228224;
    float* catb  = latB  + 2228224;       // H*128
    float* lat2p = catb  + 4194304;       // H*64
    float* sw1t  = lat2p + 2097152;       // 65280
    float* pw1fS = sw1t  + 65280;         // 245760 floats = 491520 ushorts
    float* sw2T  = pw1fS + 245760;        // 4096
    float* cwfS  = sw2T  + 4096;          // 9216 floats = 18432 ushorts
    float* pw2fS = cwfS  + 9216;          // 16384 floats = 32768 ushorts
    float* fw2T  = pw2fS + 16384;         // 16384
    float* fw3T  = fw2T  + 16384;         // 8192
    float* pbuf  = pf1;                   // p (H*128) reuses pf1+pf2

    unsigned short* pw1fH = (unsigned short*)pw1fS;
    unsigned short* pw1fL = pw1fH + 245760;
    unsigned short* W16   = (unsigned short*)cwfS;
    unsigned short* pw2fH = (unsigned short*)pw2fS;
    unsigned short* pw2fL = pw2fH + 16384;
    unsigned short* catH  = (unsigned short*)latA;   // lattices dead by cvt time
    unsigned short* catL  = catH + (size_t)HL*128;

    zero_kernel<<<4352, 256, 0, stream>>>((float4*)latA);
    repack_kernel<<<960, 256, 0, stream>>>(sw1, pw1, sw2, cw1, cw2, dw1, dw2, pw2, fw2, fw3,
                                           sw1t, pw1fH, pw1fL, sw2T, W16,
                                           pw2fH, pw2fL, fw2T, fw3T);

    mlp3_kernel<<<128, 256, 0, stream>>>(pc1, el1, w1,b1,w2,b2,w3,b3, pf1);
    mlp3_kernel<<<128, 256, 0, stream>>>(pc2, el2, w1,b1,w2,b2,w3,b3, pf2);

    splat_kernel<<<40960, 256, 0, stream>>>(pf1, bary1, off1, latA);
    splat_kernel<<<40960, 256, 0, stream>>>(pf2, bary2, off2, latB);

    blur_s_kernel<<<512, 256, 0, stream>>>(latA, nb1, sw1t, sb1, sw2T, sb2, catb, 128);
    blur_s_kernel<<<512, 256, 0, stream>>>(latB, nb2, sw1t, sb1, sw2T, sb2, lat2p, 64);

    corr_mfma_kernel<<<512, 256, 0, stream>>>(catb, lat2p, ci, W16, cb1, cb2, db1, db2);

    cvt_cat_kernel<<<4096, 256, 0, stream>>>(catb, catH, catL);

    blur_p_mfma_kernel<<<512, 256, 0, stream>>>(catH, catL, nb1, pw1fH, pw1fL, pb1,
                                                pw2fH, pw2fL, pb2, pbuf);

    head_kernel<<<512, 256, 0, stream>>>(pbuf, bary1, off1, fw2T,fb2,fw3T,fb3,fw4,fb4, out);
}

// Round 6
// 424.894 us; speedup vs baseline: 37.7036x; 1.2243x over previous
//
#include <hip/hip_runtime.h>

#define NPTS 32768
#define HL   32768
#define NNB  15
#define KC   32

typedef __attribute__((ext_vector_type(8))) short s16x8;
typedef __attribute__((ext_vector_type(4))) float f32x4;

typedef union { s16x8 v; unsigned u[4]; } pk8;

__device__ __forceinline__ float lrelu(float x){ return x > 0.0f ? x : 0.1f*x; }

__device__ __forceinline__ unsigned short bf16r(float x){
    union { float f; unsigned u; } a; a.f = x;
    unsigned r = a.u + 0x7FFF + ((a.u >> 16) & 1);
    return (unsigned short)(r >> 16);
}
// round-to-nearest-even bf16 split: x ~= hi + lo
__device__ __forceinline__ void bf16_hilo(float x, unsigned short& hi, unsigned short& lo){
    hi = bf16r(x);
    union { float f; unsigned u; } b; b.u = ((unsigned)hi) << 16;
    lo = bf16r(x - b.f);
}
__device__ __forceinline__ unsigned pk2(unsigned short a, unsigned short b){
    return (unsigned)a | ((unsigned)b << 16);
}

// rows lg*8+0..7 of a 32-row column (2 ot-tiles packed p0/p1, u32 = row pair) -> B frag
__device__ __forceinline__ pk8 shuf32(const unsigned* p0, const unsigned* p1,
                                      int sel, int srcA, int srcB){
    pk8 o;
    int a0 = __builtin_amdgcn_ds_bpermute(srcA, (int)p0[0]);
    int a1 = __builtin_amdgcn_ds_bpermute(srcA, (int)p1[0]);
    o.u[0] = (unsigned)(sel ? a1 : a0);
    int b0 = __builtin_amdgcn_ds_bpermute(srcA, (int)p0[1]);
    int b1 = __builtin_amdgcn_ds_bpermute(srcA, (int)p1[1]);
    o.u[1] = (unsigned)(sel ? b1 : b0);
    int c0 = __builtin_amdgcn_ds_bpermute(srcB, (int)p0[0]);
    int c1 = __builtin_amdgcn_ds_bpermute(srcB, (int)p1[0]);
    o.u[2] = (unsigned)(sel ? c1 : c0);
    int d0 = __builtin_amdgcn_ds_bpermute(srcB, (int)p0[1]);
    int d1 = __builtin_amdgcn_ds_bpermute(srcB, (int)p1[1]);
    o.u[3] = (unsigned)(sel ? d1 : d0);
    return o;
}

// ---------------------------------------------------------------- zero
__global__ void zero_kernel(float4* __restrict__ buf){
    buf[(size_t)blockIdx.x*256 + threadIdx.x] = make_float4(0.f,0.f,0.f,0.f);
}

// ---------------------------------------------------------------- repack weights
// SW16 layout (ushort offs): featH 0 (61440) featL 61440 | elH 122880 (4096) elL 126976
//                            sw2H 131072 (4096) sw2L 135168   total 139264
__global__ void repack_kernel(const float* __restrict__ sw1, const float* __restrict__ pw1,
                              const float* __restrict__ sw2, const float* __restrict__ cw1,
                              const float* __restrict__ cw2, const float* __restrict__ dw1,
                              const float* __restrict__ dw2, const float* __restrict__ pw2,
                              const float* __restrict__ fw2, const float* __restrict__ fw3,
                              unsigned short* __restrict__ SW16,
                              unsigned short* __restrict__ pw1fH, unsigned short* __restrict__ pw1fL,
                              unsigned short* __restrict__ W16,
                              unsigned short* __restrict__ pw2fH, unsigned short* __restrict__ pw2fL,
                              float* __restrict__ fw2T, float* __restrict__ fw3T){
    int tid = blockIdx.x*256 + threadIdx.x;
    // blur_s feat frags: f = nn*2+kt (30), ot (4)
    if (tid < 61440){
        int b = tid&7, ln = (tid>>3)&63, ot = (tid>>9)&3, f = tid>>11;
        int kt = f&1, nn = f>>1;
        int o = ot*16 + (ln&15), k = kt*32 + (ln>>4)*8 + b, c = k + 4;
        unsigned short hi, lo; bf16_hilo(sw1[(o*68+c)*15+nn], hi, lo);
        SW16[tid] = hi; SW16[61440+tid] = lo;
    }
    // blur_s el frags: kt2 (2), ot (4); k2 = nn*4+c, pad >=60
    if (tid < 4096){
        int b = tid&7, ln = (tid>>3)&63, ot = (tid>>9)&3, kt2 = tid>>11;
        int o = ot*16 + (ln&15), k2 = kt2*32 + (ln>>4)*8 + b;
        float v = (k2 < 60) ? sw1[(o*68 + (k2&3))*15 + (k2>>2)] : 0.f;
        unsigned short hi, lo; bf16_hilo(v, hi, lo);
        SW16[122880+tid] = hi; SW16[126976+tid] = lo;
    }
    // blur_s sw2 frags: kt (2), ot (4)
    if (tid < 4096){
        int b = tid&7, ln = (tid>>3)&63, ot = (tid>>9)&3, kt = tid>>11;
        int o = ot*16 + (ln&15), k = kt*32 + (ln>>4)*8 + b;
        unsigned short hi, lo; bf16_hilo(sw2[o*64+k], hi, lo);
        SW16[131072+tid] = hi; SW16[135168+tid] = lo;
    }
    // pw1 MFMA A-fragments (hi/lo): frag idx = ((nn*4+kt)*8+ot), lane-major
    if (tid < 245760){
        int b = tid & 7, ln = (tid>>3)&63, ot = (tid>>9)&7, kt = (tid>>12)&3, nn = tid>>14;
        int o = ot*16 + (ln&15), k = kt*32 + (ln>>4)*8 + b;
        float v = pw1[(o*128 + k)*15 + nn];
        unsigned short hi, lo; bf16_hilo(v, hi, lo);
        pw1fH[tid] = hi; pw1fL[tid] = lo;
    }
    if (tid < 16384){
        int b = tid & 7, ln = (tid>>3)&63, ot = (tid>>9)&7, kt = (tid>>12)&3;
        int o = ot*16 + (ln&15), k = kt*32 + (ln>>4)*8 + b;
        float v = pw2[o*128 + k];
        unsigned short hi, lo; bf16_hilo(v, hi, lo);
        pw2fH[tid] = hi; pw2fL[tid] = lo;
    }
    // corr/d-MLP weight fragments (hi/lo) into W16
    if (tid < 2048){   // cw1 (32x64): frag f=ot*2+kt
        int b = tid&7, ln = (tid>>3)&63, f = tid>>9;
        int ot = f>>1, kt = f&1;
        int o = ot*16 + (ln&15), c = kt*32 + (ln>>4)*8 + b;
        unsigned short hi, lo; bf16_hilo(cw1[o*64+c], hi, lo);
        W16[tid] = hi; W16[2048+tid] = lo;
    }
    if (tid < 1024){   // cw2 (32x32): frag f=ot
        int b = tid&7, ln = (tid>>3)&63, ot = tid>>9;
        int o = ot*16 + (ln&15), c = (ln>>4)*8 + b;
        unsigned short hi, lo; bf16_hilo(cw2[o*32+c], hi, lo);
        W16[4096+tid] = hi; W16[5120+tid] = lo;
    }
    if (tid < 2048){   // dw1 (64x32): frag f=ot (4)
        int b = tid&7, ln = (tid>>3)&63, ot = tid>>9;
        int o = ot*16 + (ln&15), c = (ln>>4)*8 + b;
        unsigned short hi, lo; bf16_hilo(dw1[o*32+c], hi, lo);
        W16[6144+tid] = hi; W16[8192+tid] = lo;
    }
    if (tid < 4096){   // dw2 (64x64): frag f=ot*2+kt (8)
        int b = tid&7, ln = (tid>>3)&63, f = tid>>9;
        int ot = f>>1, kt = f&1;
        int o = ot*16 + (ln&15), c = kt*32 + (ln>>4)*8 + b;
        unsigned short hi, lo; bf16_hilo(dw2[o*64+c], hi, lo);
        W16[10240+tid] = hi; W16[14336+tid] = lo;
    }
    if (tid < 16384){ int c = tid>>7, o = tid&127; fw2T[tid] = fw2[o*128+c]; }
    if (tid < 8192){ int c = tid>>6, o = tid&63; fw3T[tid] = fw3[o*128+c]; }
}

// ---------------------------------------------------------------- point MLP (3->32->32->64) + el pack
__global__ __launch_bounds__(256) void mlp3_kernel(
        const float* __restrict__ pc, const float* __restrict__ el,
        const float* __restrict__ w1, const float* __restrict__ b1,
        const float* __restrict__ w2, const float* __restrict__ b2,
        const float* __restrict__ w3, const float* __restrict__ b3,
        float* __restrict__ pfeat){
    __shared__ float W1[96], W2s[1024], W3s[2048], B1[32], B2[32], B3[64];
    const int t = threadIdx.x;
    for (int e=t;e<96;e+=256)   W1[e]=w1[e];
    for (int e=t;e<1024;e+=256) W2s[e]=w2[e];
    for (int e=t;e<2048;e+=256) W3s[e]=w3[e];
    if (t<32){ B1[t]=b1[t]; B2[t]=b2[t]; }
    if (t<64){ B3[t]=b3[t]; }
    __syncthreads();
    const int n = blockIdx.x*256 + t;
    const float x0 = pc[n], x1 = pc[NPTS+n], x2 = pc[2*NPTS+n];
    float h1[32];
    #pragma unroll
    for (int o=0;o<32;++o)
        h1[o] = lrelu(B1[o] + W1[o*3]*x0 + W1[o*3+1]*x1 + W1[o*3+2]*x2);
    float h2[32];
    #pragma unroll
    for (int o=0;o<32;++o){
        float a = B2[o];
        #pragma unroll
        for (int c=0;c<32;++c) a += W2s[o*32+c]*h1[c];
        h2[o] = lrelu(a);
    }
    float* row = pfeat + (size_t)n*68;
    *(float4*)row = make_float4(el[n], el[NPTS+n], el[2*NPTS+n], el[3*NPTS+n]);
    #pragma unroll
    for (int o4=0;o4<16;++o4){
        float tmp[4];
        #pragma unroll
        for (int q=0;q<4;++q){
            const int o = o4*4+q;
            float a = B3[o];
            #pragma unroll
            for (int c=0;c<32;++c) a += W3s[o*32+c]*h2[c];
            tmp[q] = lrelu(a);
        }
        *(float4*)(row + 4 + o4*4) = make_float4(tmp[0],tmp[1],tmp[2],tmp[3]);
    }
}

// ---------------------------------------------------------------- splat (scatter-add, wave-per-pair)
__global__ __launch_bounds__(256) void splat_kernel(
        const float* __restrict__ pfeat, const float* __restrict__ bary,
        const int* __restrict__ off, float* __restrict__ lat){
    const int pair = (blockIdx.x*256 + threadIdx.x) >> 6;   // 0 .. 5*NPTS-1
    const int lane = threadIdx.x & 63;
    const int n = pair & (NPTS-1);
    const int j = pair >> 15;
    const float b = bary[j*NPTS + n];
    const int o = off[j*NPTS + n];
    const float* row = pfeat + (size_t)n*68;
    float* dst = lat + (size_t)o*68;
    unsafeAtomicAdd(&dst[lane], b*row[lane]);
    if (lane < 4) unsafeAtomicAdd(&dst[64+lane], b*row[64+lane]);
}

// ---------------------------------------------------------------- lat f32 -> bf16 hi/lo, reordered [feat64][el4]
__global__ __launch_bounds__(256) void cvt_lat_kernel(const float* __restrict__ lat,
        unsigned short* __restrict__ lH, unsigned short* __restrict__ lL){
    const int idx = blockIdx.x*256 + threadIdx.x;   // HL*17
    const int r = idx / 17, j = idx - r*17;
    const int co = (j < 16) ? (4 + j*4) : 0;
    const float4 v = *(const float4*)(lat + (size_t)r*68 + co);
    unsigned short h0,h1,h2,h3,l0,l1,l2,l3;
    bf16_hilo(v.x,h0,l0); bf16_hilo(v.y,h1,l1); bf16_hilo(v.z,h2,l2); bf16_hilo(v.w,h3,l3);
    const int ko = j*4;
    *(ushort4*)(lH + (size_t)r*68 + ko) = make_ushort4(h0,h1,h2,h3);
    *(ushort4*)(lL + (size_t)r*68 + ko) = make_ushort4(l0,l1,l2,l3);
}

// ---------------------------------------------------------------- blur_s via split-bf16 MFMA
// block: 64 h, 4 waves; wave w owns o-tile w. K = 15nn x 64feat + 64el(packed) ; fused sw2.
__global__ __launch_bounds__(256) void blur_s_mfma_kernel(
        const unsigned short* __restrict__ latH, const unsigned short* __restrict__ latL,
        const int* __restrict__ nb,
        const unsigned short* __restrict__ SW16,
        const float* __restrict__ sb1, const float* __restrict__ sb2,
        float* __restrict__ outp, int ostride){
    __shared__ __align__(16) unsigned short GH[4096], GL[4096];
    __shared__ __align__(16) unsigned short EH[4096], EL[4096];
    __shared__ int sidx[NNB][64];
    const int t = threadIdx.x;
    const int hb = blockIdx.x*64;
    const int w = t>>6, lane = t&63;
    const int l15 = lane&15, lg = lane>>4;
    for (int e=t; e<NNB*64; e+=256) sidx[e>>6][e&63] = nb[(e>>6)*HL + hb + (e&63)];
    {   // zero E (pad k>=60 must be 0)
        const uint4 z4 = {0,0,0,0};
        *(uint4*)(EH + t*8) = z4; *(uint4*)(EH + 2048 + t*8) = z4;
        *(uint4*)(EL + t*8) = z4; *(uint4*)(EL + 2048 + t*8) = z4;
    }
    const f32x4 z = {0.f,0.f,0.f,0.f};
    f32x4 acc[4] = {z,z,z,z};
    __syncthreads();
    for (int nn=0; nn<NNB; ++nn){
        if (nn) __syncthreads();
        // stage feat (64 rows x 64 ch as uint2 chunks), swizzled
        #pragma unroll
        for (int i=0;i<4;++i){
            const int e = t + 256*i;          // 0..1023
            const int row = e>>4, q8 = e&15;
            const int g = sidx[nn][row];
            const uint2 vh = *(const uint2*)(latH + (size_t)g*68 + q8*4);
            const uint2 vl = *(const uint2*)(latL + (size_t)g*68 + q8*4);
            const int d = row*64 + (((q8>>1) ^ (row&7))*8) + (q8&1)*4;
            *(uint2*)(GH + d) = vh;
            *(uint2*)(GL + d) = vl;
        }
        // stage el into E[h][k2=nn*4+c], swizzled
        if (t < 64){
            const int g = sidx[nn][t];
            const uint2 eh = *(const uint2*)(latH + (size_t)g*68 + 64);
            const uint2 elv = *(const uint2*)(latL + (size_t)g*68 + 64);
            const int q0 = nn>>1;
            const int d = t*64 + ((q0 ^ (t&7))*8) + (nn&1)*4;
            *(uint2*)(EH + d) = eh;
            *(uint2*)(EL + d) = elv;
        }
        __syncthreads();
        #pragma unroll
        for (int kt=0; kt<2; ++kt){
            s16x8 BH[4], BL[4];
            #pragma unroll
            for (int ht=0; ht<4; ++ht){
                const int h = ht*16 + l15;
                const int q = kt*4 + lg;
                const int d = h*64 + ((q ^ (h&7))*8);
                BH[ht] = *(const s16x8*)(GH + d);
                BL[ht] = *(const s16x8*)(GL + d);
            }
            const int f = nn*2 + kt;
            const s16x8 AH = *(const s16x8*)(SW16 + (f*4+w)*512 + lane*8);
            const s16x8 AL = *(const s16x8*)(SW16 + 61440 + (f*4+w)*512 + lane*8);
            #pragma unroll
            for (int ht=0; ht<4; ++ht)
                acc[ht] = __builtin_amdgcn_mfma_f32_16x16x32_bf16(AH, BH[ht], acc[ht], 0,0,0);
            #pragma unroll
            for (int ht=0; ht<4; ++ht)
                acc[ht] = __builtin_amdgcn_mfma_f32_16x16x32_bf16(AH, BL[ht], acc[ht], 0,0,0);
            #pragma unroll
            for (int ht=0; ht<4; ++ht)
                acc[ht] = __builtin_amdgcn_mfma_f32_16x16x32_bf16(AL, BH[ht], acc[ht], 0,0,0);
        }
    }
    // el GEMM (K=64 packed across nn)
    #pragma unroll
    for (int kt2=0; kt2<2; ++kt2){
        s16x8 BH[4], BL[4];
        #pragma unroll
        for (int ht=0; ht<4; ++ht){
            const int h = ht*16 + l15;
            const int q = kt2*4 + lg;
            const int d = h*64 + ((q ^ (h&7))*8);
            BH[ht] = *(const s16x8*)(EH + d);
            BL[ht] = *(const s16x8*)(EL + d);
        }
        const s16x8 AH = *(const s16x8*)(SW16 + 122880 + (kt2*4+w)*512 + lane*8);
        const s16x8 AL = *(const s16x8*)(SW16 + 126976 + (kt2*4+w)*512 + lane*8);
        #pragma unroll
        for (int ht=0; ht<4; ++ht)
            acc[ht] = __builtin_amdgcn_mfma_f32_16x16x32_bf16(AH, BH[ht], acc[ht], 0,0,0);
        #pragma unroll
        for (int ht=0; ht<4; ++ht)
            acc[ht] = __builtin_amdgcn_mfma_f32_16x16x32_bf16(AH, BL[ht], acc[ht], 0,0,0);
        #pragma unroll
        for (int ht=0; ht<4; ++ht)
            acc[ht] = __builtin_amdgcn_mfma_f32_16x16x32_bf16(AL, BH[ht], acc[ht], 0,0,0);
    }
    __syncthreads();   // all waves done reading GH/GL before T overwrite
    // T = lrelu(acc + sb1) -> bf16 hi/lo in GH/GL, layout [h][o] swizzled
    {
        const int o0 = w*16 + lg*4;
        float bs1v[4];
        #pragma unroll
        for (int j=0;j<4;++j) bs1v[j] = sb1[o0+j];
        const int q16 = o0>>3;
        #pragma unroll
        for (int ht=0; ht<4; ++ht){
            const int h = ht*16 + l15;
            unsigned short th[4], tl[4];
            #pragma unroll
            for (int j=0;j<4;++j) bf16_hilo(lrelu(acc[ht][j] + bs1v[j]), th[j], tl[j]);
            const int d = h*64 + ((q16 ^ (h&7))*8) + (o0&7);
            *(ushort4*)(GH + d) = make_ushort4(th[0],th[1],th[2],th[3]);
            *(ushort4*)(GL + d) = make_ushort4(tl[0],tl[1],tl[2],tl[3]);
        }
    }
    __syncthreads();
    // GEMM2: out = lrelu(sw2 . T + sb2)
    f32x4 acc2[4] = {z,z,z,z};
    #pragma unroll
    for (int kt=0; kt<2; ++kt){
        s16x8 BH[4], BL[4];
        #pragma unroll
        for (int ht=0; ht<4; ++ht){
            const int h = ht*16 + l15;
            const int q = kt*4 + lg;
            const int d = h*64 + ((q ^ (h&7))*8);
            BH[ht] = *(const s16x8*)(GH + d);
            BL[ht] = *(const s16x8*)(GL + d);
        }
        const s16x8 AH = *(const s16x8*)(SW16 + 131072 + (kt*4+w)*512 + lane*8);
        const s16x8 AL = *(const s16x8*)(SW16 + 135168 + (kt*4+w)*512 + lane*8);
        #pragma unroll
        for (int ht=0; ht<4; ++ht)
            acc2[ht] = __builtin_amdgcn_mfma_f32_16x16x32_bf16(AH, BH[ht], acc2[ht], 0,0,0);
        #pragma unroll
        for (int ht=0; ht<4; ++ht)
            acc2[ht] = __builtin_amdgcn_mfma_f32_16x16x32_bf16(AH, BL[ht], acc2[ht], 0,0,0);
        #pragma unroll
        for (int ht=0; ht<4; ++ht)
            acc2[ht] = __builtin_amdgcn_mfma_f32_16x16x32_bf16(AL, BH[ht], acc2[ht], 0,0,0);
    }
    {
        const int o0 = w*16 + lg*4;
        float bs2v[4];
        #pragma unroll
        for (int j=0;j<4;++j) bs2v[j] = sb2[o0+j];
        #pragma unroll
        for (int ht=0; ht<4; ++ht){
            const int h = hb + ht*16 + l15;
            float4 v = make_float4(lrelu(acc2[ht][0]+bs2v[0]), lrelu(acc2[ht][1]+bs2v[1]),
                                   lrelu(acc2[ht][2]+bs2v[2]), lrelu(acc2[ht][3]+bs2v[3]));
            *(float4*)(outp + (size_t)h*ostride + o0) = v;
        }
    }
}

// ---------------------------------------------------------------- corr + d-MLP via split-bf16 MFMA
__global__ __launch_bounds__(256) void corr_mfma_kernel(
        float* __restrict__ cat, const float* __restrict__ lat2, const int* __restrict__ ci,
        const unsigned short* __restrict__ W16,
        const float* __restrict__ cb1, const float* __restrict__ cb2,
        const float* __restrict__ db1, const float* __restrict__ db2){
    const int t = threadIdx.x;
    const int lane = t & 63;
    const int l15 = lane & 15, lg = lane >> 4;
    const int hcol = blockIdx.x*64 + (t>>6)*16 + l15;
    const int srcA = (l15 + ((lg&1)*32)) * 4;
    const int srcB = srcA + 64;
    const int sel = (lg>>1) & 1;

    s16x8 C1H[2][2], C1L[2][2], C2H[2], C2L[2];
    #pragma unroll
    for (int ot=0; ot<2; ++ot){
        #pragma unroll
        for (int kt=0; kt<2; ++kt){
            C1H[ot][kt] = *(const s16x8*)(W16 + (ot*2+kt)*512 + lane*8);
            C1L[ot][kt] = *(const s16x8*)(W16 + 2048 + (ot*2+kt)*512 + lane*8);
        }
        C2H[ot] = *(const s16x8*)(W16 + 4096 + ot*512 + lane*8);
        C2L[ot] = *(const s16x8*)(W16 + 5120 + ot*512 + lane*8);
    }
    float l1f[16];
    {
        const float* lr = cat + (size_t)hcol*128;
        *(float4*)&l1f[0]  = *(const float4*)(lr + lg*8);
        *(float4*)&l1f[4]  = *(const float4*)(lr + lg*8 + 4);
        *(float4*)&l1f[8]  = *(const float4*)(lr + 32 + lg*8);
        *(float4*)&l1f[12] = *(const float4*)(lr + 32 + lg*8 + 4);
    }
    float cb1r[8], cb2r[8];
    #pragma unroll
    for (int i=0;i<8;++i){
        cb1r[i] = cb1[(i>>2)*16 + lg*4 + (i&3)];
        cb2r[i] = cb2[(i>>2)*16 + lg*4 + (i&3)];
    }
    float agg[8] = {};
    const f32x4 z = {0.f,0.f,0.f,0.f};

    int idx = ci[hcol];
    float4 g0 = *(const float4*)(lat2 + (size_t)idx*64 + lg*8);
    float4 g1 = *(const float4*)(lat2 + (size_t)idx*64 + lg*8 + 4);
    float4 g2v = *(const float4*)(lat2 + (size_t)idx*64 + 32 + lg*8);
    float4 g3 = *(const float4*)(lat2 + (size_t)idx*64 + 32 + lg*8 + 4);

    for (int k=0; k<KC; ++k){
        float p[16];
        p[0]=l1f[0]*g0.x; p[1]=l1f[1]*g0.y; p[2]=l1f[2]*g0.z; p[3]=l1f[3]*g0.w;
        p[4]=l1f[4]*g1.x; p[5]=l1f[5]*g1.y; p[6]=l1f[6]*g1.z; p[7]=l1f[7]*g1.w;
        p[8]=l1f[8]*g2v.x; p[9]=l1f[9]*g2v.y; p[10]=l1f[10]*g2v.z; p[11]=l1f[11]*g2v.w;
        p[12]=l1f[12]*g3.x; p[13]=l1f[13]*g3.y; p[14]=l1f[14]*g3.z; p[15]=l1f[15]*g3.w;
        if (k+1 < KC){
            idx = ci[(k+1)*HL + hcol];
            g0 = *(const float4*)(lat2 + (size_t)idx*64 + lg*8);
            g1 = *(const float4*)(lat2 + (size_t)idx*64 + lg*8 + 4);
            g2v = *(const float4*)(lat2 + (size_t)idx*64 + 32 + lg*8);
            g3 = *(const float4*)(lat2 + (size_t)idx*64 + 32 + lg*8 + 4);
        }
        pk8 BH[2], BL[2];
        #pragma unroll
        for (int kt=0; kt<2; ++kt){
            #pragma unroll
            for (int q=0; q<4; ++q){
                unsigned short h0,l0,h1,l1v;
                bf16_hilo(p[kt*8+2*q], h0, l0);
                bf16_hilo(p[kt*8+2*q+1], h1, l1v);
                BH[kt].u[q] = pk2(h0,h1);
                BL[kt].u[q] = pk2(l0,l1v);
            }
        }
        f32x4 a1[2] = {z, z};
        #pragma unroll
        for (int kt=0; kt<2; ++kt){
            a1[0] = __builtin_amdgcn_mfma_f32_16x16x32_bf16(C1H[0][kt], BH[kt].v, a1[0], 0,0,0);
            a1[1] = __builtin_amdgcn_mfma_f32_16x16x32_bf16(C1H[1][kt], BH[kt].v, a1[1], 0,0,0);
            a1[0] = __builtin_amdgcn_mfma_f32_16x16x32_bf16(C1H[0][kt], BL[kt].v, a1[0], 0,0,0);
            a1[1] = __builtin_amdgcn_mfma_f32_16x16x32_bf16(C1H[1][kt], BL[kt].v, a1[1], 0,0,0);
            a1[0] = __builtin_amdgcn_mfma_f32_16x16x32_bf16(C1L[0][kt], BH[kt].v, a1[0], 0,0,0);
            a1[1] = __builtin_amdgcn_mfma_f32_16x16x32_bf16(C1L[1][kt], BH[kt].v, a1[1], 0,0,0);
        }
        unsigned mh[2][2], ml[2][2];
        #pragma unroll
        for (int ot=0; ot<2; ++ot){
            #pragma unroll
            for (int j=0; j<2; ++j){
                unsigned short h0,l0,h1,l1v;
                bf16_hilo(lrelu(a1[ot][2*j]   + cb1r[ot*4+2*j]),   h0, l0);
                bf16_hilo(lrelu(a1[ot][2*j+1] + cb1r[ot*4+2*j+1]), h1, l1v);
                mh[ot][j] = pk2(h0,h1);
                ml[ot][j] = pk2(l0,l1v);
            }
        }
        pk8 B2H = shuf32(mh[0], mh[1], sel, srcA, srcB);
        pk8 B2L = shuf32(ml[0], ml[1], sel, srcA, srcB);
        f32x4 a2[2] = {z, z};
        a2[0] = __builtin_amdgcn_mfma_f32_16x16x32_bf16(C2H[0], B2H.v, a2[0], 0,0,0);
        a2[1] = __builtin_amdgcn_mfma_f32_16x16x32_bf16(C2H[1], B2H.v, a2[1], 0,0,0);
        a2[0] = __builtin_amdgcn_mfma_f32_16x16x32_bf16(C2H[0], B2L.v, a2[0], 0,0,0);
        a2[1] = __builtin_amdgcn_mfma_f32_16x16x32_bf16(C2H[1], B2L.v, a2[1], 0,0,0);
        a2[0] = __builtin_amdgcn_mfma_f32_16x16x32_bf16(C2L[0], B2H.v, a2[0], 0,0,0);
        a2[1] = __builtin_amdgcn_mfma_f32_16x16x32_bf16(C2L[1], B2H.v, a2[1], 0,0,0);
        #pragma unroll
        for (int i=0;i<8;++i)
            agg[i] += lrelu(a2[i>>2][i&3] + cb2r[i]);
    }
    #pragma unroll
    for (int i=0;i<8;++i) agg[i] *= (1.0f/32.0f);
    unsigned agH[2][2], agL[2][2];
    #pragma unroll
    for (int ot=0; ot<2; ++ot)
        #pragma unroll
        for (int j=0; j<2; ++j){
            unsigned short h0,l0,h1,l1v;
            bf16_hilo(agg[ot*4+2*j],   h0, l0);
            bf16_hilo(agg[ot*4+2*j+1], h1, l1v);
            agH[ot][j] = pk2(h0,h1); agL[ot][j] = pk2(l0,l1v);
        }
    pk8 B3H = shuf32(agH[0], agH[1], sel, srcA, srcB);
    pk8 B3L = shuf32(agL[0], agL[1], sel, srcA, srcB);
    float db1r[16], db2r[16];
    #pragma unroll
    for (int i=0;i<16;++i){
        db1r[i] = db1[(i>>2)*16 + lg*4 + (i&3)];
        db2r[i] = db2[(i>>2)*16 + lg*4 + (i&3)];
    }
    unsigned d1H[4][2], d1L[4][2];
    #pragma unroll
    for (int ot=0; ot<4; ++ot){
        s16x8 AH = *(const s16x8*)(W16 + 6144 + ot*512 + lane*8);
        s16x8 AL = *(const s16x8*)(W16 + 8192 + ot*512 + lane*8);
        f32x4 a3 = z;
        a3 = __builtin_amdgcn_mfma_f32_16x16x32_bf16(AH, B3H.v, a3, 0,0,0);
        a3 = __builtin_amdgcn_mfma_f32_16x16x32_bf16(AH, B3L.v, a3, 0,0,0);
        a3 = __builtin_amdgcn_mfma_f32_16x16x32_bf16(AL, B3H.v, a3, 0,0,0);
        #pragma unroll
        for (int j=0;j<2;++j){
            unsigned short h0,l0,h1,l1v;
            bf16_hilo(lrelu(a3[2*j]   + db1r[ot*4+2*j]),   h0, l0);
            bf16_hilo(lrelu(a3[2*j+1] + db1r[ot*4+2*j+1]), h1, l1v);
            d1H[ot][j] = pk2(h0,h1); d1L[ot][j] = pk2(l0,l1v);
        }
    }
    f32x4 a4[4] = {z,z,z,z};
    #pragma unroll
    for (int kt=0; kt<2; ++kt){
        pk8 B4H = shuf32(d1H[kt*2], d1H[kt*2+1], sel, srcA, srcB);
        pk8 B4L = shuf32(d1L[kt*2], d1L[kt*2+1], sel, srcA, srcB);
        #pragma unroll
        for (int ot=0; ot<4; ++ot){
            s16x8 AH = *(const s16x8*)(W16 + 10240 + (ot*2+kt)*512 + lane*8);
            s16x8 AL = *(const s16x8*)(W16 + 14336 + (ot*2+kt)*512 + lane*8);
            a4[ot] = __builtin_amdgcn_mfma_f32_16x16x32_bf16(AH, B4H.v, a4[ot], 0,0,0);
            a4[ot] = __builtin_amdgcn_mfma_f32_16x16x32_bf16(AH, B4L.v, a4[ot], 0,0,0);
            a4[ot] = __builtin_amdgcn_mfma_f32_16x16x32_bf16(AL, B4H.v, a4[ot], 0,0,0);
        }
    }
    float* dst = cat + (size_t)hcol*128 + 64;
    #pragma unroll
    for (int ot=0; ot<4; ++ot){
        float4 v = make_float4(lrelu(a4[ot][0]+db2r[ot*4+0]), lrelu(a4[ot][1]+db2r[ot*4+1]),
                               lrelu(a4[ot][2]+db2r[ot*4+2]), lrelu(a4[ot][3]+db2r[ot*4+3]));
        *(float4*)(dst + ot*16 + lg*4) = v;
    }
}

// ---------------------------------------------------------------- cat -> bf16 hi/lo
__global__ __launch_bounds__(256) void cvt_cat_kernel(const float* __restrict__ cat,
        unsigned short* __restrict__ cH, unsigned short* __restrict__ cL){
    const size_t i = (size_t)blockIdx.x*256 + threadIdx.x;
    const float4 v = *(const float4*)(cat + i*4);
    unsigned short h0,h1,h2,h3,l0,l1,l2,l3;
    bf16_hilo(v.x,h0,l0); bf16_hilo(v.y,h1,l1); bf16_hilo(v.z,h2,l2); bf16_hilo(v.w,h3,l3);
    *(ushort4*)(cH + i*4) = make_ushort4(h0,h1,h2,h3);
    *(ushort4*)(cL + i*4) = make_ushort4(l0,l1,l2,l3);
}

// ---------------------------------------------------------------- blur_p via split-bf16 MFMA
__global__ __launch_bounds__(256) void blur_p_mfma_kernel(
        const unsigned short* __restrict__ catH, const unsigned short* __restrict__ catL,
        const int* __restrict__ nb,
        const unsigned short* __restrict__ pw1fH, const unsigned short* __restrict__ pw1fL,
        const float* __restrict__ pb1,
        const unsigned short* __restrict__ pw2fH, const unsigned short* __restrict__ pw2fL,
        const float* __restrict__ pb2,
        float* __restrict__ p){
    __shared__ unsigned short GH[8192];
    __shared__ unsigned short GLb[8192];
    __shared__ int sidx[NNB][64];
    const int t = threadIdx.x;
    const int hb = blockIdx.x*64;
    const int w = t>>6, lane = t&63;
    const int l15 = lane&15, lg = lane>>4;
    for (int e=t; e<NNB*64; e+=256) sidx[e>>6][e&63] = nb[(e>>6)*HL + hb + (e&63)];
    f32x4 acc1[2][4];
    #pragma unroll
    for (int ot=0;ot<2;++ot)
        #pragma unroll
        for (int ht=0;ht<4;++ht) acc1[ot][ht] = (f32x4){0.f,0.f,0.f,0.f};
    __syncthreads();
    for (int nn=0; nn<NNB; ++nn){
        if (nn) __syncthreads();
        #pragma unroll
        for (int i=0;i<4;++i){
            const int j2 = t + 256*i;
            const int row = j2>>4, q = j2&15;
            const int g = sidx[nn][row];
            const uint4 vh = *(const uint4*)(catH + (size_t)g*128 + q*8);
            const uint4 vl = *(const uint4*)(catL + (size_t)g*128 + q*8);
            const int d = row*128 + ((q ^ (row&7))*8);
            *(uint4*)(GH + d) = vh;
            *(uint4*)(GLb + d) = vl;
        }
        __syncthreads();
        #pragma unroll
        for (int kt=0; kt<4; ++kt){
            s16x8 BH[4], BL[4];
            #pragma unroll
            for (int ht=0; ht<4; ++ht){
                const int h = ht*16 + l15;
                const int q = kt*4 + lg;
                const int d = h*128 + ((q ^ (h&7))*8);
                BH[ht] = *(const s16x8*)(GH + d);
                BL[ht] = *(const s16x8*)(GLb + d);
            }
            s16x8 AH[2], AL[2];
            #pragma unroll
            for (int ot=0; ot<2; ++ot){
                const size_t fo = ((size_t)((nn*4 + kt)*8 + (w*2+ot)))*512 + lane*8;
                AH[ot] = *(const s16x8*)(pw1fH + fo);
                AL[ot] = *(const s16x8*)(pw1fL + fo);
            }
            #pragma unroll
            for (int ht=0; ht<4; ++ht)
                #pragma unroll
                for (int ot=0; ot<2; ++ot)
                    acc1[ot][ht] = __builtin_amdgcn_mfma_f32_16x16x32_bf16(AH[ot], BH[ht], acc1[ot][ht], 0,0,0);
            #pragma unroll
            for (int ht=0; ht<4; ++ht)
                #pragma unroll
                for (int ot=0; ot<2; ++ot)
                    acc1[ot][ht] = __builtin_amdgcn_mfma_f32_16x16x32_bf16(AH[ot], BL[ht], acc1[ot][ht], 0,0,0);
            #pragma unroll
            for (int ht=0; ht<4; ++ht)
                #pragma unroll
                for (int ot=0; ot<2; ++ot)
                    acc1[ot][ht] = __builtin_amdgcn_mfma_f32_16x16x32_bf16(AL[ot], BH[ht], acc1[ot][ht], 0,0,0);
        }
    }
    __syncthreads();
    #pragma unroll
    for (int ot=0; ot<2; ++ot){
        const int o0 = (w*2+ot)*16 + lg*4;
        const float b0 = pb1[o0], b1v = pb1[o0+1], b2v = pb1[o0+2], b3v = pb1[o0+3];
        const int q = o0>>3;
        #pragma unroll
        for (int ht=0; ht<4; ++ht){
            const int h = ht*16 + l15;
            unsigned short th[4], tl[4];
            bf16_hilo(lrelu(acc1[ot][ht][0] + b0), th[0], tl[0]);
            bf16_hilo(lrelu(acc1[ot][ht][1] + b1v), th[1], tl[1]);
            bf16_hilo(lrelu(acc1[ot][ht][2] + b2v), th[2], tl[2]);
            bf16_hilo(lrelu(acc1[ot][ht][3] + b3v), th[3], tl[3]);
            const int d = h*128 + ((q ^ (h&7))*8) + (o0&7);
            *(ushort4*)(GH + d)  = make_ushort4(th[0],th[1],th[2],th[3]);
            *(ushort4*)(GLb + d) = make_ushort4(tl[0],tl[1],tl[2],tl[3]);
        }
    }
    __syncthreads();
    f32x4 acc2[2][4];
    #pragma unroll
    for (int ot=0;ot<2;++ot)
        #pragma unroll
        for (int ht=0;ht<4;++ht) acc2[ot][ht] = (f32x4){0.f,0.f,0.f,0.f};
    #pragma unroll
    for (int kt=0; kt<4; ++kt){
        s16x8 BH[4], BL[4];
        #pragma unroll
        for (int ht=0; ht<4; ++ht){
            const int h = ht*16 + l15;
            const int q = kt*4 + lg;
            const int d = h*128 + ((q ^ (h&7))*8);
            BH[ht] = *(const s16x8*)(GH + d);
            BL[ht] = *(const s16x8*)(GLb + d);
        }
        s16x8 AH[2], AL[2];
        #pragma unroll
        for (int ot=0; ot<2; ++ot){
            const size_t fo = ((size_t)(kt*8 + (w*2+ot)))*512 + lane*8;
            AH[ot] = *(const s16x8*)(pw2fH + fo);
            AL[ot] = *(const s16x8*)(pw2fL + fo);
        }
        #pragma unroll
        for (int ht=0; ht<4; ++ht)
            #pragma unroll
            for (int ot=0; ot<2; ++ot)
                acc2[ot][ht] = __builtin_amdgcn_mfma_f32_16x16x32_bf16(AH[ot], BH[ht], acc2[ot][ht], 0,0,0);
        #pragma unroll
        for (int ht=0; ht<4; ++ht)
            #pragma unroll
            for (int ot=0; ot<2; ++ot)
                acc2[ot][ht] = __builtin_amdgcn_mfma_f32_16x16x32_bf16(AH[ot], BL[ht], acc2[ot][ht], 0,0,0);
        #pragma unroll
        for (int ht=0; ht<4; ++ht)
            #pragma unroll
            for (int ot=0; ot<2; ++ot)
                acc2[ot][ht] = __builtin_amdgcn_mfma_f32_16x16x32_bf16(AL[ot], BH[ht], acc2[ot][ht], 0,0,0);
    }
    #pragma unroll
    for (int ot=0; ot<2; ++ot){
        const int o0 = (w*2+ot)*16 + lg*4;
        const float b0 = pb2[o0], b1v = pb2[o0+1], b2v = pb2[o0+2], b3v = pb2[o0+3];
        #pragma unroll
        for (int ht=0; ht<4; ++ht){
            const int h = hb + ht*16 + l15;
            float4 v = make_float4(lrelu(acc2[ot][ht][0] + b0), lrelu(acc2[ot][ht][1] + b1v),
                                   lrelu(acc2[ot][ht][2] + b2v), lrelu(acc2[ot][ht][3] + b3v));
            *(float4*)(p + (size_t)h*128 + o0) = v;
        }
    }
}

// ---------------------------------------------------------------- head: slice + 128->128->64->3
__global__ __launch_bounds__(256) void head_kernel(
        const float* __restrict__ p, const float* __restrict__ bary, const int* __restrict__ off,
        const float* __restrict__ fw2T, const float* __restrict__ fb2,
        const float* __restrict__ fw3T, const float* __restrict__ fb3,
        const float* __restrict__ fw4, const float* __restrict__ fb4,
        float* __restrict__ out){
    __shared__ __align__(16) float S[8704];
    __shared__ __align__(16) float WW[8192];
    __shared__ float SB[5][64];
    __shared__ int   SO[5][64];
    const int t = threadIdx.x;
    const int pb = blockIdx.x*64;
    const int oq8 = t>>4, pq = t&15;
    const int q5 = t&31, rgrp5 = t>>5;
    if (t<64){
        #pragma unroll
        for (int j=0;j<5;++j){ SB[j][t]=bary[j*NPTS+pb+t]; SO[j][t]=off[j*NPTS+pb+t]; }
    }
    __syncthreads();
    #pragma unroll
    for (int i=0;i<8;++i){
        const int row = rgrp5 + 8*i;
        float4 sa = make_float4(0.f,0.f,0.f,0.f);
        #pragma unroll
        for (int j=0;j<5;++j){
            const float4 v = *(const float4*)(p + (size_t)SO[j][row]*128 + q5*4);
            const float b = SB[j][row];
            sa.x += b*v.x; sa.y += b*v.y; sa.z += b*v.z; sa.w += b*v.w;
        }
        S[(q5*4+0)*68 + row] = sa.x;
        S[(q5*4+1)*68 + row] = sa.y;
        S[(q5*4+2)*68 + row] = sa.z;
        S[(q5*4+3)*68 + row] = sa.w;
    }
    float acc1[8][4] = {};
    #pragma unroll 1
    for (int hf=0;hf<2;++hf){
        if (hf==1) __syncthreads();
        for (int e=t;e<2048;e+=256)
            *(float4*)(WW + e*4) = *(const float4*)(fw2T + hf*8192 + e*4);
        __syncthreads();
        #pragma unroll 4
        for (int c=0;c<64;++c){
            const float4 a4 = *(const float4*)(S + (hf*64+c)*68 + pq*4);
            const float4 wa = *(const float4*)(WW + c*128 + oq8*8);
            const float4 wb = *(const float4*)(WW + c*128 + oq8*8 + 4);
            const float av[4]={a4.x,a4.y,a4.z,a4.w};
            const float wv[8]={wa.x,wa.y,wa.z,wa.w,wb.x,wb.y,wb.z,wb.w};
            #pragma unroll
            for (int i=0;i<8;++i)
                #pragma unroll
                for (int j=0;j<4;++j)
                    acc1[i][j] = fmaf(wv[i], av[j], acc1[i][j]);
        }
    }
    __syncthreads();
    float bf2[8];
    #pragma unroll
    for (int i=0;i<8;++i) bf2[i]=fb2[oq8*8+i];
    #pragma unroll
    for (int i=0;i<8;++i){
        const int o = oq8*8+i;
        float4 v = make_float4(lrelu(acc1[i][0]+bf2[i]), lrelu(acc1[i][1]+bf2[i]),
                               lrelu(acc1[i][2]+bf2[i]), lrelu(acc1[i][3]+bf2[i]));
        *(float4*)(S + o*68 + pq*4) = v;
    }
    for (int e=t;e<2048;e+=256)
        *(float4*)(WW + e*4) = *(const float4*)(fw3T + e*4);
    __syncthreads();
    const int od = t>>4;
    float bf3[4];
    #pragma unroll
    for (int i=0;i<4;++i) bf3[i]=fb3[od*4+i];
    float a2[4][4] = {};
    #pragma unroll 4
    for (int c=0;c<128;++c){
        const float4 a4 = *(const float4*)(S + c*68 + pq*4);
        const float4 w4 = *(const float4*)(WW + c*64 + od*4);
        const float av[4]={a4.x,a4.y,a4.z,a4.w};
        const float wv[4]={w4.x,w4.y,w4.z,w4.w};
        #pragma unroll
        for (int i=0;i<4;++i)
            #pragma unroll
            for (int j=0;j<4;++j)
                a2[i][j] = fmaf(wv[i], av[j], a2[i][j]);
    }
    __syncthreads();
    #pragma unroll
    for (int i=0;i<4;++i){
        float4 v = make_float4(lrelu(a2[i][0]+bf3[i]), lrelu(a2[i][1]+bf3[i]),
                               lrelu(a2[i][2]+bf3[i]), lrelu(a2[i][3]+bf3[i]));
        *(float4*)(S + (od*4+i)*68 + pq*4) = v;
    }
    __syncthreads();
    if (t < 192){
        const int r = t>>6, pp = t&63;
        float a = fb4[r];
        #pragma unroll 8
        for (int c=0;c<64;++c) a += fw4[r*64+c]*S[c*68+pp];
        out[r*NPTS + pb + pp] = a;
    }
}

// ================================================================ launch
extern "C" void kernel_launch(void* const* d_in, const int* in_sizes, int n_in,
                              void* d_out, int out_size, void* d_ws, size_t ws_size,
                              hipStream_t stream){
    const float* pc1   = (const float*)d_in[0];
    const float* pc2   = (const float*)d_in[1];
    const float* el1   = (const float*)d_in[2];
    const float* el2   = (const float*)d_in[3];
    const float* bary1 = (const float*)d_in[4];
    const float* bary2 = (const float*)d_in[5];
    const int*   off1  = (const int*)d_in[6];
    const int*   off2  = (const int*)d_in[7];
    const int*   nb1   = (const int*)d_in[8];
    const int*   nb2   = (const int*)d_in[9];
    const int*   ci    = (const int*)d_in[10];
    const float* w1    = (const float*)d_in[11];
    const float* b1    = (const float*)d_in[12];
    const float* w2    = (const float*)d_in[13];
    const float* b2    = (const float*)d_in[14];
    const float* w3    = (const float*)d_in[15];
    const float* b3    = (const float*)d_in[16];
    const float* sw1   = (const float*)d_in[17];
    const float* sb1   = (const float*)d_in[18];
    const float* sw2   = (const float*)d_in[19];
    const float* sb2   = (const float*)d_in[20];
    const float* cw1   = (const float*)d_in[21];
    const float* cb1   = (const float*)d_in[22];
    const float* cw2   = (const float*)d_in[23];
    const float* cb2   = (const float*)d_in[24];
    const float* dw1   = (const float*)d_in[25];
    const float* db1   = (const float*)d_in[26];
    const float* dw2   = (const float*)d_in[27];
    const float* db2   = (const float*)d_in[28];
    const float* pw1   = (const float*)d_in[29];
    const float* pb1   = (const float*)d_in[30];
    const float* pw2   = (const float*)d_in[31];
    const float* pb2   = (const float*)d_in[32];
    const float* fw2   = (const float*)d_in[33];
    const float* fb2   = (const float*)d_in[34];
    const float* fw3   = (const float*)d_in[35];
    const float* fb3   = (const float*)d_in[36];
    const float* fw4   = (const float*)d_in[37];
    const float* fb4   = (const float*)d_in[38];
    float* out = (float*)d_out;

    float* ws    = (float*)d_ws;
    float* pf1   = ws;                    // N*68 ; later lat16 x4 ; later pbuf
    float* pf2   = pf1   + 2228224;
    float* latA  = pf2   + 2228224;       // H*68 f32 ; later catH/catL
    float* latB  = latA  + 2228224;
    float* catb  = latB  + 2228224;       // H*128
    float* lat2p = catb  + 4194304;       // H*64
    float* pw1fS = lat2p + 2097152;       // 245760 floats = 491520 ushorts
    float* SW16f = pw1fS + 245760;        // 69632 floats = 139264 ushorts
    float* W16f  = SW16f + 69632;         // 9216 floats
    float* pw2fS = W16f  + 9216;          // 16384 floats
    float* fw2T  = pw2fS + 16384;         // 16384
    float* fw3T  = fw2T  + 16384;         // 8192
    float* pbuf  = pf1;                   // p (H*128) reuses pf1+pf2

    unsigned short* pw1fH = (unsigned short*)pw1fS;
    unsigned short* pw1fL = pw1fH + 245760;
    unsigned short* SW16  = (unsigned short*)SW16f;
    unsigned short* W16   = (unsigned short*)W16f;
    unsigned short* pw2fH = (unsigned short*)pw2fS;
    unsigned short* pw2fL = pw2fH + 16384;
    // bf16 lattices live in pf1+pf2 (pfeat dead after splat): 4 x 2228224 ushorts
    unsigned short* latA16H = (unsigned short*)pf1;
    unsigned short* latA16L = latA16H + 2228224;
    unsigned short* latB16H = latA16L + 2228224;
    unsigned short* latB16L = latB16H + 2228224;
    unsigned short* catH  = (unsigned short*)latA;   // f32 lattices dead after cvt_lat
    unsigned short* catL  = catH + (size_t)HL*128;

    zero_kernel<<<4352, 256, 0, stream>>>((float4*)latA);
    repack_kernel<<<960, 256, 0, stream>>>(sw1, pw1, sw2, cw1, cw2, dw1, dw2, pw2, fw2, fw3,
                                           SW16, pw1fH, pw1fL, W16,
                                           pw2fH, pw2fL, fw2T, fw3T);

    mlp3_kernel<<<128, 256, 0, stream>>>(pc1, el1, w1,b1,w2,b2,w3,b3, pf1);
    mlp3_kernel<<<128, 256, 0, stream>>>(pc2, el2, w1,b1,w2,b2,w3,b3, pf2);

    splat_kernel<<<40960, 256, 0, stream>>>(pf1, bary1, off1, latA);
    splat_kernel<<<40960, 256, 0, stream>>>(pf2, bary2, off2, latB);

    cvt_lat_kernel<<<2176, 256, 0, stream>>>(latA, latA16H, latA16L);
    cvt_lat_kernel<<<2176, 256, 0, stream>>>(latB, latB16H, latB16L);

    blur_s_mfma_kernel<<<512, 256, 0, stream>>>(latA16H, latA16L, nb1, SW16, sb1, sb2, catb, 128);
    blur_s_mfma_kernel<<<512, 256, 0, stream>>>(latB16H, latB16L, nb2, SW16, sb1, sb2, lat2p, 64);

    corr_mfma_kernel<<<512, 256, 0, stream>>>(catb, lat2p, ci, W16, cb1, cb2, db1, db2);

    cvt_cat_kernel<<<4096, 256, 0, stream>>>(catb, catH, catL);

    blur_p_mfma_kernel<<<512, 256, 0, stream>>>(catH, catL, nb1, pw1fH, pw1fL, pb1,
                                                pw2fH, pw2fL, pb2, pbuf);

    head_kernel<<<512, 256, 0, stream>>>(pbuf, bary1, off1, fw2T,fb2,fw3T,fb3,fw4,fb4, out);
}

// Round 7
// 403.507 us; speedup vs baseline: 39.7021x; 1.0530x over previous
//
#include <hip/hip_runtime.h>

#define NPTS 32768
#define HL   32768
#define NNB  15
#define KC   32

typedef __attribute__((ext_vector_type(8))) short s16x8;
typedef __attribute__((ext_vector_type(4))) float f32x4;

typedef union { s16x8 v; unsigned u[4]; } pk8;

__device__ __forceinline__ float lrelu(float x){ return x > 0.0f ? x : 0.1f*x; }

__device__ __forceinline__ unsigned short bf16r(float x){
    union { float f; unsigned u; } a; a.f = x;
    unsigned r = a.u + 0x7FFF + ((a.u >> 16) & 1);
    return (unsigned short)(r >> 16);
}
// round-to-nearest-even bf16 split: x ~= hi + lo
__device__ __forceinline__ void bf16_hilo(float x, unsigned short& hi, unsigned short& lo){
    hi = bf16r(x);
    union { float f; unsigned u; } b; b.u = ((unsigned)hi) << 16;
    lo = bf16r(x - b.f);
}
__device__ __forceinline__ unsigned pk2(unsigned short a, unsigned short b){
    return (unsigned)a | ((unsigned)b << 16);
}

// rows lg*8+0..7 of a 32-row column (2 ot-tiles packed p0/p1, u32 = row pair) -> B frag
__device__ __forceinline__ pk8 shuf32(const unsigned* p0, const unsigned* p1,
                                      int sel, int srcA, int srcB){
    pk8 o;
    int a0 = __builtin_amdgcn_ds_bpermute(srcA, (int)p0[0]);
    int a1 = __builtin_amdgcn_ds_bpermute(srcA, (int)p1[0]);
    o.u[0] = (unsigned)(sel ? a1 : a0);
    int b0 = __builtin_amdgcn_ds_bpermute(srcA, (int)p0[1]);
    int b1 = __builtin_amdgcn_ds_bpermute(srcA, (int)p1[1]);
    o.u[1] = (unsigned)(sel ? b1 : b0);
    int c0 = __builtin_amdgcn_ds_bpermute(srcB, (int)p0[0]);
    int c1 = __builtin_amdgcn_ds_bpermute(srcB, (int)p1[0]);
    o.u[2] = (unsigned)(sel ? c1 : c0);
    int d0 = __builtin_amdgcn_ds_bpermute(srcB, (int)p0[1]);
    int d1 = __builtin_amdgcn_ds_bpermute(srcB, (int)p1[1]);
    o.u[3] = (unsigned)(sel ? d1 : d0);
    return o;
}

// ---------------------------------------------------------------- zero
__global__ void zero_kernel(float4* __restrict__ buf){
    buf[(size_t)blockIdx.x*256 + threadIdx.x] = make_float4(0.f,0.f,0.f,0.f);
}

// ---------------------------------------------------------------- repack weights
// SW16 layout (ushort offs): featH 0 (61440) featL 61440 | elH 122880 (4096) elL 126976
//                            sw2H 131072 (4096) sw2L 135168   total 139264
__global__ void repack_kernel(const float* __restrict__ sw1, const float* __restrict__ pw1,
                              const float* __restrict__ sw2, const float* __restrict__ cw1,
                              const float* __restrict__ cw2, const float* __restrict__ dw1,
                              const float* __restrict__ dw2, const float* __restrict__ pw2,
                              const float* __restrict__ fw2, const float* __restrict__ fw3,
                              unsigned short* __restrict__ SW16,
                              unsigned short* __restrict__ pw1fH, unsigned short* __restrict__ pw1fL,
                              unsigned short* __restrict__ W16,
                              unsigned short* __restrict__ pw2fH, unsigned short* __restrict__ pw2fL,
                              float* __restrict__ fw2T, float* __restrict__ fw3T){
    int tid = blockIdx.x*256 + threadIdx.x;
    if (tid < 61440){
        int b = tid&7, ln = (tid>>3)&63, ot = (tid>>9)&3, f = tid>>11;
        int kt = f&1, nn = f>>1;
        int o = ot*16 + (ln&15), k = kt*32 + (ln>>4)*8 + b, c = k + 4;
        unsigned short hi, lo; bf16_hilo(sw1[(o*68+c)*15+nn], hi, lo);
        SW16[tid] = hi; SW16[61440+tid] = lo;
    }
    if (tid < 4096){
        int b = tid&7, ln = (tid>>3)&63, ot = (tid>>9)&3, kt2 = tid>>11;
        int o = ot*16 + (ln&15), k2 = kt2*32 + (ln>>4)*8 + b;
        float v = (k2 < 60) ? sw1[(o*68 + (k2&3))*15 + (k2>>2)] : 0.f;
        unsigned short hi, lo; bf16_hilo(v, hi, lo);
        SW16[122880+tid] = hi; SW16[126976+tid] = lo;
    }
    if (tid < 4096){
        int b = tid&7, ln = (tid>>3)&63, ot = (tid>>9)&3, kt = tid>>11;
        int o = ot*16 + (ln&15), k = kt*32 + (ln>>4)*8 + b;
        unsigned short hi, lo; bf16_hilo(sw2[o*64+k], hi, lo);
        SW16[131072+tid] = hi; SW16[135168+tid] = lo;
    }
    if (tid < 245760){
        int b = tid & 7, ln = (tid>>3)&63, ot = (tid>>9)&7, kt = (tid>>12)&3, nn = tid>>14;
        int o = ot*16 + (ln&15), k = kt*32 + (ln>>4)*8 + b;
        float v = pw1[(o*128 + k)*15 + nn];
        unsigned short hi, lo; bf16_hilo(v, hi, lo);
        pw1fH[tid] = hi; pw1fL[tid] = lo;
    }
    if (tid < 16384){
        int b = tid & 7, ln = (tid>>3)&63, ot = (tid>>9)&7, kt = (tid>>12)&3;
        int o = ot*16 + (ln&15), k = kt*32 + (ln>>4)*8 + b;
        float v = pw2[o*128 + k];
        unsigned short hi, lo; bf16_hilo(v, hi, lo);
        pw2fH[tid] = hi; pw2fL[tid] = lo;
    }
    if (tid < 2048){   // cw1 (32x64): frag f=ot*2+kt
        int b = tid&7, ln = (tid>>3)&63, f = tid>>9;
        int ot = f>>1, kt = f&1;
        int o = ot*16 + (ln&15), c = kt*32 + (ln>>4)*8 + b;
        unsigned short hi, lo; bf16_hilo(cw1[o*64+c], hi, lo);
        W16[tid] = hi; W16[2048+tid] = lo;
    }
    if (tid < 1024){   // cw2 (32x32): frag f=ot
        int b = tid&7, ln = (tid>>3)&63, ot = tid>>9;
        int o = ot*16 + (ln&15), c = (ln>>4)*8 + b;
        unsigned short hi, lo; bf16_hilo(cw2[o*32+c], hi, lo);
        W16[4096+tid] = hi; W16[5120+tid] = lo;
    }
    if (tid < 2048){   // dw1 (64x32): frag f=ot (4)
        int b = tid&7, ln = (tid>>3)&63, ot = tid>>9;
        int o = ot*16 + (ln&15), c = (ln>>4)*8 + b;
        unsigned short hi, lo; bf16_hilo(dw1[o*32+c], hi, lo);
        W16[6144+tid] = hi; W16[8192+tid] = lo;
    }
    if (tid < 4096){   // dw2 (64x64): frag f=ot*2+kt (8)
        int b = tid&7, ln = (tid>>3)&63, f = tid>>9;
        int ot = f>>1, kt = f&1;
        int o = ot*16 + (ln&15), c = kt*32 + (ln>>4)*8 + b;
        unsigned short hi, lo; bf16_hilo(dw2[o*64+c], hi, lo);
        W16[10240+tid] = hi; W16[14336+tid] = lo;
    }
    if (tid < 16384){ int c = tid>>7, o = tid&127; fw2T[tid] = fw2[o*128+c]; }
    if (tid < 8192){ int c = tid>>6, o = tid&63; fw3T[tid] = fw3[o*128+c]; }
}

// ---------------------------------------------------------------- point MLP (3->32->32->64) + el pack
__global__ __launch_bounds__(256) void mlp3_kernel(
        const float* __restrict__ pc, const float* __restrict__ el,
        const float* __restrict__ w1, const float* __restrict__ b1,
        const float* __restrict__ w2, const float* __restrict__ b2,
        const float* __restrict__ w3, const float* __restrict__ b3,
        float* __restrict__ pfeat){
    __shared__ float W1[96], W2s[1024], W3s[2048], B1[32], B2[32], B3[64];
    const int t = threadIdx.x;
    for (int e=t;e<96;e+=256)   W1[e]=w1[e];
    for (int e=t;e<1024;e+=256) W2s[e]=w2[e];
    for (int e=t;e<2048;e+=256) W3s[e]=w3[e];
    if (t<32){ B1[t]=b1[t]; B2[t]=b2[t]; }
    if (t<64){ B3[t]=b3[t]; }
    __syncthreads();
    const int n = blockIdx.x*256 + t;
    const float x0 = pc[n], x1 = pc[NPTS+n], x2 = pc[2*NPTS+n];
    float h1[32];
    #pragma unroll
    for (int o=0;o<32;++o)
        h1[o] = lrelu(B1[o] + W1[o*3]*x0 + W1[o*3+1]*x1 + W1[o*3+2]*x2);
    float h2[32];
    #pragma unroll
    for (int o=0;o<32;++o){
        float a = B2[o];
        #pragma unroll
        for (int c=0;c<32;++c) a += W2s[o*32+c]*h1[c];
        h2[o] = lrelu(a);
    }
    float* row = pfeat + (size_t)n*68;
    *(float4*)row = make_float4(el[n], el[NPTS+n], el[2*NPTS+n], el[3*NPTS+n]);
    #pragma unroll
    for (int o4=0;o4<16;++o4){
        float tmp[4];
        #pragma unroll
        for (int q=0;q<4;++q){
            const int o = o4*4+q;
            float a = B3[o];
            #pragma unroll
            for (int c=0;c<32;++c) a += W3s[o*32+c]*h2[c];
            tmp[q] = lrelu(a);
        }
        *(float4*)(row + 4 + o4*4) = make_float4(tmp[0],tmp[1],tmp[2],tmp[3]);
    }
}

// ---------------------------------------------------------------- splat (scatter-add, wave-per-pair)
__global__ __launch_bounds__(256) void splat_kernel(
        const float* __restrict__ pfeat, const float* __restrict__ bary,
        const int* __restrict__ off, float* __restrict__ lat){
    const int pair = (blockIdx.x*256 + threadIdx.x) >> 6;   // 0 .. 5*NPTS-1
    const int lane = threadIdx.x & 63;
    const int n = pair & (NPTS-1);
    const int j = pair >> 15;
    const float b = bary[j*NPTS + n];
    const int o = off[j*NPTS + n];
    const float* row = pfeat + (size_t)n*68;
    float* dst = lat + (size_t)o*68;
    unsafeAtomicAdd(&dst[lane], b*row[lane]);
    if (lane < 4) unsafeAtomicAdd(&dst[64+lane], b*row[64+lane]);
}

// ---------------------------------------------------------------- lat f32 -> bf16 hi/lo, reordered [feat64][el4]
__global__ __launch_bounds__(256) void cvt_lat_kernel(const float* __restrict__ lat,
        unsigned short* __restrict__ lH, unsigned short* __restrict__ lL){
    const int idx = blockIdx.x*256 + threadIdx.x;   // HL*17
    const int r = idx / 17, j = idx - r*17;
    const int co = (j < 16) ? (4 + j*4) : 0;
    const float4 v = *(const float4*)(lat + (size_t)r*68 + co);
    unsigned short h0,h1,h2,h3,l0,l1,l2,l3;
    bf16_hilo(v.x,h0,l0); bf16_hilo(v.y,h1,l1); bf16_hilo(v.z,h2,l2); bf16_hilo(v.w,h3,l3);
    const int ko = j*4;
    *(ushort4*)(lH + (size_t)r*68 + ko) = make_ushort4(h0,h1,h2,h3);
    *(ushort4*)(lL + (size_t)r*68 + ko) = make_ushort4(l0,l1,l2,l3);
}

// ---------------------------------------------------------------- blur_s via split-bf16 MFMA (32-row tiles, dbuf)
// block: 32 h, 4 waves; wave w owns o-tile w. side1: also writes cat bf16 (cH/cL non-null)
__global__ __launch_bounds__(256) void blur_s_mfma_kernel(
        const unsigned short* __restrict__ latH, const unsigned short* __restrict__ latL,
        const int* __restrict__ nb,
        const unsigned short* __restrict__ SW16,
        const float* __restrict__ sb1, const float* __restrict__ sb2,
        float* __restrict__ outp, int ostride,
        unsigned short* __restrict__ cH, unsigned short* __restrict__ cL){
    __shared__ __align__(16) unsigned short GH[2][2048], GL[2][2048];
    __shared__ __align__(16) unsigned short EH[2048], EL[2048];
    __shared__ int sidx[NNB][32];
    const int t = threadIdx.x;
    const int hb = blockIdx.x*32;
    const int w = t>>6, lane = t&63;
    const int l15 = lane&15, lg = lane>>4;
    for (int e=t; e<NNB*32; e+=256) sidx[e>>5][e&31] = nb[(e>>5)*HL + hb + (e&31)];
    {
        const uint4 z4 = {0,0,0,0};
        *(uint4*)(EH + t*8) = z4;
        *(uint4*)(EL + t*8) = z4;
    }
    __syncthreads();
    // prologue: stage nn=0 into buf0
    #pragma unroll
    for (int i=0;i<2;++i){
        const int e = t + 256*i;
        const int row = e>>4, q8 = e&15;
        const int g = sidx[0][row];
        const uint2 vh = *(const uint2*)(latH + (size_t)g*68 + q8*4);
        const uint2 vl = *(const uint2*)(latL + (size_t)g*68 + q8*4);
        const int d = row*64 + (((q8>>1) ^ (row&7))*8) + (q8&1)*4;
        *(uint2*)(GH[0] + d) = vh;
        *(uint2*)(GL[0] + d) = vl;
    }
    if (t < 32){
        const int g = sidx[0][t];
        const uint2 eh = *(const uint2*)(latH + (size_t)g*68 + 64);
        const uint2 elv = *(const uint2*)(latL + (size_t)g*68 + 64);
        const int d = t*64 + ((0 ^ (t&7))*8);
        *(uint2*)(EH + d) = eh;
        *(uint2*)(EL + d) = elv;
    }
    __syncthreads();
    const f32x4 z = {0.f,0.f,0.f,0.f};
    f32x4 acc[2] = {z,z};
    for (int nn=0; nn<NNB; ++nn){
        const int cur = nn&1;
        if (nn+1 < NNB){
            #pragma unroll
            for (int i=0;i<2;++i){
                const int e = t + 256*i;
                const int row = e>>4, q8 = e&15;
                const int g = sidx[nn+1][row];
                const uint2 vh = *(const uint2*)(latH + (size_t)g*68 + q8*4);
                const uint2 vl = *(const uint2*)(latL + (size_t)g*68 + q8*4);
                const int d = row*64 + (((q8>>1) ^ (row&7))*8) + (q8&1)*4;
                *(uint2*)(GH[cur^1] + d) = vh;
                *(uint2*)(GL[cur^1] + d) = vl;
            }
            if (t < 32){
                const int g = sidx[nn+1][t];
                const uint2 eh = *(const uint2*)(latH + (size_t)g*68 + 64);
                const uint2 elv = *(const uint2*)(latL + (size_t)g*68 + 64);
                const int q0 = (nn+1)>>1;
                const int d = t*64 + ((q0 ^ (t&7))*8) + ((nn+1)&1)*4;
                *(uint2*)(EH + d) = eh;
                *(uint2*)(EL + d) = elv;
            }
        }
        #pragma unroll
        for (int kt=0; kt<2; ++kt){
            s16x8 BH[2], BL[2];
            #pragma unroll
            for (int ht=0; ht<2; ++ht){
                const int h = ht*16 + l15;
                const int q = kt*4 + lg;
                const int d = h*64 + ((q ^ (h&7))*8);
                BH[ht] = *(const s16x8*)(GH[cur] + d);
                BL[ht] = *(const s16x8*)(GL[cur] + d);
            }
            const int f = nn*2 + kt;
            const s16x8 AH = *(const s16x8*)(SW16 + (f*4+w)*512 + lane*8);
            const s16x8 AL = *(const s16x8*)(SW16 + 61440 + (f*4+w)*512 + lane*8);
            #pragma unroll
            for (int ht=0; ht<2; ++ht){
                acc[ht] = __builtin_amdgcn_mfma_f32_16x16x32_bf16(AH, BH[ht], acc[ht], 0,0,0);
                acc[ht] = __builtin_amdgcn_mfma_f32_16x16x32_bf16(AH, BL[ht], acc[ht], 0,0,0);
                acc[ht] = __builtin_amdgcn_mfma_f32_16x16x32_bf16(AL, BH[ht], acc[ht], 0,0,0);
            }
        }
        __syncthreads();
    }
    // el GEMM (K=64 packed across nn)
    #pragma unroll
    for (int kt2=0; kt2<2; ++kt2){
        s16x8 BH[2], BL[2];
        #pragma unroll
        for (int ht=0; ht<2; ++ht){
            const int h = ht*16 + l15;
            const int q = kt2*4 + lg;
            const int d = h*64 + ((q ^ (h&7))*8);
            BH[ht] = *(const s16x8*)(EH + d);
            BL[ht] = *(const s16x8*)(EL + d);
        }
        const s16x8 AH = *(const s16x8*)(SW16 + 122880 + (kt2*4+w)*512 + lane*8);
        const s16x8 AL = *(const s16x8*)(SW16 + 126976 + (kt2*4+w)*512 + lane*8);
        #pragma unroll
        for (int ht=0; ht<2; ++ht){
            acc[ht] = __builtin_amdgcn_mfma_f32_16x16x32_bf16(AH, BH[ht], acc[ht], 0,0,0);
            acc[ht] = __builtin_amdgcn_mfma_f32_16x16x32_bf16(AH, BL[ht], acc[ht], 0,0,0);
            acc[ht] = __builtin_amdgcn_mfma_f32_16x16x32_bf16(AL, BH[ht], acc[ht], 0,0,0);
        }
    }
    // T = lrelu(acc + sb1) -> bf16 hi/lo in GH[0]/GL[0], layout [h][o] swizzled
    {
        const int o0 = w*16 + lg*4;
        float bs1v[4];
        #pragma unroll
        for (int j=0;j<4;++j) bs1v[j] = sb1[o0+j];
        const int q16 = o0>>3;
        #pragma unroll
        for (int ht=0; ht<2; ++ht){
            const int h = ht*16 + l15;
            unsigned short th[4], tl[4];
            #pragma unroll
            for (int j=0;j<4;++j) bf16_hilo(lrelu(acc[ht][j] + bs1v[j]), th[j], tl[j]);
            const int d = h*64 + ((q16 ^ (h&7))*8) + (o0&7);
            *(ushort4*)(GH[0] + d) = make_ushort4(th[0],th[1],th[2],th[3]);
            *(ushort4*)(GL[0] + d) = make_ushort4(tl[0],tl[1],tl[2],tl[3]);
        }
    }
    __syncthreads();
    // GEMM2: out = lrelu(sw2 . T + sb2)
    f32x4 acc2[2] = {z,z};
    #pragma unroll
    for (int kt=0; kt<2; ++kt){
        s16x8 BH[2], BL[2];
        #pragma unroll
        for (int ht=0; ht<2; ++ht){
            const int h = ht*16 + l15;
            const int q = kt*4 + lg;
            const int d = h*64 + ((q ^ (h&7))*8);
            BH[ht] = *(const s16x8*)(GH[0] + d);
            BL[ht] = *(const s16x8*)(GL[0] + d);
        }
        const s16x8 AH = *(const s16x8*)(SW16 + 131072 + (kt*4+w)*512 + lane*8);
        const s16x8 AL = *(const s16x8*)(SW16 + 135168 + (kt*4+w)*512 + lane*8);
        #pragma unroll
        for (int ht=0; ht<2; ++ht){
            acc2[ht] = __builtin_amdgcn_mfma_f32_16x16x32_bf16(AH, BH[ht], acc2[ht], 0,0,0);
            acc2[ht] = __builtin_amdgcn_mfma_f32_16x16x32_bf16(AH, BL[ht], acc2[ht], 0,0,0);
            acc2[ht] = __builtin_amdgcn_mfma_f32_16x16x32_bf16(AL, BH[ht], acc2[ht], 0,0,0);
        }
    }
    {
        const int o0 = w*16 + lg*4;
        float bs2v[4];
        #pragma unroll
        for (int j=0;j<4;++j) bs2v[j] = sb2[o0+j];
        #pragma unroll
        for (int ht=0; ht<2; ++ht){
            const int h = hb + ht*16 + l15;
            float v0 = lrelu(acc2[ht][0]+bs2v[0]), v1 = lrelu(acc2[ht][1]+bs2v[1]);
            float v2 = lrelu(acc2[ht][2]+bs2v[2]), v3 = lrelu(acc2[ht][3]+bs2v[3]);
            *(float4*)(outp + (size_t)h*ostride + o0) = make_float4(v0,v1,v2,v3);
            if (cH){
                unsigned short th[4], tl[4];
                bf16_hilo(v0, th[0], tl[0]); bf16_hilo(v1, th[1], tl[1]);
                bf16_hilo(v2, th[2], tl[2]); bf16_hilo(v3, th[3], tl[3]);
                *(ushort4*)(cH + (size_t)h*128 + o0) = make_ushort4(th[0],th[1],th[2],th[3]);
                *(ushort4*)(cL + (size_t)h*128 + o0) = make_ushort4(tl[0],tl[1],tl[2],tl[3]);
            }
        }
    }
}

// ---------------------------------------------------------------- corr + d-MLP via split-bf16 MFMA
// writes cat channels 64..127 as bf16 hi/lo directly (cvt_cat fused away)
__global__ __launch_bounds__(256) void corr_mfma_kernel(
        const float* __restrict__ cat, const float* __restrict__ lat2, const int* __restrict__ ci,
        const unsigned short* __restrict__ W16,
        const float* __restrict__ cb1, const float* __restrict__ cb2,
        const float* __restrict__ db1, const float* __restrict__ db2,
        unsigned short* __restrict__ cH, unsigned short* __restrict__ cL){
    const int t = threadIdx.x;
    const int lane = t & 63;
    const int l15 = lane & 15, lg = lane >> 4;
    const int hcol = blockIdx.x*64 + (t>>6)*16 + l15;
    const int srcA = (l15 + ((lg&1)*32)) * 4;
    const int srcB = srcA + 64;
    const int sel = (lg>>1) & 1;

    s16x8 C1H[2][2], C1L[2][2], C2H[2], C2L[2];
    #pragma unroll
    for (int ot=0; ot<2; ++ot){
        #pragma unroll
        for (int kt=0; kt<2; ++kt){
            C1H[ot][kt] = *(const s16x8*)(W16 + (ot*2+kt)*512 + lane*8);
            C1L[ot][kt] = *(const s16x8*)(W16 + 2048 + (ot*2+kt)*512 + lane*8);
        }
        C2H[ot] = *(const s16x8*)(W16 + 4096 + ot*512 + lane*8);
        C2L[ot] = *(const s16x8*)(W16 + 5120 + ot*512 + lane*8);
    }
    float l1f[16];
    {
        const float* lr = cat + (size_t)hcol*128;
        *(float4*)&l1f[0]  = *(const float4*)(lr + lg*8);
        *(float4*)&l1f[4]  = *(const float4*)(lr + lg*8 + 4);
        *(float4*)&l1f[8]  = *(const float4*)(lr + 32 + lg*8);
        *(float4*)&l1f[12] = *(const float4*)(lr + 32 + lg*8 + 4);
    }
    float cb1r[8], cb2r[8];
    #pragma unroll
    for (int i=0;i<8;++i){
        cb1r[i] = cb1[(i>>2)*16 + lg*4 + (i&3)];
        cb2r[i] = cb2[(i>>2)*16 + lg*4 + (i&3)];
    }
    float agg[8] = {};
    const f32x4 z = {0.f,0.f,0.f,0.f};

    int idx = ci[hcol];
    float4 g0 = *(const float4*)(lat2 + (size_t)idx*64 + lg*8);
    float4 g1 = *(const float4*)(lat2 + (size_t)idx*64 + lg*8 + 4);
    float4 g2v = *(const float4*)(lat2 + (size_t)idx*64 + 32 + lg*8);
    float4 g3 = *(const float4*)(lat2 + (size_t)idx*64 + 32 + lg*8 + 4);

    for (int k=0; k<KC; ++k){
        float p[16];
        p[0]=l1f[0]*g0.x; p[1]=l1f[1]*g0.y; p[2]=l1f[2]*g0.z; p[3]=l1f[3]*g0.w;
        p[4]=l1f[4]*g1.x; p[5]=l1f[5]*g1.y; p[6]=l1f[6]*g1.z; p[7]=l1f[7]*g1.w;
        p[8]=l1f[8]*g2v.x; p[9]=l1f[9]*g2v.y; p[10]=l1f[10]*g2v.z; p[11]=l1f[11]*g2v.w;
        p[12]=l1f[12]*g3.x; p[13]=l1f[13]*g3.y; p[14]=l1f[14]*g3.z; p[15]=l1f[15]*g3.w;
        if (k+1 < KC){
            idx = ci[(k+1)*HL + hcol];
            g0 = *(const float4*)(lat2 + (size_t)idx*64 + lg*8);
            g1 = *(const float4*)(lat2 + (size_t)idx*64 + lg*8 + 4);
            g2v = *(const float4*)(lat2 + (size_t)idx*64 + 32 + lg*8);
            g3 = *(const float4*)(lat2 + (size_t)idx*64 + 32 + lg*8 + 4);
        }
        pk8 BH[2], BL[2];
        #pragma unroll
        for (int kt=0; kt<2; ++kt){
            #pragma unroll
            for (int q=0; q<4; ++q){
                unsigned short h0,l0,h1,l1v;
                bf16_hilo(p[kt*8+2*q], h0, l0);
                bf16_hilo(p[kt*8+2*q+1], h1, l1v);
                BH[kt].u[q] = pk2(h0,h1);
                BL[kt].u[q] = pk2(l0,l1v);
            }
        }
        f32x4 a1[2] = {z, z};
        #pragma unroll
        for (int kt=0; kt<2; ++kt){
            a1[0] = __builtin_amdgcn_mfma_f32_16x16x32_bf16(C1H[0][kt], BH[kt].v, a1[0], 0,0,0);
            a1[1] = __builtin_amdgcn_mfma_f32_16x16x32_bf16(C1H[1][kt], BH[kt].v, a1[1], 0,0,0);
            a1[0] = __builtin_amdgcn_mfma_f32_16x16x32_bf16(C1H[0][kt], BL[kt].v, a1[0], 0,0,0);
            a1[1] = __builtin_amdgcn_mfma_f32_16x16x32_bf16(C1H[1][kt], BL[kt].v, a1[1], 0,0,0);
            a1[0] = __builtin_amdgcn_mfma_f32_16x16x32_bf16(C1L[0][kt], BH[kt].v, a1[0], 0,0,0);
            a1[1] = __builtin_amdgcn_mfma_f32_16x16x32_bf16(C1L[1][kt], BH[kt].v, a1[1], 0,0,0);
        }
        unsigned mh[2][2], ml[2][2];
        #pragma unroll
        for (int ot=0; ot<2; ++ot){
            #pragma unroll
            for (int j=0; j<2; ++j){
                unsigned short h0,l0,h1,l1v;
                bf16_hilo(lrelu(a1[ot][2*j]   + cb1r[ot*4+2*j]),   h0, l0);
                bf16_hilo(lrelu(a1[ot][2*j+1] + cb1r[ot*4+2*j+1]), h1, l1v);
                mh[ot][j] = pk2(h0,h1);
                ml[ot][j] = pk2(l0,l1v);
            }
        }
        pk8 B2H = shuf32(mh[0], mh[1], sel, srcA, srcB);
        pk8 B2L = shuf32(ml[0], ml[1], sel, srcA, srcB);
        f32x4 a2[2] = {z, z};
        a2[0] = __builtin_amdgcn_mfma_f32_16x16x32_bf16(C2H[0], B2H.v, a2[0], 0,0,0);
        a2[1] = __builtin_amdgcn_mfma_f32_16x16x32_bf16(C2H[1], B2H.v, a2[1], 0,0,0);
        a2[0] = __builtin_amdgcn_mfma_f32_16x16x32_bf16(C2H[0], B2L.v, a2[0], 0,0,0);
        a2[1] = __builtin_amdgcn_mfma_f32_16x16x32_bf16(C2H[1], B2L.v, a2[1], 0,0,0);
        a2[0] = __builtin_amdgcn_mfma_f32_16x16x32_bf16(C2L[0], B2H.v, a2[0], 0,0,0);
        a2[1] = __builtin_amdgcn_mfma_f32_16x16x32_bf16(C2L[1], B2H.v, a2[1], 0,0,0);
        #pragma unroll
        for (int i=0;i<8;++i)
            agg[i] += lrelu(a2[i>>2][i&3] + cb2r[i]);
    }
    #pragma unroll
    for (int i=0;i<8;++i) agg[i] *= (1.0f/32.0f);
    unsigned agH[2][2], agL[2][2];
    #pragma unroll
    for (int ot=0; ot<2; ++ot)
        #pragma unroll
        for (int j=0; j<2; ++j){
            unsigned short h0,l0,h1,l1v;
            bf16_hilo(agg[ot*4+2*j],   h0, l0);
            bf16_hilo(agg[ot*4+2*j+1], h1, l1v);
            agH[ot][j] = pk2(h0,h1); agL[ot][j] = pk2(l0,l1v);
        }
    pk8 B3H = shuf32(agH[0], agH[1], sel, srcA, srcB);
    pk8 B3L = shuf32(agL[0], agL[1], sel, srcA, srcB);
    float db1r[16], db2r[16];
    #pragma unroll
    for (int i=0;i<16;++i){
        db1r[i] = db1[(i>>2)*16 + lg*4 + (i&3)];
        db2r[i] = db2[(i>>2)*16 + lg*4 + (i&3)];
    }
    unsigned d1H[4][2], d1L[4][2];
    #pragma unroll
    for (int ot=0; ot<4; ++ot){
        s16x8 AH = *(const s16x8*)(W16 + 6144 + ot*512 + lane*8);
        s16x8 AL = *(const s16x8*)(W16 + 8192 + ot*512 + lane*8);
        f32x4 a3 = z;
        a3 = __builtin_amdgcn_mfma_f32_16x16x32_bf16(AH, B3H.v, a3, 0,0,0);
        a3 = __builtin_amdgcn_mfma_f32_16x16x32_bf16(AH, B3L.v, a3, 0,0,0);
        a3 = __builtin_amdgcn_mfma_f32_16x16x32_bf16(AL, B3H.v, a3, 0,0,0);
        #pragma unroll
        for (int j=0;j<2;++j){
            unsigned short h0,l0,h1,l1v;
            bf16_hilo(lrelu(a3[2*j]   + db1r[ot*4+2*j]),   h0, l0);
            bf16_hilo(lrelu(a3[2*j+1] + db1r[ot*4+2*j+1]), h1, l1v);
            d1H[ot][j] = pk2(h0,h1); d1L[ot][j] = pk2(l0,l1v);
        }
    }
    f32x4 a4[4] = {z,z,z,z};
    #pragma unroll
    for (int kt=0; kt<2; ++kt){
        pk8 B4H = shuf32(d1H[kt*2], d1H[kt*2+1], sel, srcA, srcB);
        pk8 B4L = shuf32(d1L[kt*2], d1L[kt*2+1], sel, srcA, srcB);
        #pragma unroll
        for (int ot=0; ot<4; ++ot){
            s16x8 AH = *(const s16x8*)(W16 + 10240 + (ot*2+kt)*512 + lane*8);
            s16x8 AL = *(const s16x8*)(W16 + 14336 + (ot*2+kt)*512 + lane*8);
            a4[ot] = __builtin_amdgcn_mfma_f32_16x16x32_bf16(AH, B4H.v, a4[ot], 0,0,0);
            a4[ot] = __builtin_amdgcn_mfma_f32_16x16x32_bf16(AH, B4L.v, a4[ot], 0,0,0);
            a4[ot] = __builtin_amdgcn_mfma_f32_16x16x32_bf16(AL, B4H.v, a4[ot], 0,0,0);
        }
    }
    unsigned short* dH = cH + (size_t)hcol*128 + 64;
    unsigned short* dL = cL + (size_t)hcol*128 + 64;
    #pragma unroll
    for (int ot=0; ot<4; ++ot){
        float v0 = lrelu(a4[ot][0]+db2r[ot*4+0]), v1 = lrelu(a4[ot][1]+db2r[ot*4+1]);
        float v2 = lrelu(a4[ot][2]+db2r[ot*4+2]), v3 = lrelu(a4[ot][3]+db2r[ot*4+3]);
        unsigned short th[4], tl[4];
        bf16_hilo(v0, th[0], tl[0]); bf16_hilo(v1, th[1], tl[1]);
        bf16_hilo(v2, th[2], tl[2]); bf16_hilo(v3, th[3], tl[3]);
        *(ushort4*)(dH + ot*16 + lg*4) = make_ushort4(th[0],th[1],th[2],th[3]);
        *(ushort4*)(dL + ot*16 + lg*4) = make_ushort4(tl[0],tl[1],tl[2],tl[3]);
    }
}

// ---------------------------------------------------------------- blur_p via split-bf16 MFMA (32-row tiles, dbuf)
__global__ __launch_bounds__(256) void blur_p_mfma_kernel(
        const unsigned short* __restrict__ catH, const unsigned short* __restrict__ catL,
        const int* __restrict__ nb,
        const unsigned short* __restrict__ pw1fH, const unsigned short* __restrict__ pw1fL,
        const float* __restrict__ pb1,
        const unsigned short* __restrict__ pw2fH, const unsigned short* __restrict__ pw2fL,
        const float* __restrict__ pb2,
        float* __restrict__ p){
    __shared__ __align__(16) unsigned short GH[2][4096];
    __shared__ __align__(16) unsigned short GLb[2][4096];
    __shared__ int sidx[NNB][32];
    const int t = threadIdx.x;
    const int hb = blockIdx.x*32;
    const int w = t>>6, lane = t&63;
    const int l15 = lane&15, lg = lane>>4;
    for (int e=t; e<NNB*32; e+=256) sidx[e>>5][e&31] = nb[(e>>5)*HL + hb + (e&31)];
    const f32x4 z = {0.f,0.f,0.f,0.f};
    f32x4 acc1[2][2] = {{z,z},{z,z}};
    __syncthreads();
    // prologue: stage nn=0 into buf0
    #pragma unroll
    for (int i=0;i<2;++i){
        const int e = t + 256*i;
        const int row = e>>4, q = e&15;
        const int g = sidx[0][row];
        const uint4 vh = *(const uint4*)(catH + (size_t)g*128 + q*8);
        const uint4 vl = *(const uint4*)(catL + (size_t)g*128 + q*8);
        const int d = row*128 + ((q ^ (row&7))*8);
        *(uint4*)(GH[0] + d) = vh;
        *(uint4*)(GLb[0] + d) = vl;
    }
    __syncthreads();
    for (int nn=0; nn<NNB; ++nn){
        const int cur = nn&1;
        if (nn+1 < NNB){
            #pragma unroll
            for (int i=0;i<2;++i){
                const int e = t + 256*i;
                const int row = e>>4, q = e&15;
                const int g = sidx[nn+1][row];
                const uint4 vh = *(const uint4*)(catH + (size_t)g*128 + q*8);
                const uint4 vl = *(const uint4*)(catL + (size_t)g*128 + q*8);
                const int d = row*128 + ((q ^ (row&7))*8);
                *(uint4*)(GH[cur^1] + d) = vh;
                *(uint4*)(GLb[cur^1] + d) = vl;
            }
        }
        #pragma unroll
        for (int kt=0; kt<4; ++kt){
            s16x8 BH[2], BL[2];
            #pragma unroll
            for (int ht=0; ht<2; ++ht){
                const int h = ht*16 + l15;
                const int q = kt*4 + lg;
                const int d = h*128 + ((q ^ (h&7))*8);
                BH[ht] = *(const s16x8*)(GH[cur] + d);
                BL[ht] = *(const s16x8*)(GLb[cur] + d);
            }
            s16x8 AH[2], AL[2];
            #pragma unroll
            for (int ot=0; ot<2; ++ot){
                const size_t fo = ((size_t)((nn*4 + kt)*8 + (w*2+ot)))*512 + lane*8;
                AH[ot] = *(const s16x8*)(pw1fH + fo);
                AL[ot] = *(const s16x8*)(pw1fL + fo);
            }
            #pragma unroll
            for (int ht=0; ht<2; ++ht)
                #pragma unroll
                for (int ot=0; ot<2; ++ot){
                    acc1[ot][ht] = __builtin_amdgcn_mfma_f32_16x16x32_bf16(AH[ot], BH[ht], acc1[ot][ht], 0,0,0);
                    acc1[ot][ht] = __builtin_amdgcn_mfma_f32_16x16x32_bf16(AH[ot], BL[ht], acc1[ot][ht], 0,0,0);
                    acc1[ot][ht] = __builtin_amdgcn_mfma_f32_16x16x32_bf16(AL[ot], BH[ht], acc1[ot][ht], 0,0,0);
                }
        }
        __syncthreads();
    }
    // epilogue 1: T = lrelu(acc1 + pb1) as bf16 hi/lo into GH[0]/GLb[0]
    #pragma unroll
    for (int ot=0; ot<2; ++ot){
        const int o0 = (w*2+ot)*16 + lg*4;
        const float b0 = pb1[o0], b1v = pb1[o0+1], b2v = pb1[o0+2], b3v = pb1[o0+3];
        const int q = o0>>3;
        #pragma unroll
        for (int ht=0; ht<2; ++ht){
            const int h = ht*16 + l15;
            unsigned short th[4], tl[4];
            bf16_hilo(lrelu(acc1[ot][ht][0] + b0), th[0], tl[0]);
            bf16_hilo(lrelu(acc1[ot][ht][1] + b1v), th[1], tl[1]);
            bf16_hilo(lrelu(acc1[ot][ht][2] + b2v), th[2], tl[2]);
            bf16_hilo(lrelu(acc1[ot][ht][3] + b3v), th[3], tl[3]);
            const int d = h*128 + ((q ^ (h&7))*8) + (o0&7);
            *(ushort4*)(GH[0] + d)  = make_ushort4(th[0],th[1],th[2],th[3]);
            *(ushort4*)(GLb[0] + d) = make_ushort4(tl[0],tl[1],tl[2],tl[3]);
        }
    }
    __syncthreads();
    // GEMM2: P = pw2 . T
    f32x4 acc2[2][2] = {{z,z},{z,z}};
    #pragma unroll
    for (int kt=0; kt<4; ++kt){
        s16x8 BH[2], BL[2];
        #pragma unroll
        for (int ht=0; ht<2; ++ht){
            const int h = ht*16 + l15;
            const int q = kt*4 + lg;
            const int d = h*128 + ((q ^ (h&7))*8);
            BH[ht] = *(const s16x8*)(GH[0] + d);
            BL[ht] = *(const s16x8*)(GLb[0] + d);
        }
        s16x8 AH[2], AL[2];
        #pragma unroll
        for (int ot=0; ot<2; ++ot){
            const size_t fo = ((size_t)(kt*8 + (w*2+ot)))*512 + lane*8;
            AH[ot] = *(const s16x8*)(pw2fH + fo);
            AL[ot] = *(const s16x8*)(pw2fL + fo);
        }
        #pragma unroll
        for (int ht=0; ht<2; ++ht)
            #pragma unroll
            for (int ot=0; ot<2; ++ot){
                acc2[ot][ht] = __builtin_amdgcn_mfma_f32_16x16x32_bf16(AH[ot], BH[ht], acc2[ot][ht], 0,0,0);
                acc2[ot][ht] = __builtin_amdgcn_mfma_f32_16x16x32_bf16(AH[ot], BL[ht], acc2[ot][ht], 0,0,0);
                acc2[ot][ht] = __builtin_amdgcn_mfma_f32_16x16x32_bf16(AL[ot], BH[ht], acc2[ot][ht], 0,0,0);
            }
    }
    #pragma unroll
    for (int ot=0; ot<2; ++ot){
        const int o0 = (w*2+ot)*16 + lg*4;
        const float b0 = pb2[o0], b1v = pb2[o0+1], b2v = pb2[o0+2], b3v = pb2[o0+3];
        #pragma unroll
        for (int ht=0; ht<2; ++ht){
            const int h = hb + ht*16 + l15;
            float4 v = make_float4(lrelu(acc2[ot][ht][0] + b0), lrelu(acc2[ot][ht][1] + b1v),
                                   lrelu(acc2[ot][ht][2] + b2v), lrelu(acc2[ot][ht][3] + b3v));
            *(float4*)(p + (size_t)h*128 + o0) = v;
        }
    }
}

// ---------------------------------------------------------------- head: slice + 128->128->64->3
__global__ __launch_bounds__(256) void head_kernel(
        const float* __restrict__ p, const float* __restrict__ bary, const int* __restrict__ off,
        const float* __restrict__ fw2T, const float* __restrict__ fb2,
        const float* __restrict__ fw3T, const float* __restrict__ fb3,
        const float* __restrict__ fw4, const float* __restrict__ fb4,
        float* __restrict__ out){
    __shared__ __align__(16) float S[8704];
    __shared__ __align__(16) float WW[8192];
    __shared__ float SB[5][64];
    __shared__ int   SO[5][64];
    const int t = threadIdx.x;
    const int pb = blockIdx.x*64;
    const int oq8 = t>>4, pq = t&15;
    const int q5 = t&31, rgrp5 = t>>5;
    if (t<64){
        #pragma unroll
        for (int j=0;j<5;++j){ SB[j][t]=bary[j*NPTS+pb+t]; SO[j][t]=off[j*NPTS+pb+t]; }
    }
    __syncthreads();
    #pragma unroll
    for (int i=0;i<8;++i){
        const int row = rgrp5 + 8*i;
        float4 sa = make_float4(0.f,0.f,0.f,0.f);
        #pragma unroll
        for (int j=0;j<5;++j){
            const float4 v = *(const float4*)(p + (size_t)SO[j][row]*128 + q5*4);
            const float b = SB[j][row];
            sa.x += b*v.x; sa.y += b*v.y; sa.z += b*v.z; sa.w += b*v.w;
        }
        S[(q5*4+0)*68 + row] = sa.x;
        S[(q5*4+1)*68 + row] = sa.y;
        S[(q5*4+2)*68 + row] = sa.z;
        S[(q5*4+3)*68 + row] = sa.w;
    }
    float acc1[8][4] = {};
    #pragma unroll 1
    for (int hf=0;hf<2;++hf){
        if (hf==1) __syncthreads();
        for (int e=t;e<2048;e+=256)
            *(float4*)(WW + e*4) = *(const float4*)(fw2T + hf*8192 + e*4);
        __syncthreads();
        #pragma unroll 4
        for (int c=0;c<64;++c){
            const float4 a4 = *(const float4*)(S + (hf*64+c)*68 + pq*4);
            const float4 wa = *(const float4*)(WW + c*128 + oq8*8);
            const float4 wb = *(const float4*)(WW + c*128 + oq8*8 + 4);
            const float av[4]={a4.x,a4.y,a4.z,a4.w};
            const float wv[8]={wa.x,wa.y,wa.z,wa.w,wb.x,wb.y,wb.z,wb.w};
            #pragma unroll
            for (int i=0;i<8;++i)
                #pragma unroll
                for (int j=0;j<4;++j)
                    acc1[i][j] = fmaf(wv[i], av[j], acc1[i][j]);
        }
    }
    __syncthreads();
    float bf2[8];
    #pragma unroll
    for (int i=0;i<8;++i) bf2[i]=fb2[oq8*8+i];
    #pragma unroll
    for (int i=0;i<8;++i){
        const int o = oq8*8+i;
        float4 v = make_float4(lrelu(acc1[i][0]+bf2[i]), lrelu(acc1[i][1]+bf2[i]),
                               lrelu(acc1[i][2]+bf2[i]), lrelu(acc1[i][3]+bf2[i]));
        *(float4*)(S + o*68 + pq*4) = v;
    }
    for (int e=t;e<2048;e+=256)
        *(float4*)(WW + e*4) = *(const float4*)(fw3T + e*4);
    __syncthreads();
    const int od = t>>4;
    float bf3[4];
    #pragma unroll
    for (int i=0;i<4;++i) bf3[i]=fb3[od*4+i];
    float a2[4][4] = {};
    #pragma unroll 4
    for (int c=0;c<128;++c){
        const float4 a4 = *(const float4*)(S + c*68 + pq*4);
        const float4 w4 = *(const float4*)(WW + c*64 + od*4);
        const float av[4]={a4.x,a4.y,a4.z,a4.w};
        const float wv[4]={w4.x,w4.y,w4.z,w4.w};
        #pragma unroll
        for (int i=0;i<4;++i)
            #pragma unroll
            for (int j=0;j<4;++j)
                a2[i][j] = fmaf(wv[i], av[j], a2[i][j]);
    }
    __syncthreads();
    #pragma unroll
    for (int i=0;i<4;++i){
        float4 v = make_float4(lrelu(a2[i][0]+bf3[i]), lrelu(a2[i][1]+bf3[i]),
                               lrelu(a2[i][2]+bf3[i]), lrelu(a2[i][3]+bf3[i]));
        *(float4*)(S + (od*4+i)*68 + pq*4) = v;
    }
    __syncthreads();
    if (t < 192){
        const int r = t>>6, pp = t&63;
        float a = fb4[r];
        #pragma unroll 8
        for (int c=0;c<64;++c) a += fw4[r*64+c]*S[c*68+pp];
        out[r*NPTS + pb + pp] = a;
    }
}

// ================================================================ launch
extern "C" void kernel_launch(void* const* d_in, const int* in_sizes, int n_in,
                              void* d_out, int out_size, void* d_ws, size_t ws_size,
                              hipStream_t stream){
    const float* pc1   = (const float*)d_in[0];
    const float* pc2   = (const float*)d_in[1];
    const float* el1   = (const float*)d_in[2];
    const float* el2   = (const float*)d_in[3];
    const float* bary1 = (const float*)d_in[4];
    const float* bary2 = (const float*)d_in[5];
    const int*   off1  = (const int*)d_in[6];
    const int*   off2  = (const int*)d_in[7];
    const int*   nb1   = (const int*)d_in[8];
    const int*   nb2   = (const int*)d_in[9];
    const int*   ci    = (const int*)d_in[10];
    const float* w1    = (const float*)d_in[11];
    const float* b1    = (const float*)d_in[12];
    const float* w2    = (const float*)d_in[13];
    const float* b2    = (const float*)d_in[14];
    const float* w3    = (const float*)d_in[15];
    const float* b3    = (const float*)d_in[16];
    const float* sw1   = (const float*)d_in[17];
    const float* sb1   = (const float*)d_in[18];
    const float* sw2   = (const float*)d_in[19];
    const float* sb2   = (const float*)d_in[20];
    const float* cw1   = (const float*)d_in[21];
    const float* cb1   = (const float*)d_in[22];
    const float* cw2   = (const float*)d_in[23];
    const float* cb2   = (const float*)d_in[24];
    const float* dw1   = (const float*)d_in[25];
    const float* db1   = (const float*)d_in[26];
    const float* dw2   = (const float*)d_in[27];
    const float* db2   = (const float*)d_in[28];
    const float* pw1   = (const float*)d_in[29];
    const float* pb1   = (const float*)d_in[30];
    const float* pw2   = (const float*)d_in[31];
    const float* pb2   = (const float*)d_in[32];
    const float* fw2   = (const float*)d_in[33];
    const float* fb2   = (const float*)d_in[34];
    const float* fw3   = (const float*)d_in[35];
    const float* fb3   = (const float*)d_in[36];
    const float* fw4   = (const float*)d_in[37];
    const float* fb4   = (const float*)d_in[38];
    float* out = (float*)d_out;

    float* ws    = (float*)d_ws;
    float* pf1   = ws;                    // N*68 ; later lat16 x4 ; later pbuf
    float* pf2   = pf1   + 2228224;
    float* latA  = pf2   + 2228224;       // H*68 f32 ; later catH/catL
    float* latB  = latA  + 2228224;
    float* catb  = latB  + 2228224;       // H*128
    float* lat2p = catb  + 4194304;       // H*64
    float* pw1fS = lat2p + 2097152;       // 245760 floats = 491520 ushorts
    float* SW16f = pw1fS + 245760;        // 69632 floats = 139264 ushorts
    float* W16f  = SW16f + 69632;         // 9216 floats
    float* pw2fS = W16f  + 9216;          // 16384 floats
    float* fw2T  = pw2fS + 16384;         // 16384
    float* fw3T  = fw2T  + 16384;         // 8192
    float* pbuf  = pf1;                   // p (H*128) reuses pf1+pf2

    unsigned short* pw1fH = (unsigned short*)pw1fS;
    unsigned short* pw1fL = pw1fH + 245760;
    unsigned short* SW16  = (unsigned short*)SW16f;
    unsigned short* W16   = (unsigned short*)W16f;
    unsigned short* pw2fH = (unsigned short*)pw2fS;
    unsigned short* pw2fL = pw2fH + 16384;
    unsigned short* latA16H = (unsigned short*)pf1;
    unsigned short* latA16L = latA16H + 2228224;
    unsigned short* latB16H = latA16L + 2228224;
    unsigned short* latB16L = latB16H + 2228224;
    unsigned short* catH  = (unsigned short*)latA;   // f32 lattices dead after cvt_lat
    unsigned short* catL  = catH + (size_t)HL*128;

    zero_kernel<<<4352, 256, 0, stream>>>((float4*)latA);
    repack_kernel<<<960, 256, 0, stream>>>(sw1, pw1, sw2, cw1, cw2, dw1, dw2, pw2, fw2, fw3,
                                           SW16, pw1fH, pw1fL, W16,
                                           pw2fH, pw2fL, fw2T, fw3T);

    mlp3_kernel<<<128, 256, 0, stream>>>(pc1, el1, w1,b1,w2,b2,w3,b3, pf1);
    mlp3_kernel<<<128, 256, 0, stream>>>(pc2, el2, w1,b1,w2,b2,w3,b3, pf2);

    splat_kernel<<<40960, 256, 0, stream>>>(pf1, bary1, off1, latA);
    splat_kernel<<<40960, 256, 0, stream>>>(pf2, bary2, off2, latB);

    cvt_lat_kernel<<<2176, 256, 0, stream>>>(latA, latA16H, latA16L);
    cvt_lat_kernel<<<2176, 256, 0, stream>>>(latB, latB16H, latB16L);

    blur_s_mfma_kernel<<<1024, 256, 0, stream>>>(latA16H, latA16L, nb1, SW16, sb1, sb2,
                                                 catb, 128, catH, catL);
    blur_s_mfma_kernel<<<1024, 256, 0, stream>>>(latB16H, latB16L, nb2, SW16, sb1, sb2,
                                                 lat2p, 64, (unsigned short*)nullptr,
                                                 (unsigned short*)nullptr);

    corr_mfma_kernel<<<512, 256, 0, stream>>>(catb, lat2p, ci, W16, cb1, cb2, db1, db2,
                                              catH, catL);

    blur_p_mfma_kernel<<<1024, 256, 0, stream>>>(catH, catL, nb1, pw1fH, pw1fL, pb1,
                                                 pw2fH, pw2fL, pb2, pbuf);

    head_kernel<<<512, 256, 0, stream>>>(pbuf, bary1, off1, fw2T,fb2,fw3T,fb3,fw4,fb4, out);
}